// Round 8
// baseline (698.437 us; speedup 1.0000x reference)
//
#include <hip/hip_runtime.h>
#include <hip/hip_bf16.h>
#include <cstdint>

// B=2, T=2048, HID=1024, H=16, DK=DV=64, K(conv)=4. fp32 in/out.
// RICH layout (ws >= 40MB): ws = 5 bf16 planes P0..P4 (8 MB each).
//   d_out scratch: xb bf16 [0,8M) (dead after g/beta GEMMs);
//   betab fp32 [16][4096] at [0,256K); G at [256K,512K); ob bf16 at [8M,16M).
// Pipeline: cvt -> mega_gemm(zq,zk,zv,a) -> conv q/k/v (x8) -> g-GEMM
//   -> beta-GEMM -> kk -> scan -> ln_gate -> final GEMM.
//
// Scan R8: ONE DV-ROW PER WAVE. 2048 blocks x 64 thr = 8 waves/CU = 2/SIMD:
// hardware TLP hides the per-step LDS latency that 5 rounds of compiler-
// scheduling attempts (R2-R7, all null, VGPR pinned at 88) could not.
// State s = 1 fp32/lane (DK=lane). Look-ahead transform kept (serial chain =
// 1 fma/step; the 64-lane dot reduce has a full step of slack).
// blk = row*32 + bh => blk%8 = bh%8: all 64 row-siblings of a (b,h) on one
// XCD (k/q stream L2-shared; output 128B lines merge in one L2).
// Single-wave blocks: NO barriers (LDS is in-order per wave).

using bf16 = __hip_bfloat16;
typedef __bf16 bf16x8 __attribute__((ext_vector_type(8)));
typedef __bf16 bf16x4v __attribute__((ext_vector_type(4)));
typedef float f32x4 __attribute__((ext_vector_type(4)));
typedef float f32x2 __attribute__((ext_vector_type(2)));
typedef unsigned int u32x4 __attribute__((ext_vector_type(4)));
typedef unsigned int u32x2 __attribute__((ext_vector_type(2)));

__device__ __forceinline__ __bf16 cvt_bf16(float f) {
  __hip_bfloat16 h = (__hip_bfloat16)f;
  return *reinterpret_cast<__bf16*>(&h);
}
__device__ __forceinline__ void async_copy16(const void* g, void* l) {
  __builtin_amdgcn_global_load_lds((const __attribute__((address_space(1))) void*)g,
                                   (__attribute__((address_space(3))) void*)l,
                                   16, 0, 0);
}
__device__ __forceinline__ float bcf(unsigned int u) { return __builtin_bit_cast(float, u); }
template <int CTRL>
__device__ __forceinline__ float dpp_f(float x) {
  int y = __builtin_amdgcn_update_dpp(0, __builtin_bit_cast(int, x), CTRL, 0xF, 0xF, true);
  return __builtin_bit_cast(float, y);
}
// full 64-lane sum: 4 DPP stages (16-lane groups) + cross-16 + cross-32
__device__ __forceinline__ float red64(float x) {
  x += dpp_f<0xB1>(x);
  x += dpp_f<0x4E>(x);
  x += dpp_f<0x141>(x);
  x += dpp_f<0x140>(x);
  x += __shfl_xor(x, 16);
  x += __shfl_xor(x, 32);
  return x;
}

// fp32 -> bf16 plane (4M elements)
__global__ __launch_bounds__(256) void cvt_plane_kernel(
    const float* __restrict__ in, bf16* __restrict__ out)
{
  size_t i = ((size_t)blockIdx.x * 256 + threadIdx.x) * 4;
  float4 f = *(const float4*)(in + i);
  bf16x4v t;
  t[0] = cvt_bf16(f.x); t[1] = cvt_bf16(f.y); t[2] = cvt_bf16(f.z); t[3] = cvt_bf16(f.w);
  *(bf16x4v*)((__bf16*)out + i) = t;
}

// C = A * Bt^T. A: MxK (bf16 async-staged unless A_FP32); Bt: NxK fp32.
// MODE 2: raw->bf16; 3: sigmoid(acc+bias)->bf16; 4: raw->fp32; 5: sigmoid(acc+bias)->fp32 TRANSPOSED
template <int MODE, bool A_FP32>
__global__ __launch_bounds__(256) void gemm_bt(
    const void* __restrict__ Av, const float* __restrict__ Bt,
    const float* __restrict__ bias, float* __restrict__ Cf, bf16* __restrict__ Cb,
    int M, int N, int K)
{
  __shared__ __align__(16) __bf16 As[128 * 32];
  __shared__ __align__(16) __bf16 Bs[128 * 32];

  const int tid  = threadIdx.x;
  const int lane = tid & 63;
  const int wave = tid >> 6;
  const int tile_m = blockIdx.y * 128;
  const int tile_n = blockIdx.x * 128;
  const int wm = (wave >> 1) * 64;
  const int wn = (wave & 1) * 64;

  const int srow = lane >> 2;
  const int scol = (lane & 3) * 8;

  f32x4 acc[4][4];
#pragma unroll
  for (int i = 0; i < 4; ++i)
#pragma unroll
    for (int j = 0; j < 4; ++j) acc[i][j] = {0.f, 0.f, 0.f, 0.f};

  for (int k0 = 0; k0 < K; k0 += 32) {
    float4 b0[2], b1[2], a0[2], a1[2];
#pragma unroll
    for (int s = 0; s < 2; ++s) {
      int brow = tile_n + s * 64 + wave * 16 + srow;
      if (brow > N - 1) brow = N - 1;             // clamp (beta GEMM: N=16)
      const float* bp = Bt + (size_t)brow * K + k0 + scol;
      b0[s] = *(const float4*)bp;
      b1[s] = *(const float4*)(bp + 4);
      if (A_FP32) {
        int arow = tile_m + s * 64 + wave * 16 + srow;
        const float* ap = (const float*)Av + (size_t)arow * K + k0 + scol;
        a0[s] = *(const float4*)ap;
        a1[s] = *(const float4*)(ap + 4);
      }
    }
    __syncthreads();
#pragma unroll
    for (int s = 0; s < 2; ++s) {
      if (!A_FP32) {
        int arow = tile_m + s * 64 + wave * 16 + srow;
        async_copy16((const __bf16*)Av + (size_t)arow * K + k0 + scol,
                     &As[(s * 64 + wave * 16 + srow) * 32 + scol]);
      } else {
        bf16x8 ua;
        ua[0] = cvt_bf16(a0[s].x); ua[1] = cvt_bf16(a0[s].y);
        ua[2] = cvt_bf16(a0[s].z); ua[3] = cvt_bf16(a0[s].w);
        ua[4] = cvt_bf16(a1[s].x); ua[5] = cvt_bf16(a1[s].y);
        ua[6] = cvt_bf16(a1[s].z); ua[7] = cvt_bf16(a1[s].w);
        *(bf16x8*)&As[(s * 64 + wave * 16 + srow) * 32 + scol] = ua;
      }
      bf16x8 u;
      u[0] = cvt_bf16(b0[s].x); u[1] = cvt_bf16(b0[s].y);
      u[2] = cvt_bf16(b0[s].z); u[3] = cvt_bf16(b0[s].w);
      u[4] = cvt_bf16(b1[s].x); u[5] = cvt_bf16(b1[s].y);
      u[6] = cvt_bf16(b1[s].z); u[7] = cvt_bf16(b1[s].w);
      *(bf16x8*)&Bs[(s * 64 + wave * 16 + srow) * 32 + scol] = u;
    }
    __syncthreads();

    bf16x8 af[4], bfr[4];
#pragma unroll
    for (int i = 0; i < 4; ++i)
      af[i] = *(const bf16x8*)&As[(wm + i * 16 + (lane & 15)) * 32 + (lane >> 4) * 8];
#pragma unroll
    for (int j = 0; j < 4; ++j)
      bfr[j] = *(const bf16x8*)&Bs[(wn + j * 16 + (lane & 15)) * 32 + (lane >> 4) * 8];

#pragma unroll
    for (int i = 0; i < 4; ++i)
#pragma unroll
      for (int j = 0; j < 4; ++j)
        acc[i][j] = __builtin_amdgcn_mfma_f32_16x16x32_bf16(af[i], bfr[j], acc[i][j], 0, 0, 0);
  }

  // C/D layout (m89-verified): col = lane&15, row = (lane>>4)*4 + reg
#pragma unroll
  for (int i = 0; i < 4; ++i) {
#pragma unroll
    for (int j = 0; j < 4; ++j) {
#pragma unroll
      for (int r = 0; r < 4; ++r) {
        int gm = tile_m + wm + i * 16 + (lane >> 4) * 4 + r;
        int gn = tile_n + wn + j * 16 + (lane & 15);
        if (gn < N) {
          float val = acc[i][j][r];
          if (MODE == 3 || MODE == 5) {
            float bv = bias ? bias[gn] : 0.f;
            val = 1.f / (1.f + __expf(-(val + bv)));
          }
          if (MODE == 4)      Cf[(size_t)gm * N + gn] = val;
          else if (MODE == 5) Cf[(size_t)gn * M + gm] = val;   // transposed
          else                Cb[(size_t)gm * N + gn] = (bf16)val;
        }
      }
    }
  }
}

// Fused 4-projection GEMM: C4 = A @ [Wq;Wk;Wv;Wa]^T, logical N=4096.
__global__ __launch_bounds__(256) void mega_gemm(
    const bf16* __restrict__ Av, const float* __restrict__ Wq,
    const float* __restrict__ Wk, const float* __restrict__ Wv,
    const float* __restrict__ Wa, const float* __restrict__ ba,
    bf16* __restrict__ C4, int M, int K)
{
  __shared__ __align__(16) __bf16 As[128 * 32];
  __shared__ __align__(16) __bf16 Bs[128 * 32];

  const int tid  = threadIdx.x;
  const int lane = tid & 63;
  const int wave = tid >> 6;
  const int tile_m = blockIdx.y * 128;
  const int tile_n = blockIdx.x * 128;
  const int grp = tile_n >> 10;                 // which weight (tile fully inside)
  const int tnl = tile_n & 1023;                // local col base
  const float* Bt = (grp == 0) ? Wq : (grp == 1) ? Wk : (grp == 2) ? Wv : Wa;
  const int wm = (wave >> 1) * 64;
  const int wn = (wave & 1) * 64;

  const int srow = lane >> 2;
  const int scol = (lane & 3) * 8;

  f32x4 acc[4][4];
#pragma unroll
  for (int i = 0; i < 4; ++i)
#pragma unroll
    for (int j = 0; j < 4; ++j) acc[i][j] = {0.f, 0.f, 0.f, 0.f};

  for (int k0 = 0; k0 < K; k0 += 32) {
    float4 b0[2], b1[2];
#pragma unroll
    for (int s = 0; s < 2; ++s) {
      int brow = tnl + s * 64 + wave * 16 + srow;
      const float* bp = Bt + (size_t)brow * K + k0 + scol;
      b0[s] = *(const float4*)bp;
      b1[s] = *(const float4*)(bp + 4);
    }
    __syncthreads();
#pragma unroll
    for (int s = 0; s < 2; ++s) {
      int arow = tile_m + s * 64 + wave * 16 + srow;
      async_copy16((const __bf16*)Av + (size_t)arow * K + k0 + scol,
                   &As[(s * 64 + wave * 16 + srow) * 32 + scol]);
      bf16x8 u;
      u[0] = cvt_bf16(b0[s].x); u[1] = cvt_bf16(b0[s].y);
      u[2] = cvt_bf16(b0[s].z); u[3] = cvt_bf16(b0[s].w);
      u[4] = cvt_bf16(b1[s].x); u[5] = cvt_bf16(b1[s].y);
      u[6] = cvt_bf16(b1[s].z); u[7] = cvt_bf16(b1[s].w);
      *(bf16x8*)&Bs[(s * 64 + wave * 16 + srow) * 32 + scol] = u;
    }
    __syncthreads();

    bf16x8 af[4], bfr[4];
#pragma unroll
    for (int i = 0; i < 4; ++i)
      af[i] = *(const bf16x8*)&As[(wm + i * 16 + (lane & 15)) * 32 + (lane >> 4) * 8];
#pragma unroll
    for (int j = 0; j < 4; ++j)
      bfr[j] = *(const bf16x8*)&Bs[(wn + j * 16 + (lane & 15)) * 32 + (lane >> 4) * 8];

#pragma unroll
    for (int i = 0; i < 4; ++i)
#pragma unroll
      for (int j = 0; j < 4; ++j)
        acc[i][j] = __builtin_amdgcn_mfma_f32_16x16x32_bf16(af[i], bfr[j], acc[i][j], 0, 0, 0);
  }

  bf16* Cp = (bf16*)((__bf16*)C4 + (size_t)grp * M * 1024);
#pragma unroll
  for (int i = 0; i < 4; ++i) {
#pragma unroll
    for (int j = 0; j < 4; ++j) {
#pragma unroll
      for (int r = 0; r < 4; ++r) {
        int gm = tile_m + wm + i * 16 + (lane >> 4) * 4 + r;
        int col = tnl + wn + j * 16 + (lane & 15);
        float val = acc[i][j][r];
        if (grp == 3) val = 1.f / (1.f + __expf(-(val + ba[col])));
        ((__bf16*)Cp)[(size_t)gm * 1024 + col] = cvt_bf16(val);
      }
    }
  }
}

// causal depthwise conv K=4 + bias + SiLU (+scale), x8 vectorized.
__global__ __launch_bounds__(256) void conv_silu_kernel(
    const bf16* __restrict__ z, const float* __restrict__ w,
    const float* __restrict__ bias, bf16* __restrict__ out, float scale)
{
  int idx = blockIdx.x * 256 + threadIdx.x;   // 512K threads
  int c8 = idx & 127;
  int m  = idx >> 7;
  int t  = m & 2047;
  int c0 = c8 * 8;

  const __bf16* base = (const __bf16*)z + (size_t)m * 1024 + c0;
  const bf16x8 zzero = __builtin_bit_cast(bf16x8, (u32x4){0u, 0u, 0u, 0u});
  bf16x8 z3 = *(const bf16x8*)base;
  bf16x8 z2 = (t >= 1) ? *(const bf16x8*)(base - 1024) : zzero;
  bf16x8 z1 = (t >= 2) ? *(const bf16x8*)(base - 2048) : zzero;
  bf16x8 z0 = (t >= 3) ? *(const bf16x8*)(base - 3072) : zzero;

  const float* wp = w + c0 * 4;     // [ch][tap], 32 contiguous floats
  bf16x8 res;
#pragma unroll
  for (int e = 0; e < 8; ++e) {
    float4 we = *(const float4*)(wp + e * 4);
    float acc = bias[c0 + e] + (float)z3[e] * we.w;
    acc += (float)z2[e] * we.z;
    acc += (float)z1[e] * we.y;
    acc += (float)z0[e] * we.x;
    float s = acc / (1.f + __expf(-acc));
    res[e] = cvt_bf16(s * scale);
  }
  *(bf16x8*)((__bf16*)out + (size_t)m * 1024 + c0) = res;
}

// G[h][b*2048+t] = beta[h][b*2048+t] * (k_{t-1} . k_t) over DK=64 (0 at t=0).
__global__ __launch_bounds__(256) void kk_kernel(
    const bf16* __restrict__ k, const float* __restrict__ betab,
    float* __restrict__ G)
{
  int tid = blockIdx.x * 256 + threadIdx.x;
  int out = tid >> 2;            // h*4096 + m, m = b*2048+t
  int j   = tid & 3;
  int h = out >> 12;
  int m = out & 4095;
  int t = m & 2047;
  float s = 0.f;
  if (t > 0) {
    const __bf16* r1 = (const __bf16*)k + (size_t)m * 1024 + h * 64 + j * 16;
    const __bf16* r0 = r1 - 1024;
    bf16x8 a0 = *(const bf16x8*)r0;
    bf16x8 a1 = *(const bf16x8*)(r0 + 8);
    bf16x8 b0 = *(const bf16x8*)r1;
    bf16x8 b1 = *(const bf16x8*)(r1 + 8);
#pragma unroll
    for (int e = 0; e < 8; ++e)
      s += (float)a0[e] * (float)b0[e] + (float)a1[e] * (float)b1[e];
  }
  s += __shfl_xor(s, 1);
  s += __shfl_xor(s, 2);
  if (j == 0) G[out] = betab[out] * s;
}

// delta-rule scan: 1 DV-row per wave. 2048 blocks x 64 thr (8 waves/CU,
// 2/SIMD). blk = row*32 + bh. Lane = DK index; s = S[row][lane] fp32.
// Look-ahead: u(t) = S(t-2).k(t); cc_t = A_t - cc_{t-1}*G_t (1 fma chain).
__global__ __launch_bounds__(64, 2) void scan_kernel(
    const bf16* __restrict__ q, const bf16* __restrict__ k,
    const bf16* __restrict__ v, const bf16* __restrict__ a,
    const float* __restrict__ betab, const float* __restrict__ gkk,
    bf16* __restrict__ o)
{
  const int blk = blockIdx.x;
  const int bh  = blk & 31;          // blk%8 = bh%8 -> (b,h) pinned to one XCD
  const int row = blk >> 5;          // DV row 0..63
  const int b = bh >> 4, h = bh & 15;
  const int lane = threadIdx.x;      // DK index 0..63

  __shared__ __align__(16) __bf16 sk16[2][16][64];   // 4 KB
  __shared__ __align__(16) __bf16 sq16[2][16][64];   // 4 KB
  __shared__ __align__(16) float  sparm[2][16][4];   // 512 B [v,a,beta,G]
  __shared__ __align__(16) float  so[16][68];        // 4.25 KB

  const size_t bkq = (size_t)b * 2048 * 1024 + h * 64;   // k/q base
  const size_t bo  = bkq + row;                          // o scalar column
  const __bf16* kp = (const __bf16*)k;
  const __bf16* qp = (const __bf16*)q;
  const __bf16* vp = (const __bf16*)v;
  const __bf16* ap = (const __bf16*)a;

  const int g_st = lane >> 3;          // staging step row 0..7
  const int g_cg = (lane & 7) * 8;     // staging col
  const int sl   = lane & 15;
  const int grp  = lane >> 4;          // 0:v 1:a 2:beta 3:G

  bf16x8 pk0, pk1, pq0, pq1;
  float pparm;
  auto fetch = [&](int t0) {
    size_t r0 = bkq + (size_t)(t0 + g_st) * 1024 + g_cg;
    size_t r1 = r0 + 8ull * 1024;
    pk0 = *(const bf16x8*)(kp + r0);
    pk1 = *(const bf16x8*)(kp + r1);
    pq0 = *(const bf16x8*)(qp + r0);
    pq1 = *(const bf16x8*)(qp + r1);
    int t = t0 + sl;
    if (grp == 0)
      pparm = (float)*(vp + (size_t)(b * 2048 + t) * 1024 + h * 64 + row);
    else if (grp == 1)
      pparm = (float)*(ap + (size_t)(b * 2048 + t) * 1024 + h * 64 + row);
    else if (grp == 2)
      pparm = betab[(size_t)h * 4096 + b * 2048 + t];
    else
      pparm = gkk[(size_t)h * 4096 + b * 2048 + t];
  };
  auto commit = [&](int cb) {
    *(bf16x8*)&sk16[cb][g_st][g_cg]     = pk0;
    *(bf16x8*)&sk16[cb][8 + g_st][g_cg] = pk1;
    *(bf16x8*)&sq16[cb][g_st][g_cg]     = pq0;
    *(bf16x8*)&sq16[cb][8 + g_st][g_cg] = pq1;
    sparm[cb][sl][grp] = pparm;
  };

  fetch(0); commit(0);

  float s = 0.f, u = 0.f, cc = 0.f, aprev = 0.f, sold = 0.f;
  float kcur = (float)sk16[0][0][lane];   // single wave: LDS in-order after commit

  for (int c = 0; c < 128; ++c) {
    const int buf = c & 1;
    const bool hasNext = (c + 1 < 128);

    if (hasNext) fetch((c + 1) * 16);   // VMEM in flight during compute

#pragma unroll
    for (int i = 0; i < 16; ++i) {
      f32x4 pm = *(const f32x4*)&sparm[buf][i][0];   // uniform broadcast b128
      const float vr = pm[0], ar = pm[1], bt = pm[2], Gt = pm[3];
      float qt = (float)sq16[buf][i][lane];
      float knx = 0.f, unxt = 0.f;
      if (i < 15) {
        knx = (float)sk16[buf][i + 1][lane];
        unxt = red64(s * knx);           // uses s = S(t-1): one step of slack
      } else {
        sold = s;                        // S(t-1) for next chunk's preamble
      }
      float A_ = bt * __builtin_fmaf(aprev, u, -vr);
      cc = __builtin_fmaf(-cc, Gt, A_);  // the only loop-carried fma
      s = __builtin_fmaf(ar, s, -(cc * kcur));
      so[i][lane] = s * qt;              // deferred output partial
      aprev = ar;
      if (i < 15) { kcur = knx; u = unxt; }
    }

    if (hasNext) commit(buf ^ 1);        // vmcnt wait here; LDS in-order

    // deferred output reduce: 16 outputs x 64 partials; 4 lanes per output
    {
      int st = lane >> 2, part = lane & 3;
      float4 A0 = *(const float4*)&so[st][part * 16];
      float4 A1 = *(const float4*)&so[st][part * 16 + 4];
      float4 A2 = *(const float4*)&so[st][part * 16 + 8];
      float4 A3 = *(const float4*)&so[st][part * 16 + 12];
      float sr = (((A0.x + A0.y) + (A0.z + A0.w)) + ((A1.x + A1.y) + (A1.z + A1.w)))
               + (((A2.x + A2.y) + (A2.z + A2.w)) + ((A3.x + A3.y) + (A3.z + A3.w)));
      sr += __shfl_xor(sr, 1);
      sr += __shfl_xor(sr, 2);
      if (part == 0)
        *((__bf16*)o + bo + (size_t)(c * 16 + st) * 1024) = cvt_bf16(sr);
    }

    if (hasNext) {
      // preamble for next chunk: kcur = k[first]; u = Sold . k[first]
      kcur = (float)sk16[buf ^ 1][0][lane];
      u = red64(sold * kcur);
    }
  }
}

// LayerNorm over DV=64 per (b,t,h) row, *ln_w+ln_b, *gate -> bf16
__global__ __launch_bounds__(256) void ln_gate_kernel(
    const bf16* __restrict__ o, const bf16* __restrict__ g,
    const float* __restrict__ lnw, const float* __restrict__ lnb,
    bf16* __restrict__ out)
{
  int row = blockIdx.x * 4 + (threadIdx.x >> 6);
  int lane = threadIdx.x & 63;
  size_t idx = (size_t)row * 64 + lane;
  float xv = (float)o[idx];
  float mu = xv;
#pragma unroll
  for (int s = 1; s < 64; s <<= 1) mu += __shfl_xor(mu, s);
  mu *= (1.f / 64.f);
  float d = xv - mu;
  float vv = d * d;
#pragma unroll
  for (int s = 1; s < 64; s <<= 1) vv += __shfl_xor(vv, s);
  vv *= (1.f / 64.f);
  float y = d * rsqrtf(vv + 1e-5f) * lnw[lane] + lnb[lane];
  y *= (float)g[idx];
  out[idx] = (bf16)y;
}

extern "C" void kernel_launch(void* const* d_in, const int* in_sizes, int n_in,
                              void* d_out, int out_size, void* d_ws, size_t ws_size,
                              hipStream_t stream)
{
  const float* x   = (const float*)d_in[0];
  const float* Wq  = (const float*)d_in[1];
  const float* Wk  = (const float*)d_in[2];
  const float* Wv  = (const float*)d_in[3];
  const float* Wa  = (const float*)d_in[4];
  const float* ba  = (const float*)d_in[5];
  const float* Wb  = (const float*)d_in[6];
  const float* bb  = (const float*)d_in[7];
  const float* Wg  = (const float*)d_in[8];
  const float* Wo  = (const float*)d_in[9];
  const float* qcw = (const float*)d_in[10];
  const float* qcb = (const float*)d_in[11];
  const float* kcw = (const float*)d_in[12];
  const float* kcb = (const float*)d_in[13];
  const float* vcw = (const float*)d_in[14];
  const float* vcb = (const float*)d_in[15];
  const float* lnw = (const float*)d_in[16];
  const float* lnb = (const float*)d_in[17];

  const int M = 4096, HID = 1024;
  const size_t PLANE = (size_t)M * HID;
  const size_t PB = PLANE * sizeof(bf16);          // 8 MB bf16 plane

  char* ws = (char*)d_ws;
  float* outf  = (float*)d_out;
  float* betab = outf;                               // [0,256K)
  float* gkk   = (float*)((char*)d_out + 256 * 1024);// [256K,512K)
  bf16*  ob    = (bf16*)((char*)d_out + 8 * 1024 * 1024); // [8M,16M)

  const bool rich = (ws_size >= 5 * PB + 1024);

  dim3 blk(256);
  dim3 g8(8, 32);
  int nconv = (int)((size_t)M * 128 / 256);          // x8-vectorized conv grid

  if (rich) {
    bf16* P0 = (bf16*)(ws);
    bf16* P1 = (bf16*)(ws + PB);
    bf16* P2 = (bf16*)(ws + 2 * PB);
    bf16* P3 = (bf16*)(ws + 3 * PB);
    bf16* P4 = (bf16*)(ws + 4 * PB);
    bf16* xb = (bf16*)d_out;                         // [0,8M), dead before betab

    cvt_plane_kernel<<<(int)(PLANE / 1024), blk, 0, stream>>>(x, xb);
    // zq->P0, zk->P1, zv->P2, a(sigmoid+ba)->P3
    mega_gemm<<<dim3(32, 32), blk, 0, stream>>>(xb, Wq, Wk, Wv, Wa, ba, P0, M, HID);
    conv_silu_kernel<<<nconv, blk, 0, stream>>>(P0, qcw, qcb, P4, 1.f);     // q->P4
    conv_silu_kernel<<<nconv, blk, 0, stream>>>(P1, kcw, kcb, P0, 0.125f);  // k->P0
    conv_silu_kernel<<<nconv, blk, 0, stream>>>(P2, vcw, vcb, P1, 1.f);     // v->P1
    gemm_bt<3, false><<<g8, blk, 0, stream>>>(xb, Wg, nullptr, nullptr, P2, M, HID, HID); // g->P2
    gemm_bt<5, false><<<dim3(1, 32), blk, 0, stream>>>(xb, Wb, bb, betab, nullptr, M, 16, HID);
    kk_kernel<<<1024, blk, 0, stream>>>(P0, betab, gkk);
    scan_kernel<<<2048, dim3(64), 0, stream>>>(P4, P0, P1, P3, betab, gkk, ob);
    ln_gate_kernel<<<M * 16 / 4, blk, 0, stream>>>(ob, P2, lnw, lnb, P3);   // ->P3
    gemm_bt<4, false><<<g8, blk, 0, stream>>>(P3, Wo, nullptr, outf, nullptr, M, HID, HID);
  } else {
    bf16* P  = (bf16*)(ws);
    bf16* qb = (bf16*)(ws + PB);
    bf16* kb = (bf16*)(ws + 2 * PB);
    bf16* vb = (bf16*)(ws + 3 * PB);

    gemm_bt<2, true><<<g8, blk, 0, stream>>>(x, Wq, nullptr, nullptr, P, M, HID, HID);
    conv_silu_kernel<<<nconv, blk, 0, stream>>>(P, qcw, qcb, qb, 1.f);
    gemm_bt<2, true><<<g8, blk, 0, stream>>>(x, Wk, nullptr, nullptr, P, M, HID, HID);
    conv_silu_kernel<<<nconv, blk, 0, stream>>>(P, kcw, kcb, kb, 0.125f);
    gemm_bt<2, true><<<g8, blk, 0, stream>>>(x, Wv, nullptr, nullptr, P, M, HID, HID);
    conv_silu_kernel<<<nconv, blk, 0, stream>>>(P, vcw, vcb, vb, 1.f);
    gemm_bt<3, true><<<g8, blk, 0, stream>>>(x, Wa, ba, nullptr, P, M, HID, HID);
    gemm_bt<5, true><<<dim3(1, 32), blk, 0, stream>>>(x, Wb, bb, betab, nullptr, M, 16, HID);
    kk_kernel<<<1024, blk, 0, stream>>>(kb, betab, gkk);
    scan_kernel<<<2048, dim3(64), 0, stream>>>(qb, kb, vb, P, betab, gkk, ob);
    gemm_bt<3, true><<<g8, blk, 0, stream>>>(x, Wg, nullptr, nullptr, qb, M, HID, HID);
    ln_gate_kernel<<<M * 16 / 4, blk, 0, stream>>>(ob, qb, lnw, lnb, kb);
    gemm_bt<4, false><<<g8, blk, 0, stream>>>(kb, Wo, nullptr, outf, nullptr, M, HID, HID);
  }
}

// Round 9
// 510.637 us; speedup vs baseline: 1.3678x; 1.3678x over previous
//
#include <hip/hip_runtime.h>
#include <hip/hip_bf16.h>
#include <cstdint>

// B=2, T=2048, HID=1024, H=16, DK=DV=64, K(conv)=4. fp32 in/out.
// RICH layout (ws >= 40MB): ws = 5 bf16 planes P0..P4 (8 MB each).
//   d_out scratch: xb bf16 [0,8M) (dead after beta GEMM);
//   betab fp32 [16][4096] at [0,256K); G at [256K,512K); ob bf16 at [8M,16M).
// Pipeline: cvt -> mega_gemm(zq,zk,zv,a) -> conv q/k/v (x8) -> beta-GEMM
//   -> kk -> FUSED scan+g-GEMM -> ln_gate -> final GEMM.
//
// Scan: R7-proven version (2-step-group pipeline, 199us). R8's 1-row/wave
// TLP experiment REVERTED (occupancy rose 4x but per-wave serial path grew;
// 367us). Scan is single-wave per block -> __syncthreads removed (LDS is
// in-order within a wave), enabling wave-exit in the fused kernel.
// FUSION: scan leaves ~30/32 wave slots + all MFMA pipes idle for ~199us.
// g-GEMM (independent of scan; output consumed after) runs as blocks
// 512..767 of the SAME launch -> its ~25us serial time + a launch gap
// disappear into the scan's shadow (m114: MFMA/VALU waves co-schedule).

using bf16 = __hip_bfloat16;
typedef __bf16 bf16x8 __attribute__((ext_vector_type(8)));
typedef __bf16 bf16x4v __attribute__((ext_vector_type(4)));
typedef float f32x4 __attribute__((ext_vector_type(4)));
typedef float f32x2 __attribute__((ext_vector_type(2)));
typedef unsigned int u32x4 __attribute__((ext_vector_type(4)));
typedef unsigned int u32x2 __attribute__((ext_vector_type(2)));

__device__ __forceinline__ __bf16 cvt_bf16(float f) {
  __hip_bfloat16 h = (__hip_bfloat16)f;
  return *reinterpret_cast<__bf16*>(&h);
}
__device__ __forceinline__ void async_copy16(const void* g, void* l) {
  __builtin_amdgcn_global_load_lds((const __attribute__((address_space(1))) void*)g,
                                   (__attribute__((address_space(3))) void*)l,
                                   16, 0, 0);
}
__device__ __forceinline__ float bcf(unsigned int u) { return __builtin_bit_cast(float, u); }
template <int CTRL>
__device__ __forceinline__ float dpp_f(float x) {
  int y = __builtin_amdgcn_update_dpp(0, __builtin_bit_cast(int, x), CTRL, 0xF, 0xF, true);
  return __builtin_bit_cast(float, y);
}

// fp32 -> bf16 plane (4M elements)
__global__ __launch_bounds__(256) void cvt_plane_kernel(
    const float* __restrict__ in, bf16* __restrict__ out)
{
  size_t i = ((size_t)blockIdx.x * 256 + threadIdx.x) * 4;
  float4 f = *(const float4*)(in + i);
  bf16x4v t;
  t[0] = cvt_bf16(f.x); t[1] = cvt_bf16(f.y); t[2] = cvt_bf16(f.z); t[3] = cvt_bf16(f.w);
  *(bf16x4v*)((__bf16*)out + i) = t;
}

// C = A * Bt^T. A: MxK (bf16 async-staged unless A_FP32); Bt: NxK fp32.
// MODE 2: raw->bf16; 3: sigmoid(acc+bias)->bf16; 4: raw->fp32; 5: sigmoid(acc+bias)->fp32 TRANSPOSED
template <int MODE, bool A_FP32>
__global__ __launch_bounds__(256) void gemm_bt(
    const void* __restrict__ Av, const float* __restrict__ Bt,
    const float* __restrict__ bias, float* __restrict__ Cf, bf16* __restrict__ Cb,
    int M, int N, int K)
{
  __shared__ __align__(16) __bf16 As[128 * 32];
  __shared__ __align__(16) __bf16 Bs[128 * 32];

  const int tid  = threadIdx.x;
  const int lane = tid & 63;
  const int wave = tid >> 6;
  const int tile_m = blockIdx.y * 128;
  const int tile_n = blockIdx.x * 128;
  const int wm = (wave >> 1) * 64;
  const int wn = (wave & 1) * 64;

  const int srow = lane >> 2;
  const int scol = (lane & 3) * 8;

  f32x4 acc[4][4];
#pragma unroll
  for (int i = 0; i < 4; ++i)
#pragma unroll
    for (int j = 0; j < 4; ++j) acc[i][j] = {0.f, 0.f, 0.f, 0.f};

  for (int k0 = 0; k0 < K; k0 += 32) {
    float4 b0[2], b1[2], a0[2], a1[2];
#pragma unroll
    for (int s = 0; s < 2; ++s) {
      int brow = tile_n + s * 64 + wave * 16 + srow;
      if (brow > N - 1) brow = N - 1;             // clamp (beta GEMM: N=16)
      const float* bp = Bt + (size_t)brow * K + k0 + scol;
      b0[s] = *(const float4*)bp;
      b1[s] = *(const float4*)(bp + 4);
      if (A_FP32) {
        int arow = tile_m + s * 64 + wave * 16 + srow;
        const float* ap = (const float*)Av + (size_t)arow * K + k0 + scol;
        a0[s] = *(const float4*)ap;
        a1[s] = *(const float4*)(ap + 4);
      }
    }
    __syncthreads();
#pragma unroll
    for (int s = 0; s < 2; ++s) {
      if (!A_FP32) {
        int arow = tile_m + s * 64 + wave * 16 + srow;
        async_copy16((const __bf16*)Av + (size_t)arow * K + k0 + scol,
                     &As[(s * 64 + wave * 16 + srow) * 32 + scol]);
      } else {
        bf16x8 ua;
        ua[0] = cvt_bf16(a0[s].x); ua[1] = cvt_bf16(a0[s].y);
        ua[2] = cvt_bf16(a0[s].z); ua[3] = cvt_bf16(a0[s].w);
        ua[4] = cvt_bf16(a1[s].x); ua[5] = cvt_bf16(a1[s].y);
        ua[6] = cvt_bf16(a1[s].z); ua[7] = cvt_bf16(a1[s].w);
        *(bf16x8*)&As[(s * 64 + wave * 16 + srow) * 32 + scol] = ua;
      }
      bf16x8 u;
      u[0] = cvt_bf16(b0[s].x); u[1] = cvt_bf16(b0[s].y);
      u[2] = cvt_bf16(b0[s].z); u[3] = cvt_bf16(b0[s].w);
      u[4] = cvt_bf16(b1[s].x); u[5] = cvt_bf16(b1[s].y);
      u[6] = cvt_bf16(b1[s].z); u[7] = cvt_bf16(b1[s].w);
      *(bf16x8*)&Bs[(s * 64 + wave * 16 + srow) * 32 + scol] = u;
    }
    __syncthreads();

    bf16x8 af[4], bfr[4];
#pragma unroll
    for (int i = 0; i < 4; ++i)
      af[i] = *(const bf16x8*)&As[(wm + i * 16 + (lane & 15)) * 32 + (lane >> 4) * 8];
#pragma unroll
    for (int j = 0; j < 4; ++j)
      bfr[j] = *(const bf16x8*)&Bs[(wn + j * 16 + (lane & 15)) * 32 + (lane >> 4) * 8];

#pragma unroll
    for (int i = 0; i < 4; ++i)
#pragma unroll
      for (int j = 0; j < 4; ++j)
        acc[i][j] = __builtin_amdgcn_mfma_f32_16x16x32_bf16(af[i], bfr[j], acc[i][j], 0, 0, 0);
  }

  // C/D layout (m89-verified): col = lane&15, row = (lane>>4)*4 + reg
#pragma unroll
  for (int i = 0; i < 4; ++i) {
#pragma unroll
    for (int j = 0; j < 4; ++j) {
#pragma unroll
      for (int r = 0; r < 4; ++r) {
        int gm = tile_m + wm + i * 16 + (lane >> 4) * 4 + r;
        int gn = tile_n + wn + j * 16 + (lane & 15);
        if (gn < N) {
          float val = acc[i][j][r];
          if (MODE == 3 || MODE == 5) {
            float bv = bias ? bias[gn] : 0.f;
            val = 1.f / (1.f + __expf(-(val + bv)));
          }
          if (MODE == 4)      Cf[(size_t)gm * N + gn] = val;
          else if (MODE == 5) Cf[(size_t)gn * M + gm] = val;   // transposed
          else                Cb[(size_t)gm * N + gn] = (bf16)val;
        }
      }
    }
  }
}

// Fused 4-projection GEMM: C4 = A @ [Wq;Wk;Wv;Wa]^T, logical N=4096.
__global__ __launch_bounds__(256) void mega_gemm(
    const bf16* __restrict__ Av, const float* __restrict__ Wq,
    const float* __restrict__ Wk, const float* __restrict__ Wv,
    const float* __restrict__ Wa, const float* __restrict__ ba,
    bf16* __restrict__ C4, int M, int K)
{
  __shared__ __align__(16) __bf16 As[128 * 32];
  __shared__ __align__(16) __bf16 Bs[128 * 32];

  const int tid  = threadIdx.x;
  const int lane = tid & 63;
  const int wave = tid >> 6;
  const int tile_m = blockIdx.y * 128;
  const int tile_n = blockIdx.x * 128;
  const int grp = tile_n >> 10;                 // which weight (tile fully inside)
  const int tnl = tile_n & 1023;                // local col base
  const float* Bt = (grp == 0) ? Wq : (grp == 1) ? Wk : (grp == 2) ? Wv : Wa;
  const int wm = (wave >> 1) * 64;
  const int wn = (wave & 1) * 64;

  const int srow = lane >> 2;
  const int scol = (lane & 3) * 8;

  f32x4 acc[4][4];
#pragma unroll
  for (int i = 0; i < 4; ++i)
#pragma unroll
    for (int j = 0; j < 4; ++j) acc[i][j] = {0.f, 0.f, 0.f, 0.f};

  for (int k0 = 0; k0 < K; k0 += 32) {
    float4 b0[2], b1[2];
#pragma unroll
    for (int s = 0; s < 2; ++s) {
      int brow = tnl + s * 64 + wave * 16 + srow;
      const float* bp = Bt + (size_t)brow * K + k0 + scol;
      b0[s] = *(const float4*)bp;
      b1[s] = *(const float4*)(bp + 4);
    }
    __syncthreads();
#pragma unroll
    for (int s = 0; s < 2; ++s) {
      int arow = tile_m + s * 64 + wave * 16 + srow;
      async_copy16((const __bf16*)Av + (size_t)arow * K + k0 + scol,
                   &As[(s * 64 + wave * 16 + srow) * 32 + scol]);
      bf16x8 u;
      u[0] = cvt_bf16(b0[s].x); u[1] = cvt_bf16(b0[s].y);
      u[2] = cvt_bf16(b0[s].z); u[3] = cvt_bf16(b0[s].w);
      u[4] = cvt_bf16(b1[s].x); u[5] = cvt_bf16(b1[s].y);
      u[6] = cvt_bf16(b1[s].z); u[7] = cvt_bf16(b1[s].w);
      *(bf16x8*)&Bs[(s * 64 + wave * 16 + srow) * 32 + scol] = u;
    }
    __syncthreads();

    bf16x8 af[4], bfr[4];
#pragma unroll
    for (int i = 0; i < 4; ++i)
      af[i] = *(const bf16x8*)&As[(wm + i * 16 + (lane & 15)) * 32 + (lane >> 4) * 8];
#pragma unroll
    for (int j = 0; j < 4; ++j)
      bfr[j] = *(const bf16x8*)&Bs[(wn + j * 16 + (lane & 15)) * 32 + (lane >> 4) * 8];

#pragma unroll
    for (int i = 0; i < 4; ++i)
#pragma unroll
      for (int j = 0; j < 4; ++j)
        acc[i][j] = __builtin_amdgcn_mfma_f32_16x16x32_bf16(af[i], bfr[j], acc[i][j], 0, 0, 0);
  }

  bf16* Cp = (bf16*)((__bf16*)C4 + (size_t)grp * M * 1024);
#pragma unroll
  for (int i = 0; i < 4; ++i) {
#pragma unroll
    for (int j = 0; j < 4; ++j) {
#pragma unroll
      for (int r = 0; r < 4; ++r) {
        int gm = tile_m + wm + i * 16 + (lane >> 4) * 4 + r;
        int col = tnl + wn + j * 16 + (lane & 15);
        float val = acc[i][j][r];
        if (grp == 3) val = 1.f / (1.f + __expf(-(val + ba[col])));
        ((__bf16*)Cp)[(size_t)gm * 1024 + col] = cvt_bf16(val);
      }
    }
  }
}

// causal depthwise conv K=4 + bias + SiLU (+scale), x8 vectorized.
__global__ __launch_bounds__(256) void conv_silu_kernel(
    const bf16* __restrict__ z, const float* __restrict__ w,
    const float* __restrict__ bias, bf16* __restrict__ out, float scale)
{
  int idx = blockIdx.x * 256 + threadIdx.x;   // 512K threads
  int c8 = idx & 127;
  int m  = idx >> 7;
  int t  = m & 2047;
  int c0 = c8 * 8;

  const __bf16* base = (const __bf16*)z + (size_t)m * 1024 + c0;
  const bf16x8 zzero = __builtin_bit_cast(bf16x8, (u32x4){0u, 0u, 0u, 0u});
  bf16x8 z3 = *(const bf16x8*)base;
  bf16x8 z2 = (t >= 1) ? *(const bf16x8*)(base - 1024) : zzero;
  bf16x8 z1 = (t >= 2) ? *(const bf16x8*)(base - 2048) : zzero;
  bf16x8 z0 = (t >= 3) ? *(const bf16x8*)(base - 3072) : zzero;

  const float* wp = w + c0 * 4;     // [ch][tap], 32 contiguous floats
  bf16x8 res;
#pragma unroll
  for (int e = 0; e < 8; ++e) {
    float4 we = *(const float4*)(wp + e * 4);
    float acc = bias[c0 + e] + (float)z3[e] * we.w;
    acc += (float)z2[e] * we.z;
    acc += (float)z1[e] * we.y;
    acc += (float)z0[e] * we.x;
    float s = acc / (1.f + __expf(-acc));
    res[e] = cvt_bf16(s * scale);
  }
  *(bf16x8*)((__bf16*)out + (size_t)m * 1024 + c0) = res;
}

// G[h][b*2048+t] = beta[h][b*2048+t] * (k_{t-1} . k_t) over DK=64 (0 at t=0).
__global__ __launch_bounds__(256) void kk_kernel(
    const bf16* __restrict__ k, const float* __restrict__ betab,
    float* __restrict__ G)
{
  int tid = blockIdx.x * 256 + threadIdx.x;
  int out = tid >> 2;            // h*4096 + m, m = b*2048+t
  int j   = tid & 3;
  int h = out >> 12;
  int m = out & 4095;
  int t = m & 2047;
  float s = 0.f;
  if (t > 0) {
    const __bf16* r1 = (const __bf16*)k + (size_t)m * 1024 + h * 64 + j * 16;
    const __bf16* r0 = r1 - 1024;
    bf16x8 a0 = *(const bf16x8*)r0;
    bf16x8 a1 = *(const bf16x8*)(r0 + 8);
    bf16x8 b0 = *(const bf16x8*)r1;
    bf16x8 b1 = *(const bf16x8*)(r1 + 8);
#pragma unroll
    for (int e = 0; e < 8; ++e)
      s += (float)a0[e] * (float)b0[e] + (float)a1[e] * (float)b1[e];
  }
  s += __shfl_xor(s, 1);
  s += __shfl_xor(s, 2);
  if (j == 0) G[out] = betab[out] * s;
}

// One scan step (constant word indices only).
#define SCAN_STEP(i, KN0, KN1, Q0, Q1, WV, WA, BT, GT, LAST)                  \
  {                                                                           \
    const float vr = ((i) & 1) ? bcf((WV) & 0xffff0000u) : bcf((WV) << 16);   \
    const float ar = ((i) & 1) ? bcf((WA) & 0xffff0000u) : bcf((WA) << 16);   \
    float unxt = 0.f;                                                         \
    f32x2 k2n0 = {0.f, 0.f}, k2n1 = {0.f, 0.f};                               \
    if (!(LAST)) {                                                            \
      k2n0 = unpk(KN0); k2n1 = unpk(KN1);                                     \
      f32x2 dd = S20 * k2n0; dd += S21 * k2n1;                                \
      unxt = dd[0] + dd[1];                                                   \
      unxt += dpp_f<0xB1>(unxt);  unxt += dpp_f<0x4E>(unxt);                  \
      unxt += dpp_f<0x141>(unxt); unxt += dpp_f<0x140>(unxt);                 \
    } else { Sold0 = S20; Sold1 = S21; }                                      \
    float A_ = (BT) * __builtin_fmaf(aprev, u, -vr);                          \
    cc = __builtin_fmaf(-cc, (GT), A_);                                       \
    f32x2 q20 = unpk(Q0), q21 = unpk(Q1);                                     \
    const f32x2 cc2 = {cc, cc}, arv = {ar, ar};                               \
    f32x2 oo;                                                                 \
    { f32x2 t0 = cc2 * k2c0; S20 = arv * S20 - t0; oo = S20 * q20;            \
      f32x2 t1 = cc2 * k2c1; S21 = arv * S21 - t1; oo += S21 * q21; }         \
    so[(i)][lane] = oo[0] + oo[1];                                            \
    aprev = ar;                                                               \
    if (!(LAST)) { k2c0 = k2n0; k2c1 = k2n1; u = unxt; }                      \
  }

// Load one 2-step group (g = 0..7) into a named set (14 regs).
#define LOADG(KS, QS, VS, AS, BS, GS, g)                                      \
  KS = *(const u32x4*)&skT[buf][sg][(g) * 8];                                 \
  QS = *(const u32x4*)&sqT[buf][sg][(g) * 8];                                 \
  VS = *(const unsigned int*)&svaT[buf][0][r4][(g) * 2];                      \
  AS = *(const unsigned int*)&svaT[buf][1][r4][(g) * 2];                      \
  BS = *(const f32x2*)&sbeta[c * 16 + (g) * 2];                               \
  GS = *(const f32x2*)&sG[c * 16 + (g) * 2];

// FUSED kernel: blocks 0..511 = delta-rule scan (single wave; threads>=64
// exit; NO barriers -- LDS is in-order within a wave). Blocks 512..767 =
// g-GEMM: sigmoid(x @ Wg^T) -> gout (fp32 A path; 128x128 tiles, (8,32)).
// The GEMM rides in the scan's idle wave slots / MFMA pipes (m114).
__global__ __launch_bounds__(256) void scan_gemm_kernel(
    const bf16* __restrict__ q, const bf16* __restrict__ k,
    const bf16* __restrict__ v, const bf16* __restrict__ a,
    const float* __restrict__ betab, const float* __restrict__ gkk,
    bf16* __restrict__ o,
    const float* __restrict__ x, const float* __restrict__ Wg,
    bf16* __restrict__ gout)
{
  __shared__ __align__(16) __bf16 skT[2][16][72];    // scan: 4608 B
  __shared__ __align__(16) __bf16 sqT[2][16][72];    // scan: 4608 B
  __shared__ __align__(16) __bf16 svaT[2][2][4][16]; // scan: 512 B
  __shared__ __align__(16) float  so[16][68];        // scan: 4352 B
  __shared__ __align__(16) __bf16 so2[16][4];        // scan
  __shared__ float sbeta[2048];                      // scan: 8 KB
  __shared__ float sG[2048];                         // scan: 8 KB
  __shared__ __align__(16) __bf16 As[128 * 32];      // gemm: 8 KB
  __shared__ __align__(16) __bf16 Bs[128 * 32];      // gemm: 8 KB

  if (blockIdx.x >= 512) {
    // ---------------- g-GEMM path (all 256 threads) ----------------
    const int gb   = blockIdx.x - 512;
    const int tid  = threadIdx.x;
    const int lane = tid & 63;
    const int wave = tid >> 6;
    const int tile_m = (gb >> 3) * 128;
    const int tile_n = (gb & 7) * 128;
    const int wm = (wave >> 1) * 64;
    const int wn = (wave & 1) * 64;
    const int srow = lane >> 2;
    const int scol = (lane & 3) * 8;

    f32x4 acc[4][4];
#pragma unroll
    for (int i = 0; i < 4; ++i)
#pragma unroll
      for (int j = 0; j < 4; ++j) acc[i][j] = {0.f, 0.f, 0.f, 0.f};

    for (int k0 = 0; k0 < 1024; k0 += 32) {
      float4 b0[2], b1[2], a0[2], a1[2];
#pragma unroll
      for (int s = 0; s < 2; ++s) {
        int brow = tile_n + s * 64 + wave * 16 + srow;
        const float* bp = Wg + (size_t)brow * 1024 + k0 + scol;
        b0[s] = *(const float4*)bp;
        b1[s] = *(const float4*)(bp + 4);
        int arow = tile_m + s * 64 + wave * 16 + srow;
        const float* ap = x + (size_t)arow * 1024 + k0 + scol;
        a0[s] = *(const float4*)ap;
        a1[s] = *(const float4*)(ap + 4);
      }
      __syncthreads();
#pragma unroll
      for (int s = 0; s < 2; ++s) {
        bf16x8 ua;
        ua[0] = cvt_bf16(a0[s].x); ua[1] = cvt_bf16(a0[s].y);
        ua[2] = cvt_bf16(a0[s].z); ua[3] = cvt_bf16(a0[s].w);
        ua[4] = cvt_bf16(a1[s].x); ua[5] = cvt_bf16(a1[s].y);
        ua[6] = cvt_bf16(a1[s].z); ua[7] = cvt_bf16(a1[s].w);
        *(bf16x8*)&As[(s * 64 + wave * 16 + srow) * 32 + scol] = ua;
        bf16x8 ub;
        ub[0] = cvt_bf16(b0[s].x); ub[1] = cvt_bf16(b0[s].y);
        ub[2] = cvt_bf16(b0[s].z); ub[3] = cvt_bf16(b0[s].w);
        ub[4] = cvt_bf16(b1[s].x); ub[5] = cvt_bf16(b1[s].y);
        ub[6] = cvt_bf16(b1[s].z); ub[7] = cvt_bf16(b1[s].w);
        *(bf16x8*)&Bs[(s * 64 + wave * 16 + srow) * 32 + scol] = ub;
      }
      __syncthreads();

      bf16x8 af[4], bfr[4];
#pragma unroll
      for (int i = 0; i < 4; ++i)
        af[i] = *(const bf16x8*)&As[(wm + i * 16 + (lane & 15)) * 32 + (lane >> 4) * 8];
#pragma unroll
      for (int j = 0; j < 4; ++j)
        bfr[j] = *(const bf16x8*)&Bs[(wn + j * 16 + (lane & 15)) * 32 + (lane >> 4) * 8];

#pragma unroll
      for (int i = 0; i < 4; ++i)
#pragma unroll
        for (int j = 0; j < 4; ++j)
          acc[i][j] = __builtin_amdgcn_mfma_f32_16x16x32_bf16(af[i], bfr[j], acc[i][j], 0, 0, 0);
    }

#pragma unroll
    for (int i = 0; i < 4; ++i)
#pragma unroll
      for (int j = 0; j < 4; ++j)
#pragma unroll
        for (int r = 0; r < 4; ++r) {
          int gm = tile_m + wm + i * 16 + (lane >> 4) * 4 + r;
          int gn = tile_n + wn + j * 16 + (lane & 15);
          float val = 1.f / (1.f + __expf(-acc[i][j][r]));
          gout[(size_t)gm * 1024 + gn] = (bf16)val;
        }
    return;
  }

  // ---------------- scan path (single wave; extra waves exit) ----------------
  if (threadIdx.x >= 64) return;

  const int blk = blockIdx.x;
  const int qd = blk >> 5;           // DV slice 0..15 (4 rows each)
  const int bh = blk & 31;
  const int b = bh >> 4, h = bh & 15;
  const int lane = threadIdx.x;      // single wave
  const int r4 = lane >> 4;          // local row 0..3
  const int sg = lane & 15;

  {
    const float* bp = betab + (size_t)h * 4096 + b * 2048;
    const float* gp = gkk   + (size_t)h * 4096 + b * 2048;
    for (int t = lane; t < 2048; t += 64) { sbeta[t] = bp[t]; sG[t] = gp[t]; }
  }

  const size_t bkq = (size_t)b * 2048 * 1024 + h * 64;   // k/q plane base
  const size_t bva = bkq + qd * 4;                       // v/a/o slice base
  const __bf16* kp = (const __bf16*)k;
  const __bf16* qp = (const __bf16*)q;

  const int g_st = lane >> 3;          // staging step-in-group 0..7
  const int g_cg = (lane & 7) * 8;     // staging col (bf16 units)
  const int sgp  = (lane & 7) * 2;     // sg-slice pair base for commit
  const int va_vh = (lane >> 4) & 1;   // lanes 0-15: v, 16-31: a
  const int va_st = lane & 15;

  bf16x8 pk0, pk1, pq0, pq1;
  bf16x4v pva;
  auto fetch = [&](int t0) {
    int st0 = t0 + g_st, st1 = t0 + 8 + g_st;
    pk0 = *(const bf16x8*)(kp + bkq + (size_t)st0 * 1024 + g_cg);
    pk1 = *(const bf16x8*)(kp + bkq + (size_t)st1 * 1024 + g_cg);
    pq0 = *(const bf16x8*)(qp + bkq + (size_t)st0 * 1024 + g_cg);
    pq1 = *(const bf16x8*)(qp + bkq + (size_t)st1 * 1024 + g_cg);
    if (lane < 32) {
      const __bf16* src = va_vh ? (const __bf16*)a : (const __bf16*)v;
      pva = *(const bf16x4v*)(src + bva + (size_t)(t0 + va_st) * 1024);
    }
  };
  auto commit = [&](int cb) {
    {
      u32x4 wk = __builtin_bit_cast(u32x4, pk0);
      u32x4 wq = __builtin_bit_cast(u32x4, pq0);
      u32x2 lo, hi;
      lo[0] = wk[0]; lo[1] = wk[1]; hi[0] = wk[2]; hi[1] = wk[3];
      *(u32x2*)&skT[cb][sgp][g_st * 4]     = lo;
      *(u32x2*)&skT[cb][sgp + 1][g_st * 4] = hi;
      lo[0] = wq[0]; lo[1] = wq[1]; hi[0] = wq[2]; hi[1] = wq[3];
      *(u32x2*)&sqT[cb][sgp][g_st * 4]     = lo;
      *(u32x2*)&sqT[cb][sgp + 1][g_st * 4] = hi;
    }
    {
      u32x4 wk = __builtin_bit_cast(u32x4, pk1);
      u32x4 wq = __builtin_bit_cast(u32x4, pq1);
      u32x2 lo, hi;
      lo[0] = wk[0]; lo[1] = wk[1]; hi[0] = wk[2]; hi[1] = wk[3];
      *(u32x2*)&skT[cb][sgp][(8 + g_st) * 4]     = lo;
      *(u32x2*)&skT[cb][sgp + 1][(8 + g_st) * 4] = hi;
      lo[0] = wq[0]; lo[1] = wq[1]; hi[0] = wq[2]; hi[1] = wq[3];
      *(u32x2*)&sqT[cb][sgp][(8 + g_st) * 4]     = lo;
      *(u32x2*)&sqT[cb][sgp + 1][(8 + g_st) * 4] = hi;
    }
    if (lane < 32) {
#pragma unroll
      for (int r = 0; r < 4; ++r) svaT[cb][va_vh][r][va_st] = pva[r];
    }
  };

  fetch(0); commit(0);

  f32x2 S20 = {0.f, 0.f}, S21 = {0.f, 0.f};
  f32x2 Sold0 = {0.f, 0.f}, Sold1 = {0.f, 0.f};
  float u = 0.f, cc = 0.f, aprev = 0.f;

  auto unpk = [&](unsigned int w) -> f32x2 {
    f32x2 r; r[0] = bcf(w << 16); r[1] = bcf(w & 0xffff0000u); return r;
  };

  for (int c = 0; c < 128; ++c) {
    const int buf = c & 1;
    const bool hasNext = (c + 1 < 128);

    if (hasNext) fetch((c + 1) * 16);   // VMEM issued first

    // ---- 3-set pipeline over eight 2-step groups ----
    u32x4 kA, qA, kB, qB, kC, qC;
    unsigned int vA, aA, vB, aB, vC, aC;
    f32x2 bA, gA, bB, gB, bC, gC;

    LOADG(kA, qA, vA, aA, bA, gA, 0)
    LOADG(kB, qB, vB, aB, bB, gB, 1)
    LOADG(kC, qC, vC, aC, bC, gC, 2)

    // chunk preamble: u for step 0 = Sold . k_0
    f32x2 k2c0 = unpk(kA[0]);
    f32x2 k2c1 = unpk(kA[1]);
    {
      f32x2 dd = Sold0 * k2c0;
      dd += Sold1 * k2c1;
      float un = dd[0] + dd[1];
      un += dpp_f<0xB1>(un);
      un += dpp_f<0x4E>(un);
      un += dpp_f<0x141>(un);
      un += dpp_f<0x140>(un);
      u = un;   // c==0: Sold=0 -> u=0, correct
    }

    SCAN_STEP(0,  kA[2], kA[3], qA[0], qA[1], vA, aA, bA[0], gA[0], false)
    SCAN_STEP(1,  kB[0], kB[1], qA[2], qA[3], vA, aA, bA[1], gA[1], false)
    LOADG(kA, qA, vA, aA, bA, gA, 3)
    SCAN_STEP(2,  kB[2], kB[3], qB[0], qB[1], vB, aB, bB[0], gB[0], false)
    SCAN_STEP(3,  kC[0], kC[1], qB[2], qB[3], vB, aB, bB[1], gB[1], false)
    LOADG(kB, qB, vB, aB, bB, gB, 4)
    SCAN_STEP(4,  kC[2], kC[3], qC[0], qC[1], vC, aC, bC[0], gC[0], false)
    SCAN_STEP(5,  kA[0], kA[1], qC[2], qC[3], vC, aC, bC[1], gC[1], false)  // kA = g3
    LOADG(kC, qC, vC, aC, bC, gC, 5)
    SCAN_STEP(6,  kA[2], kA[3], qA[0], qA[1], vA, aA, bA[0], gA[0], false)  // g3
    SCAN_STEP(7,  kB[0], kB[1], qA[2], qA[3], vA, aA, bA[1], gA[1], false)  // kB = g4
    LOADG(kA, qA, vA, aA, bA, gA, 6)
    SCAN_STEP(8,  kB[2], kB[3], qB[0], qB[1], vB, aB, bB[0], gB[0], false)  // g4
    SCAN_STEP(9,  kC[0], kC[1], qB[2], qB[3], vB, aB, bB[1], gB[1], false)  // kC = g5
    LOADG(kB, qB, vB, aB, bB, gB, 7)
    SCAN_STEP(10, kC[2], kC[3], qC[0], qC[1], vC, aC, bC[0], gC[0], false)  // g5
    SCAN_STEP(11, kA[0], kA[1], qC[2], qC[3], vC, aC, bC[1], gC[1], false)  // kA = g6
    SCAN_STEP(12, kA[2], kA[3], qA[0], qA[1], vA, aA, bA[0], gA[0], false)  // g6
    SCAN_STEP(13, kB[0], kB[1], qA[2], qA[3], vA, aA, bA[1], gA[1], false)  // kB = g7
    SCAN_STEP(14, kB[2], kB[3], qB[0], qB[1], vB, aB, bB[0], gB[0], false)  // g7
    SCAN_STEP(15, kB[2], kB[3], qB[2], qB[3], vB, aB, bB[1], gB[1], true)   // LAST

    // deferred output reduction + coalesced store (single wave: ds-ordered)
    {
      int st = lane >> 2, rr = lane & 3;      // 64 outputs: 16 steps x 4 rows
      float4 A0 = *(const float4*)&so[st][rr * 16];
      float4 A1 = *(const float4*)&so[st][rr * 16 + 4];
      float4 A2 = *(const float4*)&so[st][rr * 16 + 8];
      float4 A3 = *(const float4*)&so[st][rr * 16 + 12];
      float s = (((A0.x + A0.y) + (A0.z + A0.w)) + ((A1.x + A1.y) + (A1.z + A1.w)))
              + (((A2.x + A2.y) + (A2.z + A2.w)) + ((A3.x + A3.y) + (A3.z + A3.w)));
      so2[st][rr] = cvt_bf16(s);
    }
    if (lane < 16)
      *(bf16x4v*)((__bf16*)o + bva + (size_t)(c * 16 + lane) * 1024) =
          *(const bf16x4v*)&so2[lane][0];

    if (hasNext) commit(buf ^ 1);
  }
}

// LayerNorm over DV=64 per (b,t,h) row, *ln_w+ln_b, *gate -> bf16
__global__ __launch_bounds__(256) void ln_gate_kernel(
    const bf16* __restrict__ o, const bf16* __restrict__ g,
    const float* __restrict__ lnw, const float* __restrict__ lnb,
    bf16* __restrict__ out)
{
  int row = blockIdx.x * 4 + (threadIdx.x >> 6);
  int lane = threadIdx.x & 63;
  size_t idx = (size_t)row * 64 + lane;
  float xv = (float)o[idx];
  float mu = xv;
#pragma unroll
  for (int s = 1; s < 64; s <<= 1) mu += __shfl_xor(mu, s);
  mu *= (1.f / 64.f);
  float d = xv - mu;
  float vv = d * d;
#pragma unroll
  for (int s = 1; s < 64; s <<= 1) vv += __shfl_xor(vv, s);
  vv *= (1.f / 64.f);
  float y = d * rsqrtf(vv + 1e-5f) * lnw[lane] + lnb[lane];
  y *= (float)g[idx];
  out[idx] = (bf16)y;
}

extern "C" void kernel_launch(void* const* d_in, const int* in_sizes, int n_in,
                              void* d_out, int out_size, void* d_ws, size_t ws_size,
                              hipStream_t stream)
{
  const float* x   = (const float*)d_in[0];
  const float* Wq  = (const float*)d_in[1];
  const float* Wk  = (const float*)d_in[2];
  const float* Wv  = (const float*)d_in[3];
  const float* Wa  = (const float*)d_in[4];
  const float* ba  = (const float*)d_in[5];
  const float* Wb  = (const float*)d_in[6];
  const float* bb  = (const float*)d_in[7];
  const float* Wg  = (const float*)d_in[8];
  const float* Wo  = (const float*)d_in[9];
  const float* qcw = (const float*)d_in[10];
  const float* qcb = (const float*)d_in[11];
  const float* kcw = (const float*)d_in[12];
  const float* kcb = (const float*)d_in[13];
  const float* vcw = (const float*)d_in[14];
  const float* vcb = (const float*)d_in[15];
  const float* lnw = (const float*)d_in[16];
  const float* lnb = (const float*)d_in[17];

  const int M = 4096, HID = 1024;
  const size_t PLANE = (size_t)M * HID;
  const size_t PB = PLANE * sizeof(bf16);          // 8 MB bf16 plane

  char* ws = (char*)d_ws;
  float* outf  = (float*)d_out;
  float* betab = outf;                               // [0,256K)
  float* gkk   = (float*)((char*)d_out + 256 * 1024);// [256K,512K)
  bf16*  ob    = (bf16*)((char*)d_out + 8 * 1024 * 1024); // [8M,16M)

  const bool rich = (ws_size >= 5 * PB + 1024);

  dim3 blk(256);
  dim3 g8(8, 32);
  int nconv = (int)((size_t)M * 128 / 256);          // x8-vectorized conv grid

  if (rich) {
    bf16* P0 = (bf16*)(ws);
    bf16* P1 = (bf16*)(ws + PB);
    bf16* P2 = (bf16*)(ws + 2 * PB);
    bf16* P3 = (bf16*)(ws + 3 * PB);
    bf16* P4 = (bf16*)(ws + 4 * PB);
    bf16* xb = (bf16*)d_out;                         // [0,8M), dead before betab

    cvt_plane_kernel<<<(int)(PLANE / 1024), blk, 0, stream>>>(x, xb);
    // zq->P0, zk->P1, zv->P2, a(sigmoid+ba)->P3
    mega_gemm<<<dim3(32, 32), blk, 0, stream>>>(xb, Wq, Wk, Wv, Wa, ba, P0, M, HID);
    conv_silu_kernel<<<nconv, blk, 0, stream>>>(P0, qcw, qcb, P4, 1.f);     // q->P4
    conv_silu_kernel<<<nconv, blk, 0, stream>>>(P1, kcw, kcb, P0, 0.125f);  // k->P0
    conv_silu_kernel<<<nconv, blk, 0, stream>>>(P2, vcw, vcb, P1, 1.f);     // v->P1
    gemm_bt<5, false><<<dim3(1, 32), blk, 0, stream>>>(xb, Wb, bb, betab, nullptr, M, 16, HID);
    kk_kernel<<<1024, blk, 0, stream>>>(P0, betab, gkk);
    // FUSED: scan (blocks 0..511) + g = sigmoid(x@Wg^T) -> P2 (blocks 512..767)
    scan_gemm_kernel<<<768, blk, 0, stream>>>(P4, P0, P1, P3, betab, gkk, ob,
                                              x, Wg, P2);
    ln_gate_kernel<<<M * 16 / 4, blk, 0, stream>>>(ob, P2, lnw, lnb, P3);   // ->P3
    gemm_bt<4, false><<<g8, blk, 0, stream>>>(P3, Wo, nullptr, outf, nullptr, M, HID, HID);
  } else {
    bf16* P  = (bf16*)(ws);
    bf16* qb = (bf16*)(ws + PB);
    bf16* kb = (bf16*)(ws + 2 * PB);
    bf16* vb = (bf16*)(ws + 3 * PB);

    gemm_bt<2, true><<<g8, blk, 0, stream>>>(x, Wq, nullptr, nullptr, P, M, HID, HID);
    conv_silu_kernel<<<nconv, blk, 0, stream>>>(P, qcw, qcb, qb, 1.f);
    gemm_bt<2, true><<<g8, blk, 0, stream>>>(x, Wk, nullptr, nullptr, P, M, HID, HID);
    conv_silu_kernel<<<nconv, blk, 0, stream>>>(P, kcw, kcb, kb, 0.125f);
    gemm_bt<2, true><<<g8, blk, 0, stream>>>(x, Wv, nullptr, nullptr, P, M, HID, HID);
    conv_silu_kernel<<<nconv, blk, 0, stream>>>(P, vcw, vcb, vb, 1.f);
    gemm_bt<3, true><<<g8, blk, 0, stream>>>(x, Wa, ba, nullptr, P, M, HID, HID);
    gemm_bt<5, true><<<dim3(1, 32), blk, 0, stream>>>(x, Wb, bb, betab, nullptr, M, 16, HID);
    kk_kernel<<<1024, blk, 0, stream>>>(kb, betab, gkk);
    scan_gemm_kernel<<<512, blk, 0, stream>>>(qb, kb, vb, P, betab, gkk, ob,
                                              x, Wg, nullptr);
    gemm_bt<3, true><<<g8, blk, 0, stream>>>(x, Wg, nullptr, nullptr, qb, M, HID, HID);
    ln_gate_kernel<<<M * 16 / 4, blk, 0, stream>>>(ob, qb, lnw, lnb, kb);
    gemm_bt<4, false><<<g8, blk, 0, stream>>>(kb, Wo, nullptr, outf, nullptr, M, HID, HID);
  }
}

// Round 10
// 469.722 us; speedup vs baseline: 1.4869x; 1.0871x over previous
//
#include <hip/hip_runtime.h>
#include <hip/hip_bf16.h>
#include <cstdint>

// B=2, T=2048, HID=1024, H=16, DK=DV=64, K(conv)=4. fp32 in/out.
// RICH memory plan (ws >= 40MB): ws = P0..P4 (8MB bf16 planes).
//  d_out[0,8M): xb (bf16 x), dead after mega_gemm2 -> then k-plane (conv out)
//  d_out[8M,16M): W4b (bf16 Wq|Wk|Wv|Wa), dead after mega_gemm2 -> q-plane
//  P4[0,256K): betab fp32; P4[256K,512K): gkk fp32  (fixes old xb/betab alias race)
//  P0: zq -> (conv_q reads) -> scan output o
//  P1: zk -> (conv_k reads) -> v-plane (conv_v out) -> ln_gate out
//  P2: zv -> (conv_v reads) -> g-plane (fused g-GEMM out)
//  P3: a (sigmoid) plane, live until scan
// Launches (9): cvtw -> mega_gemm2(+beta fused) -> conv q -> conv k -> conv v
//   -> kk -> FUSED scan+g-GEMM -> ln_gate -> final GEMM.
//
// mega_gemm2: A AND B both bf16 via global_load_lds width-16 (m97 ladder:
// the fp32->bf16 in-loop weight conversion was the VALU staging tax; weights
// are read 32x so converting once amortizes). Beta-GEMM rides as 32 extra
// blocks (blockIdx.x==32) instead of a separate latency-bound launch.
// Scan: R9-proven fused form, untouched.

using bf16 = __hip_bfloat16;
typedef __bf16 bf16x8 __attribute__((ext_vector_type(8)));
typedef __bf16 bf16x4v __attribute__((ext_vector_type(4)));
typedef float f32x4 __attribute__((ext_vector_type(4)));
typedef float f32x2 __attribute__((ext_vector_type(2)));
typedef unsigned int u32x4 __attribute__((ext_vector_type(4)));
typedef unsigned int u32x2 __attribute__((ext_vector_type(2)));

__device__ __forceinline__ __bf16 cvt_bf16(float f) {
  __hip_bfloat16 h = (__hip_bfloat16)f;
  return *reinterpret_cast<__bf16*>(&h);
}
__device__ __forceinline__ void async_copy16(const void* g, void* l) {
  __builtin_amdgcn_global_load_lds((const __attribute__((address_space(1))) void*)g,
                                   (__attribute__((address_space(3))) void*)l,
                                   16, 0, 0);
}
__device__ __forceinline__ float bcf(unsigned int u) { return __builtin_bit_cast(float, u); }
template <int CTRL>
__device__ __forceinline__ float dpp_f(float x) {
  int y = __builtin_amdgcn_update_dpp(0, __builtin_bit_cast(int, x), CTRL, 0xF, 0xF, true);
  return __builtin_bit_cast(float, y);
}

// fp32 -> bf16: x plane (blocks 0..4095) + 4 weight planes (blocks 4096..8191)
__global__ __launch_bounds__(256) void cvtw_kernel(
    const float* __restrict__ x, const float* __restrict__ Wq,
    const float* __restrict__ Wk, const float* __restrict__ Wv,
    const float* __restrict__ Wa, bf16* __restrict__ xb, bf16* __restrict__ w4b)
{
  int blk = blockIdx.x;
  const float* src;
  __bf16* dst;
  size_t off;
  if (blk < 4096) {
    src = x; dst = (__bf16*)xb;
    off = (size_t)blk * 1024 + threadIdx.x * 4;
  } else {
    int wb = blk - 4096;
    int wi = wb >> 10;
    src = (wi == 0) ? Wq : (wi == 1) ? Wk : (wi == 2) ? Wv : Wa;
    dst = (__bf16*)w4b + (size_t)wi * 1024 * 1024;
    off = (size_t)(wb & 1023) * 1024 + threadIdx.x * 4;
  }
  float4 f = *(const float4*)(src + off);
  bf16x4v t;
  t[0] = cvt_bf16(f.x); t[1] = cvt_bf16(f.y); t[2] = cvt_bf16(f.z); t[3] = cvt_bf16(f.w);
  *(bf16x4v*)(dst + off) = t;
}

// C = A * Bt^T. A: MxK (bf16 async-staged unless A_FP32); Bt: NxK fp32.
// MODE 2: raw->bf16; 3: sigmoid(acc+bias)->bf16; 4: raw->fp32; 5: sigmoid(acc+bias)->fp32 TRANSPOSED
template <int MODE, bool A_FP32>
__global__ __launch_bounds__(256) void gemm_bt(
    const void* __restrict__ Av, const float* __restrict__ Bt,
    const float* __restrict__ bias, float* __restrict__ Cf, bf16* __restrict__ Cb,
    int M, int N, int K)
{
  __shared__ __align__(16) __bf16 As[128 * 32];
  __shared__ __align__(16) __bf16 Bs[128 * 32];

  const int tid  = threadIdx.x;
  const int lane = tid & 63;
  const int wave = tid >> 6;
  const int tile_m = blockIdx.y * 128;
  const int tile_n = blockIdx.x * 128;
  const int wm = (wave >> 1) * 64;
  const int wn = (wave & 1) * 64;

  const int srow = lane >> 2;
  const int scol = (lane & 3) * 8;

  f32x4 acc[4][4];
#pragma unroll
  for (int i = 0; i < 4; ++i)
#pragma unroll
    for (int j = 0; j < 4; ++j) acc[i][j] = {0.f, 0.f, 0.f, 0.f};

  for (int k0 = 0; k0 < K; k0 += 32) {
    float4 b0[2], b1[2], a0[2], a1[2];
#pragma unroll
    for (int s = 0; s < 2; ++s) {
      int brow = tile_n + s * 64 + wave * 16 + srow;
      if (brow > N - 1) brow = N - 1;             // clamp (beta GEMM: N=16)
      const float* bp = Bt + (size_t)brow * K + k0 + scol;
      b0[s] = *(const float4*)bp;
      b1[s] = *(const float4*)(bp + 4);
      if (A_FP32) {
        int arow = tile_m + s * 64 + wave * 16 + srow;
        const float* ap = (const float*)Av + (size_t)arow * K + k0 + scol;
        a0[s] = *(const float4*)ap;
        a1[s] = *(const float4*)(ap + 4);
      }
    }
    __syncthreads();
#pragma unroll
    for (int s = 0; s < 2; ++s) {
      if (!A_FP32) {
        int arow = tile_m + s * 64 + wave * 16 + srow;
        async_copy16((const __bf16*)Av + (size_t)arow * K + k0 + scol,
                     &As[(s * 64 + wave * 16 + srow) * 32 + scol]);
      } else {
        bf16x8 ua;
        ua[0] = cvt_bf16(a0[s].x); ua[1] = cvt_bf16(a0[s].y);
        ua[2] = cvt_bf16(a0[s].z); ua[3] = cvt_bf16(a0[s].w);
        ua[4] = cvt_bf16(a1[s].x); ua[5] = cvt_bf16(a1[s].y);
        ua[6] = cvt_bf16(a1[s].z); ua[7] = cvt_bf16(a1[s].w);
        *(bf16x8*)&As[(s * 64 + wave * 16 + srow) * 32 + scol] = ua;
      }
      bf16x8 u;
      u[0] = cvt_bf16(b0[s].x); u[1] = cvt_bf16(b0[s].y);
      u[2] = cvt_bf16(b0[s].z); u[3] = cvt_bf16(b0[s].w);
      u[4] = cvt_bf16(b1[s].x); u[5] = cvt_bf16(b1[s].y);
      u[6] = cvt_bf16(b1[s].z); u[7] = cvt_bf16(b1[s].w);
      *(bf16x8*)&Bs[(s * 64 + wave * 16 + srow) * 32 + scol] = u;
    }
    __syncthreads();

    bf16x8 af[4], bfr[4];
#pragma unroll
    for (int i = 0; i < 4; ++i)
      af[i] = *(const bf16x8*)&As[(wm + i * 16 + (lane & 15)) * 32 + (lane >> 4) * 8];
#pragma unroll
    for (int j = 0; j < 4; ++j)
      bfr[j] = *(const bf16x8*)&Bs[(wn + j * 16 + (lane & 15)) * 32 + (lane >> 4) * 8];

#pragma unroll
    for (int i = 0; i < 4; ++i)
#pragma unroll
      for (int j = 0; j < 4; ++j)
        acc[i][j] = __builtin_amdgcn_mfma_f32_16x16x32_bf16(af[i], bfr[j], acc[i][j], 0, 0, 0);
  }

  // C/D layout (m89-verified): col = lane&15, row = (lane>>4)*4 + reg
#pragma unroll
  for (int i = 0; i < 4; ++i) {
#pragma unroll
    for (int j = 0; j < 4; ++j) {
#pragma unroll
      for (int r = 0; r < 4; ++r) {
        int gm = tile_m + wm + i * 16 + (lane >> 4) * 4 + r;
        int gn = tile_n + wn + j * 16 + (lane & 15);
        if (gn < N) {
          float val = acc[i][j][r];
          if (MODE == 3 || MODE == 5) {
            float bv = bias ? bias[gn] : 0.f;
            val = 1.f / (1.f + __expf(-(val + bv)));
          }
          if (MODE == 4)      Cf[(size_t)gm * N + gn] = val;
          else if (MODE == 5) Cf[(size_t)gn * M + gm] = val;   // transposed
          else                Cb[(size_t)gm * N + gn] = (bf16)val;
        }
      }
    }
  }
}

// Fused 4-projection + beta GEMM. Grid (33,32):
//  blockIdx.x<32: C4 plane tiles (A=xb bf16 async, B=W4b bf16 async);
//  blockIdx.x==32: beta tile (B=Wb fp32 16 rows, clamped; out: sigmoid
//  transposed betab[16][4096]).  Plane 3 (Wa): sigmoid(val + ba[col]).
__global__ __launch_bounds__(256) void mega_gemm2(
    const bf16* __restrict__ Av, const bf16* __restrict__ W4b,
    const float* __restrict__ Wb, const float* __restrict__ bb,
    const float* __restrict__ ba, bf16* __restrict__ C4,
    float* __restrict__ betab)
{
  __shared__ __align__(16) __bf16 As[128 * 32];
  __shared__ __align__(16) __bf16 Bs[128 * 32];

  const int tid  = threadIdx.x;
  const int lane = tid & 63;
  const int wave = tid >> 6;
  const int tile_m = blockIdx.y * 128;
  const bool isbeta = (blockIdx.x >= 32);
  const int tile_n = isbeta ? 0 : blockIdx.x * 128;
  const int grp = tile_n >> 10;
  const int tnl = tile_n & 1023;
  const int wm = (wave >> 1) * 64;
  const int wn = (wave & 1) * 64;

  const int srow = lane >> 2;
  const int scol = (lane & 3) * 8;

  f32x4 acc[4][4];
#pragma unroll
  for (int i = 0; i < 4; ++i)
#pragma unroll
    for (int j = 0; j < 4; ++j) acc[i][j] = {0.f, 0.f, 0.f, 0.f};

  const __bf16* Wp = (const __bf16*)W4b + (size_t)grp * 1024 * 1024;

  for (int k0 = 0; k0 < 1024; k0 += 32) {
    float4 b0[2], b1[2];
    if (isbeta) {
#pragma unroll
      for (int s = 0; s < 2; ++s) {
        int brow = s * 64 + wave * 16 + srow;
        if (brow > 15) brow = 15;
        const float* bp = Wb + (size_t)brow * 1024 + k0 + scol;
        b0[s] = *(const float4*)bp;
        b1[s] = *(const float4*)(bp + 4);
      }
    }
    __syncthreads();
#pragma unroll
    for (int s = 0; s < 2; ++s) {
      int arow = tile_m + s * 64 + wave * 16 + srow;
      async_copy16((const __bf16*)Av + (size_t)arow * 1024 + k0 + scol,
                   &As[(s * 64 + wave * 16 + srow) * 32 + scol]);
      if (!isbeta) {
        int brow = tnl + s * 64 + wave * 16 + srow;
        async_copy16(Wp + (size_t)brow * 1024 + k0 + scol,
                     &Bs[(s * 64 + wave * 16 + srow) * 32 + scol]);
      } else {
        bf16x8 u;
        u[0] = cvt_bf16(b0[s].x); u[1] = cvt_bf16(b0[s].y);
        u[2] = cvt_bf16(b0[s].z); u[3] = cvt_bf16(b0[s].w);
        u[4] = cvt_bf16(b1[s].x); u[5] = cvt_bf16(b1[s].y);
        u[6] = cvt_bf16(b1[s].z); u[7] = cvt_bf16(b1[s].w);
        *(bf16x8*)&Bs[(s * 64 + wave * 16 + srow) * 32 + scol] = u;
      }
    }
    __syncthreads();

    bf16x8 af[4], bfr[4];
#pragma unroll
    for (int i = 0; i < 4; ++i)
      af[i] = *(const bf16x8*)&As[(wm + i * 16 + (lane & 15)) * 32 + (lane >> 4) * 8];
#pragma unroll
    for (int j = 0; j < 4; ++j)
      bfr[j] = *(const bf16x8*)&Bs[(wn + j * 16 + (lane & 15)) * 32 + (lane >> 4) * 8];

#pragma unroll
    for (int i = 0; i < 4; ++i)
#pragma unroll
      for (int j = 0; j < 4; ++j)
        acc[i][j] = __builtin_amdgcn_mfma_f32_16x16x32_bf16(af[i], bfr[j], acc[i][j], 0, 0, 0);
  }

  if (!isbeta) {
    bf16* Cp = (bf16*)((__bf16*)C4 + (size_t)grp * 4096 * 1024);
#pragma unroll
    for (int i = 0; i < 4; ++i)
#pragma unroll
      for (int j = 0; j < 4; ++j)
#pragma unroll
        for (int r = 0; r < 4; ++r) {
          int gm = tile_m + wm + i * 16 + (lane >> 4) * 4 + r;
          int col = tnl + wn + j * 16 + (lane & 15);
          float val = acc[i][j][r];
          if (grp == 3) val = 1.f / (1.f + __expf(-(val + ba[col])));
          ((__bf16*)Cp)[(size_t)gm * 1024 + col] = cvt_bf16(val);
        }
  } else {
#pragma unroll
    for (int i = 0; i < 4; ++i)
#pragma unroll
      for (int j = 0; j < 4; ++j)
#pragma unroll
        for (int r = 0; r < 4; ++r) {
          int gm = tile_m + wm + i * 16 + (lane >> 4) * 4 + r;
          int gn = wn + j * 16 + (lane & 15);
          if (gn < 16) {
            float val = 1.f / (1.f + __expf(-(acc[i][j][r] + bb[gn])));
            betab[(size_t)gn * 4096 + gm] = val;
          }
        }
  }
}

// causal depthwise conv K=4 + bias + SiLU (+scale), x8 vectorized.
__global__ __launch_bounds__(256) void conv_silu_kernel(
    const bf16* __restrict__ z, const float* __restrict__ w,
    const float* __restrict__ bias, bf16* __restrict__ out, float scale)
{
  int idx = blockIdx.x * 256 + threadIdx.x;   // 512K threads
  int c8 = idx & 127;
  int m  = idx >> 7;
  int t  = m & 2047;
  int c0 = c8 * 8;

  const __bf16* base = (const __bf16*)z + (size_t)m * 1024 + c0;
  const bf16x8 zzero = __builtin_bit_cast(bf16x8, (u32x4){0u, 0u, 0u, 0u});
  bf16x8 z3 = *(const bf16x8*)base;
  bf16x8 z2 = (t >= 1) ? *(const bf16x8*)(base - 1024) : zzero;
  bf16x8 z1 = (t >= 2) ? *(const bf16x8*)(base - 2048) : zzero;
  bf16x8 z0 = (t >= 3) ? *(const bf16x8*)(base - 3072) : zzero;

  const float* wp = w + c0 * 4;     // [ch][tap], 32 contiguous floats
  bf16x8 res;
#pragma unroll
  for (int e = 0; e < 8; ++e) {
    float4 we = *(const float4*)(wp + e * 4);
    float acc = bias[c0 + e] + (float)z3[e] * we.w;
    acc += (float)z2[e] * we.z;
    acc += (float)z1[e] * we.y;
    acc += (float)z0[e] * we.x;
    float s = acc / (1.f + __expf(-acc));
    res[e] = cvt_bf16(s * scale);
  }
  *(bf16x8*)((__bf16*)out + (size_t)m * 1024 + c0) = res;
}

// G[h][b*2048+t] = beta[h][b*2048+t] * (k_{t-1} . k_t) over DK=64 (0 at t=0).
__global__ __launch_bounds__(256) void kk_kernel(
    const bf16* __restrict__ k, const float* __restrict__ betab,
    float* __restrict__ G)
{
  int tid = blockIdx.x * 256 + threadIdx.x;
  int out = tid >> 2;            // h*4096 + m, m = b*2048+t
  int j   = tid & 3;
  int h = out >> 12;
  int m = out & 4095;
  int t = m & 2047;
  float s = 0.f;
  if (t > 0) {
    const __bf16* r1 = (const __bf16*)k + (size_t)m * 1024 + h * 64 + j * 16;
    const __bf16* r0 = r1 - 1024;
    bf16x8 a0 = *(const bf16x8*)r0;
    bf16x8 a1 = *(const bf16x8*)(r0 + 8);
    bf16x8 b0 = *(const bf16x8*)r1;
    bf16x8 b1 = *(const bf16x8*)(r1 + 8);
#pragma unroll
    for (int e = 0; e < 8; ++e)
      s += (float)a0[e] * (float)b0[e] + (float)a1[e] * (float)b1[e];
  }
  s += __shfl_xor(s, 1);
  s += __shfl_xor(s, 2);
  if (j == 0) G[out] = betab[out] * s;
}

// One scan step (constant word indices only).
#define SCAN_STEP(i, KN0, KN1, Q0, Q1, WV, WA, BT, GT, LAST)                  \
  {                                                                           \
    const float vr = ((i) & 1) ? bcf((WV) & 0xffff0000u) : bcf((WV) << 16);   \
    const float ar = ((i) & 1) ? bcf((WA) & 0xffff0000u) : bcf((WA) << 16);   \
    float unxt = 0.f;                                                         \
    f32x2 k2n0 = {0.f, 0.f}, k2n1 = {0.f, 0.f};                               \
    if (!(LAST)) {                                                            \
      k2n0 = unpk(KN0); k2n1 = unpk(KN1);                                     \
      f32x2 dd = S20 * k2n0; dd += S21 * k2n1;                                \
      unxt = dd[0] + dd[1];                                                   \
      unxt += dpp_f<0xB1>(unxt);  unxt += dpp_f<0x4E>(unxt);                  \
      unxt += dpp_f<0x141>(unxt); unxt += dpp_f<0x140>(unxt);                 \
    } else { Sold0 = S20; Sold1 = S21; }                                      \
    float A_ = (BT) * __builtin_fmaf(aprev, u, -vr);                          \
    cc = __builtin_fmaf(-cc, (GT), A_);                                       \
    f32x2 q20 = unpk(Q0), q21 = unpk(Q1);                                     \
    const f32x2 cc2 = {cc, cc}, arv = {ar, ar};                               \
    f32x2 oo;                                                                 \
    { f32x2 t0 = cc2 * k2c0; S20 = arv * S20 - t0; oo = S20 * q20;            \
      f32x2 t1 = cc2 * k2c1; S21 = arv * S21 - t1; oo += S21 * q21; }         \
    so[(i)][lane] = oo[0] + oo[1];                                            \
    aprev = ar;                                                               \
    if (!(LAST)) { k2c0 = k2n0; k2c1 = k2n1; u = unxt; }                      \
  }

// Load one 2-step group (g = 0..7) into a named set (14 regs).
#define LOADG(KS, QS, VS, AS, BS, GS, g)                                      \
  KS = *(const u32x4*)&skT[buf][sg][(g) * 8];                                 \
  QS = *(const u32x4*)&sqT[buf][sg][(g) * 8];                                 \
  VS = *(const unsigned int*)&svaT[buf][0][r4][(g) * 2];                      \
  AS = *(const unsigned int*)&svaT[buf][1][r4][(g) * 2];                      \
  BS = *(const f32x2*)&sbeta[c * 16 + (g) * 2];                               \
  GS = *(const f32x2*)&sG[c * 16 + (g) * 2];

// FUSED kernel: blocks 0..511 = delta-rule scan (single wave; threads>=64
// exit; NO barriers -- LDS is in-order within a wave). Blocks 512..767 =
// g-GEMM: sigmoid(x @ Wg^T) -> gout (fp32 A path; 128x128 tiles).
__global__ __launch_bounds__(256) void scan_gemm_kernel(
    const bf16* __restrict__ q, const bf16* __restrict__ k,
    const bf16* __restrict__ v, const bf16* __restrict__ a,
    const float* __restrict__ betab, const float* __restrict__ gkk,
    bf16* __restrict__ o,
    const float* __restrict__ x, const float* __restrict__ Wg,
    bf16* __restrict__ gout)
{
  __shared__ __align__(16) __bf16 skT[2][16][72];    // scan: 4608 B
  __shared__ __align__(16) __bf16 sqT[2][16][72];    // scan: 4608 B
  __shared__ __align__(16) __bf16 svaT[2][2][4][16]; // scan: 512 B
  __shared__ __align__(16) float  so[16][68];        // scan: 4352 B
  __shared__ __align__(16) __bf16 so2[16][4];        // scan
  __shared__ float sbeta[2048];                      // scan: 8 KB
  __shared__ float sG[2048];                         // scan: 8 KB
  __shared__ __align__(16) __bf16 As[128 * 32];      // gemm: 8 KB
  __shared__ __align__(16) __bf16 Bs[128 * 32];      // gemm: 8 KB

  if (blockIdx.x >= 512) {
    // ---------------- g-GEMM path (all 256 threads) ----------------
    const int gb   = blockIdx.x - 512;
    const int tid  = threadIdx.x;
    const int lane = tid & 63;
    const int wave = tid >> 6;
    const int tile_m = (gb >> 3) * 128;
    const int tile_n = (gb & 7) * 128;
    const int wm = (wave >> 1) * 64;
    const int wn = (wave & 1) * 64;
    const int srow = lane >> 2;
    const int scol = (lane & 3) * 8;

    f32x4 acc[4][4];
#pragma unroll
    for (int i = 0; i < 4; ++i)
#pragma unroll
      for (int j = 0; j < 4; ++j) acc[i][j] = {0.f, 0.f, 0.f, 0.f};

    for (int k0 = 0; k0 < 1024; k0 += 32) {
      float4 b0[2], b1[2], a0[2], a1[2];
#pragma unroll
      for (int s = 0; s < 2; ++s) {
        int brow = tile_n + s * 64 + wave * 16 + srow;
        const float* bp = Wg + (size_t)brow * 1024 + k0 + scol;
        b0[s] = *(const float4*)bp;
        b1[s] = *(const float4*)(bp + 4);
        int arow = tile_m + s * 64 + wave * 16 + srow;
        const float* ap = x + (size_t)arow * 1024 + k0 + scol;
        a0[s] = *(const float4*)ap;
        a1[s] = *(const float4*)(ap + 4);
      }
      __syncthreads();
#pragma unroll
      for (int s = 0; s < 2; ++s) {
        bf16x8 ua;
        ua[0] = cvt_bf16(a0[s].x); ua[1] = cvt_bf16(a0[s].y);
        ua[2] = cvt_bf16(a0[s].z); ua[3] = cvt_bf16(a0[s].w);
        ua[4] = cvt_bf16(a1[s].x); ua[5] = cvt_bf16(a1[s].y);
        ua[6] = cvt_bf16(a1[s].z); ua[7] = cvt_bf16(a1[s].w);
        *(bf16x8*)&As[(s * 64 + wave * 16 + srow) * 32 + scol] = ua;
        bf16x8 ub;
        ub[0] = cvt_bf16(b0[s].x); ub[1] = cvt_bf16(b0[s].y);
        ub[2] = cvt_bf16(b0[s].z); ub[3] = cvt_bf16(b0[s].w);
        ub[4] = cvt_bf16(b1[s].x); ub[5] = cvt_bf16(b1[s].y);
        ub[6] = cvt_bf16(b1[s].z); ub[7] = cvt_bf16(b1[s].w);
        *(bf16x8*)&Bs[(s * 64 + wave * 16 + srow) * 32 + scol] = ub;
      }
      __syncthreads();

      bf16x8 af[4], bfr[4];
#pragma unroll
      for (int i = 0; i < 4; ++i)
        af[i] = *(const bf16x8*)&As[(wm + i * 16 + (lane & 15)) * 32 + (lane >> 4) * 8];
#pragma unroll
      for (int j = 0; j < 4; ++j)
        bfr[j] = *(const bf16x8*)&Bs[(wn + j * 16 + (lane & 15)) * 32 + (lane >> 4) * 8];

#pragma unroll
      for (int i = 0; i < 4; ++i)
#pragma unroll
        for (int j = 0; j < 4; ++j)
          acc[i][j] = __builtin_amdgcn_mfma_f32_16x16x32_bf16(af[i], bfr[j], acc[i][j], 0, 0, 0);
    }

#pragma unroll
    for (int i = 0; i < 4; ++i)
#pragma unroll
      for (int j = 0; j < 4; ++j)
#pragma unroll
        for (int r = 0; r < 4; ++r) {
          int gm = tile_m + wm + i * 16 + (lane >> 4) * 4 + r;
          int gn = tile_n + wn + j * 16 + (lane & 15);
          float val = 1.f / (1.f + __expf(-acc[i][j][r]));
          gout[(size_t)gm * 1024 + gn] = (bf16)val;
        }
    return;
  }

  // ---------------- scan path (single wave; extra waves exit) ----------------
  if (threadIdx.x >= 64) return;

  const int blk = blockIdx.x;
  const int qd = blk >> 5;           // DV slice 0..15 (4 rows each)
  const int bh = blk & 31;
  const int b = bh >> 4, h = bh & 15;
  const int lane = threadIdx.x;      // single wave
  const int r4 = lane >> 4;          // local row 0..3
  const int sg = lane & 15;

  {
    const float* bp = betab + (size_t)h * 4096 + b * 2048;
    const float* gp = gkk   + (size_t)h * 4096 + b * 2048;
    for (int t = lane; t < 2048; t += 64) { sbeta[t] = bp[t]; sG[t] = gp[t]; }
  }

  const size_t bkq = (size_t)b * 2048 * 1024 + h * 64;   // k/q plane base
  const size_t bva = bkq + qd * 4;                       // v/a/o slice base
  const __bf16* kp = (const __bf16*)k;
  const __bf16* qp = (const __bf16*)q;

  const int g_st = lane >> 3;          // staging step-in-group 0..7
  const int g_cg = (lane & 7) * 8;     // staging col (bf16 units)
  const int sgp  = (lane & 7) * 2;     // sg-slice pair base for commit
  const int va_vh = (lane >> 4) & 1;   // lanes 0-15: v, 16-31: a
  const int va_st = lane & 15;

  bf16x8 pk0, pk1, pq0, pq1;
  bf16x4v pva;
  auto fetch = [&](int t0) {
    int st0 = t0 + g_st, st1 = t0 + 8 + g_st;
    pk0 = *(const bf16x8*)(kp + bkq + (size_t)st0 * 1024 + g_cg);
    pk1 = *(const bf16x8*)(kp + bkq + (size_t)st1 * 1024 + g_cg);
    pq0 = *(const bf16x8*)(qp + bkq + (size_t)st0 * 1024 + g_cg);
    pq1 = *(const bf16x8*)(qp + bkq + (size_t)st1 * 1024 + g_cg);
    if (lane < 32) {
      const __bf16* src = va_vh ? (const __bf16*)a : (const __bf16*)v;
      pva = *(const bf16x4v*)(src + bva + (size_t)(t0 + va_st) * 1024);
    }
  };
  auto commit = [&](int cb) {
    {
      u32x4 wk = __builtin_bit_cast(u32x4, pk0);
      u32x4 wq = __builtin_bit_cast(u32x4, pq0);
      u32x2 lo, hi;
      lo[0] = wk[0]; lo[1] = wk[1]; hi[0] = wk[2]; hi[1] = wk[3];
      *(u32x2*)&skT[cb][sgp][g_st * 4]     = lo;
      *(u32x2*)&skT[cb][sgp + 1][g_st * 4] = hi;
      lo[0] = wq[0]; lo[1] = wq[1]; hi[0] = wq[2]; hi[1] = wq[3];
      *(u32x2*)&sqT[cb][sgp][g_st * 4]     = lo;
      *(u32x2*)&sqT[cb][sgp + 1][g_st * 4] = hi;
    }
    {
      u32x4 wk = __builtin_bit_cast(u32x4, pk1);
      u32x4 wq = __builtin_bit_cast(u32x4, pq1);
      u32x2 lo, hi;
      lo[0] = wk[0]; lo[1] = wk[1]; hi[0] = wk[2]; hi[1] = wk[3];
      *(u32x2*)&skT[cb][sgp][(8 + g_st) * 4]     = lo;
      *(u32x2*)&skT[cb][sgp + 1][(8 + g_st) * 4] = hi;
      lo[0] = wq[0]; lo[1] = wq[1]; hi[0] = wq[2]; hi[1] = wq[3];
      *(u32x2*)&sqT[cb][sgp][(8 + g_st) * 4]     = lo;
      *(u32x2*)&sqT[cb][sgp + 1][(8 + g_st) * 4] = hi;
    }
    if (lane < 32) {
#pragma unroll
      for (int r = 0; r < 4; ++r) svaT[cb][va_vh][r][va_st] = pva[r];
    }
  };

  fetch(0); commit(0);

  f32x2 S20 = {0.f, 0.f}, S21 = {0.f, 0.f};
  f32x2 Sold0 = {0.f, 0.f}, Sold1 = {0.f, 0.f};
  float u = 0.f, cc = 0.f, aprev = 0.f;

  auto unpk = [&](unsigned int w) -> f32x2 {
    f32x2 r; r[0] = bcf(w << 16); r[1] = bcf(w & 0xffff0000u); return r;
  };

  for (int c = 0; c < 128; ++c) {
    const int buf = c & 1;
    const bool hasNext = (c + 1 < 128);

    if (hasNext) fetch((c + 1) * 16);   // VMEM issued first

    // ---- 3-set pipeline over eight 2-step groups ----
    u32x4 kA, qA, kB, qB, kC, qC;
    unsigned int vA, aA, vB, aB, vC, aC;
    f32x2 bA, gA, bB, gB, bC, gC;

    LOADG(kA, qA, vA, aA, bA, gA, 0)
    LOADG(kB, qB, vB, aB, bB, gB, 1)
    LOADG(kC, qC, vC, aC, bC, gC, 2)

    // chunk preamble: u for step 0 = Sold . k_0
    f32x2 k2c0 = unpk(kA[0]);
    f32x2 k2c1 = unpk(kA[1]);
    {
      f32x2 dd = Sold0 * k2c0;
      dd += Sold1 * k2c1;
      float un = dd[0] + dd[1];
      un += dpp_f<0xB1>(un);
      un += dpp_f<0x4E>(un);
      un += dpp_f<0x141>(un);
      un += dpp_f<0x140>(un);
      u = un;   // c==0: Sold=0 -> u=0, correct
    }

    SCAN_STEP(0,  kA[2], kA[3], qA[0], qA[1], vA, aA, bA[0], gA[0], false)
    SCAN_STEP(1,  kB[0], kB[1], qA[2], qA[3], vA, aA, bA[1], gA[1], false)
    LOADG(kA, qA, vA, aA, bA, gA, 3)
    SCAN_STEP(2,  kB[2], kB[3], qB[0], qB[1], vB, aB, bB[0], gB[0], false)
    SCAN_STEP(3,  kC[0], kC[1], qB[2], qB[3], vB, aB, bB[1], gB[1], false)
    LOADG(kB, qB, vB, aB, bB, gB, 4)
    SCAN_STEP(4,  kC[2], kC[3], qC[0], qC[1], vC, aC, bC[0], gC[0], false)
    SCAN_STEP(5,  kA[0], kA[1], qC[2], qC[3], vC, aC, bC[1], gC[1], false)  // kA = g3
    LOADG(kC, qC, vC, aC, bC, gC, 5)
    SCAN_STEP(6,  kA[2], kA[3], qA[0], qA[1], vA, aA, bA[0], gA[0], false)  // g3
    SCAN_STEP(7,  kB[0], kB[1], qA[2], qA[3], vA, aA, bA[1], gA[1], false)  // kB = g4
    LOADG(kA, qA, vA, aA, bA, gA, 6)
    SCAN_STEP(8,  kB[2], kB[3], qB[0], qB[1], vB, aB, bB[0], gB[0], false)  // g4
    SCAN_STEP(9,  kC[0], kC[1], qB[2], qB[3], vB, aB, bB[1], gB[1], false)  // kC = g5
    LOADG(kB, qB, vB, aB, bB, gB, 7)
    SCAN_STEP(10, kC[2], kC[3], qC[0], qC[1], vC, aC, bC[0], gC[0], false)  // g5
    SCAN_STEP(11, kA[0], kA[1], qC[2], qC[3], vC, aC, bC[1], gC[1], false)  // kA = g6
    SCAN_STEP(12, kA[2], kA[3], qA[0], qA[1], vA, aA, bA[0], gA[0], false)  // g6
    SCAN_STEP(13, kB[0], kB[1], qA[2], qA[3], vA, aA, bA[1], gA[1], false)  // kB = g7
    SCAN_STEP(14, kB[2], kB[3], qB[0], qB[1], vB, aB, bB[0], gB[0], false)  // g7
    SCAN_STEP(15, kB[2], kB[3], qB[2], qB[3], vB, aB, bB[1], gB[1], true)   // LAST

    // deferred output reduction + coalesced store (single wave: ds-ordered)
    {
      int st = lane >> 2, rr = lane & 3;      // 64 outputs: 16 steps x 4 rows
      float4 A0 = *(const float4*)&so[st][rr * 16];
      float4 A1 = *(const float4*)&so[st][rr * 16 + 4];
      float4 A2 = *(const float4*)&so[st][rr * 16 + 8];
      float4 A3 = *(const float4*)&so[st][rr * 16 + 12];
      float s = (((A0.x + A0.y) + (A0.z + A0.w)) + ((A1.x + A1.y) + (A1.z + A1.w)))
              + (((A2.x + A2.y) + (A2.z + A2.w)) + ((A3.x + A3.y) + (A3.z + A3.w)));
      so2[st][rr] = cvt_bf16(s);
    }
    if (lane < 16)
      *(bf16x4v*)((__bf16*)o + bva + (size_t)(c * 16 + lane) * 1024) =
          *(const bf16x4v*)&so2[lane][0];

    if (hasNext) commit(buf ^ 1);
  }
}

// LayerNorm over DV=64 per (b,t,h) row, *ln_w+ln_b, *gate -> bf16
__global__ __launch_bounds__(256) void ln_gate_kernel(
    const bf16* __restrict__ o, const bf16* __restrict__ g,
    const float* __restrict__ lnw, const float* __restrict__ lnb,
    bf16* __restrict__ out)
{
  int row = blockIdx.x * 4 + (threadIdx.x >> 6);
  int lane = threadIdx.x & 63;
  size_t idx = (size_t)row * 64 + lane;
  float xv = (float)o[idx];
  float mu = xv;
#pragma unroll
  for (int s = 1; s < 64; s <<= 1) mu += __shfl_xor(mu, s);
  mu *= (1.f / 64.f);
  float d = xv - mu;
  float vv = d * d;
#pragma unroll
  for (int s = 1; s < 64; s <<= 1) vv += __shfl_xor(vv, s);
  vv *= (1.f / 64.f);
  float y = d * rsqrtf(vv + 1e-5f) * lnw[lane] + lnb[lane];
  y *= (float)g[idx];
  out[idx] = (bf16)y;
}

extern "C" void kernel_launch(void* const* d_in, const int* in_sizes, int n_in,
                              void* d_out, int out_size, void* d_ws, size_t ws_size,
                              hipStream_t stream)
{
  const float* x   = (const float*)d_in[0];
  const float* Wq  = (const float*)d_in[1];
  const float* Wk  = (const float*)d_in[2];
  const float* Wv  = (const float*)d_in[3];
  const float* Wa  = (const float*)d_in[4];
  const float* ba  = (const float*)d_in[5];
  const float* Wb  = (const float*)d_in[6];
  const float* bb  = (const float*)d_in[7];
  const float* Wg  = (const float*)d_in[8];
  const float* Wo  = (const float*)d_in[9];
  const float* qcw = (const float*)d_in[10];
  const float* qcb = (const float*)d_in[11];
  const float* kcw = (const float*)d_in[12];
  const float* kcb = (const float*)d_in[13];
  const float* vcw = (const float*)d_in[14];
  const float* vcb = (const float*)d_in[15];
  const float* lnw = (const float*)d_in[16];
  const float* lnb = (const float*)d_in[17];

  const int M = 4096, HID = 1024;
  const size_t PLANE = (size_t)M * HID;
  const size_t PB = PLANE * sizeof(bf16);          // 8 MB bf16 plane

  char* ws = (char*)d_ws;
  float* outf = (float*)d_out;
  const bool rich = (ws_size >= 5 * PB + 1024);

  dim3 blk(256);
  dim3 g8(8, 32);
  int nconv = (int)((size_t)M * 128 / 256);          // x8-vectorized conv grid

  if (rich) {
    bf16* P0 = (bf16*)(ws);
    bf16* P1 = (bf16*)(ws + PB);
    bf16* P2 = (bf16*)(ws + 2 * PB);
    bf16* P3 = (bf16*)(ws + 3 * PB);
    bf16* P4 = (bf16*)(ws + 4 * PB);
    bf16*  xb    = (bf16*)d_out;                          // [0,8M): x bf16, dead after mega
    bf16*  W4b   = (bf16*)((char*)d_out + 8 * 1024 * 1024); // [8M,16M): weights, dead after mega
    bf16*  Kb    = xb;                                    // k-plane reuses [0,8M)
    bf16*  Qb    = W4b;                                   // q-plane reuses [8M,16M)
    float* betab = (float*)P4;                            // P4[0,256K)
    float* gkk   = (float*)((char*)P4 + 256 * 1024);      // P4[256K,512K)

    // 1. convert x + 4 projection weights to bf16
    cvtw_kernel<<<8192, blk, 0, stream>>>(x, Wq, Wk, Wv, Wa, xb, W4b);
    // 2. fused 4-projection + beta GEMM: zq->P0 zk->P1 zv->P2 a->P3, betab->P4
    mega_gemm2<<<dim3(33, 32), blk, 0, stream>>>(xb, W4b, Wb, bb, ba, P0, betab);
    // 3-5. convs (xb, W4b dead now)
    conv_silu_kernel<<<nconv, blk, 0, stream>>>(P0, qcw, qcb, Qb, 1.f);     // q->[8M,16M)
    conv_silu_kernel<<<nconv, blk, 0, stream>>>(P1, kcw, kcb, Kb, 0.125f);  // k->[0,8M)
    conv_silu_kernel<<<nconv, blk, 0, stream>>>(P2, vcw, vcb, P1, 1.f);     // v->P1
    // 6. G = beta * (k_{t-1}.k_t)
    kk_kernel<<<1024, blk, 0, stream>>>(Kb, betab, gkk);
    // 7. FUSED scan (o->P0) + g-GEMM (sigmoid(x@Wg^T)->P2)
    scan_gemm_kernel<<<768, blk, 0, stream>>>(Qb, Kb, P1, P3, betab, gkk, P0,
                                              x, Wg, P2);
    // 8. LN + gate -> P1
    ln_gate_kernel<<<M * 16 / 4, blk, 0, stream>>>(P0, P2, lnw, lnb, P1);
    // 9. final: out = (P1) @ Wo^T  (overwrites all d_out scratch)
    gemm_bt<4, false><<<g8, blk, 0, stream>>>(P1, Wo, nullptr, outf, nullptr, M, HID, HID);
  } else {
    bf16* P  = (bf16*)(ws);
    bf16* qb = (bf16*)(ws + PB);
    bf16* kb = (bf16*)(ws + 2 * PB);
    bf16* vb = (bf16*)(ws + 3 * PB);
    float* betab = (float*)d_out;
    float* gkk   = (float*)((char*)d_out + 256 * 1024);
    bf16*  ob    = (bf16*)((char*)d_out + 8 * 1024 * 1024);

    gemm_bt<2, true><<<g8, blk, 0, stream>>>(x, Wq, nullptr, nullptr, P, M, HID, HID);
    conv_silu_kernel<<<nconv, blk, 0, stream>>>(P, qcw, qcb, qb, 1.f);
    gemm_bt<2, true><<<g8, blk, 0, stream>>>(x, Wk, nullptr, nullptr, P, M, HID, HID);
    conv_silu_kernel<<<nconv, blk, 0, stream>>>(P, kcw, kcb, kb, 0.125f);
    gemm_bt<2, true><<<g8, blk, 0, stream>>>(x, Wv, nullptr, nullptr, P, M, HID, HID);
    conv_silu_kernel<<<nconv, blk, 0, stream>>>(P, vcw, vcb, vb, 1.f);
    gemm_bt<3, true><<<g8, blk, 0, stream>>>(x, Wa, ba, nullptr, P, M, HID, HID);
    gemm_bt<5, true><<<dim3(1, 32), blk, 0, stream>>>(x, Wb, bb, betab, nullptr, M, 16, HID);
    kk_kernel<<<1024, blk, 0, stream>>>(kb, betab, gkk);
    scan_gemm_kernel<<<512, blk, 0, stream>>>(qb, kb, vb, P, betab, gkk, ob,
                                              x, Wg, nullptr);
    gemm_bt<3, true><<<g8, blk, 0, stream>>>(x, Wg, nullptr, nullptr, qb, M, HID, HID);
    ln_gate_kernel<<<M * 16 / 4, blk, 0, stream>>>(ob, qb, lnw, lnb, kb);
    gemm_bt<4, false><<<g8, blk, 0, stream>>>(kb, Wo, nullptr, outf, nullptr, M, HID, HID);
  }
}

// Round 11
// 460.756 us; speedup vs baseline: 1.5159x; 1.0195x over previous
//
#include <hip/hip_runtime.h>
#include <hip/hip_bf16.h>
#include <cstdint>

// B=2, T=2048, HID=1024, H=16, DK=DV=64, K(conv)=4. fp32 in/out.
// RICH memory plan (ws >= 40MB): ws = P0..P4 (8MB bf16 planes).
//  d_out[0,8M): xb (bf16 x), dead after mega_gemm2 -> then k-plane (conv out)
//  d_out[8M,16M): W4b (bf16 Wq|Wk|Wv|Wa), dead after mega_gemm2 -> q-plane
//  P4[0,256K): betab fp32; [256K,512K): gkk fp32; [1M,3M): Wgb bf16;
//  [3M,5M): Wob bf16.
//  P0: zq -> scan output o;  P1: zk -> v-plane -> ln_gate out;
//  P2: zv -> g-plane;        P3: a (sigmoid) plane, live until scan.
// Launches (9): cvtw -> mega_gemm2(+beta) -> conv q/k/v -> kk
//   -> FUSED scan+g-GEMM -> ln_gate -> gemm_bb (final, both-bf16-async).
//
// R11: final GEMM upgraded to both-operand global_load_lds (R10's mega win
// applied to Wo); g-GEMM inside scan_gemm gets bf16 B (Wgb) -> half the
// VALU staging competing with scan waves. Scan: R9-proven form, untouched.

using bf16 = __hip_bfloat16;
typedef __bf16 bf16x8 __attribute__((ext_vector_type(8)));
typedef __bf16 bf16x4v __attribute__((ext_vector_type(4)));
typedef float f32x4 __attribute__((ext_vector_type(4)));
typedef float f32x2 __attribute__((ext_vector_type(2)));
typedef unsigned int u32x4 __attribute__((ext_vector_type(4)));
typedef unsigned int u32x2 __attribute__((ext_vector_type(2)));

__device__ __forceinline__ __bf16 cvt_bf16(float f) {
  __hip_bfloat16 h = (__hip_bfloat16)f;
  return *reinterpret_cast<__bf16*>(&h);
}
__device__ __forceinline__ void async_copy16(const void* g, void* l) {
  __builtin_amdgcn_global_load_lds((const __attribute__((address_space(1))) void*)g,
                                   (__attribute__((address_space(3))) void*)l,
                                   16, 0, 0);
}
__device__ __forceinline__ float bcf(unsigned int u) { return __builtin_bit_cast(float, u); }
template <int CTRL>
__device__ __forceinline__ float dpp_f(float x) {
  int y = __builtin_amdgcn_update_dpp(0, __builtin_bit_cast(int, x), CTRL, 0xF, 0xF, true);
  return __builtin_bit_cast(float, y);
}

// fp32 -> bf16: x (blocks 0..4095), W4 (4096..8191), Wg (8192..9215),
// Wo (9216..10239).
__global__ __launch_bounds__(256) void cvtw_kernel(
    const float* __restrict__ x, const float* __restrict__ Wq,
    const float* __restrict__ Wk, const float* __restrict__ Wv,
    const float* __restrict__ Wa, const float* __restrict__ Wg,
    const float* __restrict__ Wo, bf16* __restrict__ xb,
    bf16* __restrict__ w4b, bf16* __restrict__ wgb, bf16* __restrict__ wob)
{
  int blk = blockIdx.x;
  const float* src;
  __bf16* dst;
  size_t off;
  if (blk < 4096) {
    src = x; dst = (__bf16*)xb;
    off = (size_t)blk * 1024 + threadIdx.x * 4;
  } else if (blk < 8192) {
    int wb = blk - 4096;
    int wi = wb >> 10;
    src = (wi == 0) ? Wq : (wi == 1) ? Wk : (wi == 2) ? Wv : Wa;
    dst = (__bf16*)w4b + (size_t)wi * 1024 * 1024;
    off = (size_t)(wb & 1023) * 1024 + threadIdx.x * 4;
  } else if (blk < 9216) {
    src = Wg; dst = (__bf16*)wgb;
    off = (size_t)(blk - 8192) * 1024 + threadIdx.x * 4;
  } else {
    src = Wo; dst = (__bf16*)wob;
    off = (size_t)(blk - 9216) * 1024 + threadIdx.x * 4;
  }
  float4 f = *(const float4*)(src + off);
  bf16x4v t;
  t[0] = cvt_bf16(f.x); t[1] = cvt_bf16(f.y); t[2] = cvt_bf16(f.z); t[3] = cvt_bf16(f.w);
  *(bf16x4v*)(dst + off) = t;
}

// C = A * Bt^T. A: MxK (bf16 async-staged unless A_FP32); Bt: NxK fp32.
// MODE 2: raw->bf16; 3: sigmoid(acc+bias)->bf16; 4: raw->fp32; 5: sigmoid(acc+bias)->fp32 TRANSPOSED
template <int MODE, bool A_FP32>
__global__ __launch_bounds__(256) void gemm_bt(
    const void* __restrict__ Av, const float* __restrict__ Bt,
    const float* __restrict__ bias, float* __restrict__ Cf, bf16* __restrict__ Cb,
    int M, int N, int K)
{
  __shared__ __align__(16) __bf16 As[128 * 32];
  __shared__ __align__(16) __bf16 Bs[128 * 32];

  const int tid  = threadIdx.x;
  const int lane = tid & 63;
  const int wave = tid >> 6;
  const int tile_m = blockIdx.y * 128;
  const int tile_n = blockIdx.x * 128;
  const int wm = (wave >> 1) * 64;
  const int wn = (wave & 1) * 64;

  const int srow = lane >> 2;
  const int scol = (lane & 3) * 8;

  f32x4 acc[4][4];
#pragma unroll
  for (int i = 0; i < 4; ++i)
#pragma unroll
    for (int j = 0; j < 4; ++j) acc[i][j] = {0.f, 0.f, 0.f, 0.f};

  for (int k0 = 0; k0 < K; k0 += 32) {
    float4 b0[2], b1[2], a0[2], a1[2];
#pragma unroll
    for (int s = 0; s < 2; ++s) {
      int brow = tile_n + s * 64 + wave * 16 + srow;
      if (brow > N - 1) brow = N - 1;             // clamp (beta GEMM: N=16)
      const float* bp = Bt + (size_t)brow * K + k0 + scol;
      b0[s] = *(const float4*)bp;
      b1[s] = *(const float4*)(bp + 4);
      if (A_FP32) {
        int arow = tile_m + s * 64 + wave * 16 + srow;
        const float* ap = (const float*)Av + (size_t)arow * K + k0 + scol;
        a0[s] = *(const float4*)ap;
        a1[s] = *(const float4*)(ap + 4);
      }
    }
    __syncthreads();
#pragma unroll
    for (int s = 0; s < 2; ++s) {
      if (!A_FP32) {
        int arow = tile_m + s * 64 + wave * 16 + srow;
        async_copy16((const __bf16*)Av + (size_t)arow * K + k0 + scol,
                     &As[(s * 64 + wave * 16 + srow) * 32 + scol]);
      } else {
        bf16x8 ua;
        ua[0] = cvt_bf16(a0[s].x); ua[1] = cvt_bf16(a0[s].y);
        ua[2] = cvt_bf16(a0[s].z); ua[3] = cvt_bf16(a0[s].w);
        ua[4] = cvt_bf16(a1[s].x); ua[5] = cvt_bf16(a1[s].y);
        ua[6] = cvt_bf16(a1[s].z); ua[7] = cvt_bf16(a1[s].w);
        *(bf16x8*)&As[(s * 64 + wave * 16 + srow) * 32 + scol] = ua;
      }
      bf16x8 u;
      u[0] = cvt_bf16(b0[s].x); u[1] = cvt_bf16(b0[s].y);
      u[2] = cvt_bf16(b0[s].z); u[3] = cvt_bf16(b0[s].w);
      u[4] = cvt_bf16(b1[s].x); u[5] = cvt_bf16(b1[s].y);
      u[6] = cvt_bf16(b1[s].z); u[7] = cvt_bf16(b1[s].w);
      *(bf16x8*)&Bs[(s * 64 + wave * 16 + srow) * 32 + scol] = u;
    }
    __syncthreads();

    bf16x8 af[4], bfr[4];
#pragma unroll
    for (int i = 0; i < 4; ++i)
      af[i] = *(const bf16x8*)&As[(wm + i * 16 + (lane & 15)) * 32 + (lane >> 4) * 8];
#pragma unroll
    for (int j = 0; j < 4; ++j)
      bfr[j] = *(const bf16x8*)&Bs[(wn + j * 16 + (lane & 15)) * 32 + (lane >> 4) * 8];

#pragma unroll
    for (int i = 0; i < 4; ++i)
#pragma unroll
      for (int j = 0; j < 4; ++j)
        acc[i][j] = __builtin_amdgcn_mfma_f32_16x16x32_bf16(af[i], bfr[j], acc[i][j], 0, 0, 0);
  }

  // C/D layout (m89-verified): col = lane&15, row = (lane>>4)*4 + reg
#pragma unroll
  for (int i = 0; i < 4; ++i) {
#pragma unroll
    for (int j = 0; j < 4; ++j) {
#pragma unroll
      for (int r = 0; r < 4; ++r) {
        int gm = tile_m + wm + i * 16 + (lane >> 4) * 4 + r;
        int gn = tile_n + wn + j * 16 + (lane & 15);
        if (gn < N) {
          float val = acc[i][j][r];
          if (MODE == 3 || MODE == 5) {
            float bv = bias ? bias[gn] : 0.f;
            val = 1.f / (1.f + __expf(-(val + bv)));
          }
          if (MODE == 4)      Cf[(size_t)gm * N + gn] = val;
          else if (MODE == 5) Cf[(size_t)gn * M + gm] = val;   // transposed
          else                Cb[(size_t)gm * N + gn] = (bf16)val;
        }
      }
    }
  }
}

// Final GEMM: C(fp32) = A(bf16) @ Bw(bf16)^T, M=4096 N=1024 K=1024.
// Both operands via global_load_lds. Grid (8,32).
__global__ __launch_bounds__(256) void gemm_bb(
    const bf16* __restrict__ A, const bf16* __restrict__ Bw,
    float* __restrict__ C)
{
  __shared__ __align__(16) __bf16 As[128 * 32];
  __shared__ __align__(16) __bf16 Bs[128 * 32];

  const int tid  = threadIdx.x;
  const int lane = tid & 63;
  const int wave = tid >> 6;
  const int tile_m = blockIdx.y * 128;
  const int tile_n = blockIdx.x * 128;
  const int wm = (wave >> 1) * 64;
  const int wn = (wave & 1) * 64;
  const int srow = lane >> 2;
  const int scol = (lane & 3) * 8;

  f32x4 acc[4][4];
#pragma unroll
  for (int i = 0; i < 4; ++i)
#pragma unroll
    for (int j = 0; j < 4; ++j) acc[i][j] = {0.f, 0.f, 0.f, 0.f};

  for (int k0 = 0; k0 < 1024; k0 += 32) {
    __syncthreads();
#pragma unroll
    for (int s = 0; s < 2; ++s) {
      int arow = tile_m + s * 64 + wave * 16 + srow;
      async_copy16((const __bf16*)A + (size_t)arow * 1024 + k0 + scol,
                   &As[(s * 64 + wave * 16 + srow) * 32 + scol]);
      int brow = tile_n + s * 64 + wave * 16 + srow;
      async_copy16((const __bf16*)Bw + (size_t)brow * 1024 + k0 + scol,
                   &Bs[(s * 64 + wave * 16 + srow) * 32 + scol]);
    }
    __syncthreads();

    bf16x8 af[4], bfr[4];
#pragma unroll
    for (int i = 0; i < 4; ++i)
      af[i] = *(const bf16x8*)&As[(wm + i * 16 + (lane & 15)) * 32 + (lane >> 4) * 8];
#pragma unroll
    for (int j = 0; j < 4; ++j)
      bfr[j] = *(const bf16x8*)&Bs[(wn + j * 16 + (lane & 15)) * 32 + (lane >> 4) * 8];

#pragma unroll
    for (int i = 0; i < 4; ++i)
#pragma unroll
      for (int j = 0; j < 4; ++j)
        acc[i][j] = __builtin_amdgcn_mfma_f32_16x16x32_bf16(af[i], bfr[j], acc[i][j], 0, 0, 0);
  }

#pragma unroll
  for (int i = 0; i < 4; ++i)
#pragma unroll
    for (int j = 0; j < 4; ++j)
#pragma unroll
      for (int r = 0; r < 4; ++r) {
        int gm = tile_m + wm + i * 16 + (lane >> 4) * 4 + r;
        int gn = tile_n + wn + j * 16 + (lane & 15);
        C[(size_t)gm * 1024 + gn] = acc[i][j][r];
      }
}

// Fused 4-projection + beta GEMM. Grid (33,32).
__global__ __launch_bounds__(256) void mega_gemm2(
    const bf16* __restrict__ Av, const bf16* __restrict__ W4b,
    const float* __restrict__ Wb, const float* __restrict__ bb,
    const float* __restrict__ ba, bf16* __restrict__ C4,
    float* __restrict__ betab)
{
  __shared__ __align__(16) __bf16 As[128 * 32];
  __shared__ __align__(16) __bf16 Bs[128 * 32];

  const int tid  = threadIdx.x;
  const int lane = tid & 63;
  const int wave = tid >> 6;
  const int tile_m = blockIdx.y * 128;
  const bool isbeta = (blockIdx.x >= 32);
  const int tile_n = isbeta ? 0 : blockIdx.x * 128;
  const int grp = tile_n >> 10;
  const int tnl = tile_n & 1023;
  const int wm = (wave >> 1) * 64;
  const int wn = (wave & 1) * 64;

  const int srow = lane >> 2;
  const int scol = (lane & 3) * 8;

  f32x4 acc[4][4];
#pragma unroll
  for (int i = 0; i < 4; ++i)
#pragma unroll
    for (int j = 0; j < 4; ++j) acc[i][j] = {0.f, 0.f, 0.f, 0.f};

  const __bf16* Wp = (const __bf16*)W4b + (size_t)grp * 1024 * 1024;

  for (int k0 = 0; k0 < 1024; k0 += 32) {
    float4 b0[2], b1[2];
    if (isbeta) {
#pragma unroll
      for (int s = 0; s < 2; ++s) {
        int brow = s * 64 + wave * 16 + srow;
        if (brow > 15) brow = 15;
        const float* bp = Wb + (size_t)brow * 1024 + k0 + scol;
        b0[s] = *(const float4*)bp;
        b1[s] = *(const float4*)(bp + 4);
      }
    }
    __syncthreads();
#pragma unroll
    for (int s = 0; s < 2; ++s) {
      int arow = tile_m + s * 64 + wave * 16 + srow;
      async_copy16((const __bf16*)Av + (size_t)arow * 1024 + k0 + scol,
                   &As[(s * 64 + wave * 16 + srow) * 32 + scol]);
      if (!isbeta) {
        int brow = tnl + s * 64 + wave * 16 + srow;
        async_copy16(Wp + (size_t)brow * 1024 + k0 + scol,
                     &Bs[(s * 64 + wave * 16 + srow) * 32 + scol]);
      } else {
        bf16x8 u;
        u[0] = cvt_bf16(b0[s].x); u[1] = cvt_bf16(b0[s].y);
        u[2] = cvt_bf16(b0[s].z); u[3] = cvt_bf16(b0[s].w);
        u[4] = cvt_bf16(b1[s].x); u[5] = cvt_bf16(b1[s].y);
        u[6] = cvt_bf16(b1[s].z); u[7] = cvt_bf16(b1[s].w);
        *(bf16x8*)&Bs[(s * 64 + wave * 16 + srow) * 32 + scol] = u;
      }
    }
    __syncthreads();

    bf16x8 af[4], bfr[4];
#pragma unroll
    for (int i = 0; i < 4; ++i)
      af[i] = *(const bf16x8*)&As[(wm + i * 16 + (lane & 15)) * 32 + (lane >> 4) * 8];
#pragma unroll
    for (int j = 0; j < 4; ++j)
      bfr[j] = *(const bf16x8*)&Bs[(wn + j * 16 + (lane & 15)) * 32 + (lane >> 4) * 8];

#pragma unroll
    for (int i = 0; i < 4; ++i)
#pragma unroll
      for (int j = 0; j < 4; ++j)
        acc[i][j] = __builtin_amdgcn_mfma_f32_16x16x32_bf16(af[i], bfr[j], acc[i][j], 0, 0, 0);
  }

  if (!isbeta) {
    bf16* Cp = (bf16*)((__bf16*)C4 + (size_t)grp * 4096 * 1024);
#pragma unroll
    for (int i = 0; i < 4; ++i)
#pragma unroll
      for (int j = 0; j < 4; ++j)
#pragma unroll
        for (int r = 0; r < 4; ++r) {
          int gm = tile_m + wm + i * 16 + (lane >> 4) * 4 + r;
          int col = tnl + wn + j * 16 + (lane & 15);
          float val = acc[i][j][r];
          if (grp == 3) val = 1.f / (1.f + __expf(-(val + ba[col])));
          ((__bf16*)Cp)[(size_t)gm * 1024 + col] = cvt_bf16(val);
        }
  } else {
#pragma unroll
    for (int i = 0; i < 4; ++i)
#pragma unroll
      for (int j = 0; j < 4; ++j)
#pragma unroll
        for (int r = 0; r < 4; ++r) {
          int gm = tile_m + wm + i * 16 + (lane >> 4) * 4 + r;
          int gn = wn + j * 16 + (lane & 15);
          if (gn < 16) {
            float val = 1.f / (1.f + __expf(-(acc[i][j][r] + bb[gn])));
            betab[(size_t)gn * 4096 + gm] = val;
          }
        }
  }
}

// causal depthwise conv K=4 + bias + SiLU (+scale), x8 vectorized.
__global__ __launch_bounds__(256) void conv_silu_kernel(
    const bf16* __restrict__ z, const float* __restrict__ w,
    const float* __restrict__ bias, bf16* __restrict__ out, float scale)
{
  int idx = blockIdx.x * 256 + threadIdx.x;   // 512K threads
  int c8 = idx & 127;
  int m  = idx >> 7;
  int t  = m & 2047;
  int c0 = c8 * 8;

  const __bf16* base = (const __bf16*)z + (size_t)m * 1024 + c0;
  const bf16x8 zzero = __builtin_bit_cast(bf16x8, (u32x4){0u, 0u, 0u, 0u});
  bf16x8 z3 = *(const bf16x8*)base;
  bf16x8 z2 = (t >= 1) ? *(const bf16x8*)(base - 1024) : zzero;
  bf16x8 z1 = (t >= 2) ? *(const bf16x8*)(base - 2048) : zzero;
  bf16x8 z0 = (t >= 3) ? *(const bf16x8*)(base - 3072) : zzero;

  const float* wp = w + c0 * 4;     // [ch][tap], 32 contiguous floats
  bf16x8 res;
#pragma unroll
  for (int e = 0; e < 8; ++e) {
    float4 we = *(const float4*)(wp + e * 4);
    float acc = bias[c0 + e] + (float)z3[e] * we.w;
    acc += (float)z2[e] * we.z;
    acc += (float)z1[e] * we.y;
    acc += (float)z0[e] * we.x;
    float s = acc / (1.f + __expf(-acc));
    res[e] = cvt_bf16(s * scale);
  }
  *(bf16x8*)((__bf16*)out + (size_t)m * 1024 + c0) = res;
}

// G[h][b*2048+t] = beta[h][b*2048+t] * (k_{t-1} . k_t) over DK=64 (0 at t=0).
__global__ __launch_bounds__(256) void kk_kernel(
    const bf16* __restrict__ k, const float* __restrict__ betab,
    float* __restrict__ G)
{
  int tid = blockIdx.x * 256 + threadIdx.x;
  int out = tid >> 2;            // h*4096 + m, m = b*2048+t
  int j   = tid & 3;
  int h = out >> 12;
  int m = out & 4095;
  int t = m & 2047;
  float s = 0.f;
  if (t > 0) {
    const __bf16* r1 = (const __bf16*)k + (size_t)m * 1024 + h * 64 + j * 16;
    const __bf16* r0 = r1 - 1024;
    bf16x8 a0 = *(const bf16x8*)r0;
    bf16x8 a1 = *(const bf16x8*)(r0 + 8);
    bf16x8 b0 = *(const bf16x8*)r1;
    bf16x8 b1 = *(const bf16x8*)(r1 + 8);
#pragma unroll
    for (int e = 0; e < 8; ++e)
      s += (float)a0[e] * (float)b0[e] + (float)a1[e] * (float)b1[e];
  }
  s += __shfl_xor(s, 1);
  s += __shfl_xor(s, 2);
  if (j == 0) G[out] = betab[out] * s;
}

// One scan step (constant word indices only).
#define SCAN_STEP(i, KN0, KN1, Q0, Q1, WV, WA, BT, GT, LAST)                  \
  {                                                                           \
    const float vr = ((i) & 1) ? bcf((WV) & 0xffff0000u) : bcf((WV) << 16);   \
    const float ar = ((i) & 1) ? bcf((WA) & 0xffff0000u) : bcf((WA) << 16);   \
    float unxt = 0.f;                                                         \
    f32x2 k2n0 = {0.f, 0.f}, k2n1 = {0.f, 0.f};                               \
    if (!(LAST)) {                                                            \
      k2n0 = unpk(KN0); k2n1 = unpk(KN1);                                     \
      f32x2 dd = S20 * k2n0; dd += S21 * k2n1;                                \
      unxt = dd[0] + dd[1];                                                   \
      unxt += dpp_f<0xB1>(unxt);  unxt += dpp_f<0x4E>(unxt);                  \
      unxt += dpp_f<0x141>(unxt); unxt += dpp_f<0x140>(unxt);                 \
    } else { Sold0 = S20; Sold1 = S21; }                                      \
    float A_ = (BT) * __builtin_fmaf(aprev, u, -vr);                          \
    cc = __builtin_fmaf(-cc, (GT), A_);                                       \
    f32x2 q20 = unpk(Q0), q21 = unpk(Q1);                                     \
    const f32x2 cc2 = {cc, cc}, arv = {ar, ar};                               \
    f32x2 oo;                                                                 \
    { f32x2 t0 = cc2 * k2c0; S20 = arv * S20 - t0; oo = S20 * q20;            \
      f32x2 t1 = cc2 * k2c1; S21 = arv * S21 - t1; oo += S21 * q21; }         \
    so[(i)][lane] = oo[0] + oo[1];                                            \
    aprev = ar;                                                               \
    if (!(LAST)) { k2c0 = k2n0; k2c1 = k2n1; u = unxt; }                      \
  }

// Load one 2-step group (g = 0..7) into a named set (14 regs).
#define LOADG(KS, QS, VS, AS, BS, GS, g)                                      \
  KS = *(const u32x4*)&skT[buf][sg][(g) * 8];                                 \
  QS = *(const u32x4*)&sqT[buf][sg][(g) * 8];                                 \
  VS = *(const unsigned int*)&svaT[buf][0][r4][(g) * 2];                      \
  AS = *(const unsigned int*)&svaT[buf][1][r4][(g) * 2];                      \
  BS = *(const f32x2*)&sbeta[c * 16 + (g) * 2];                               \
  GS = *(const f32x2*)&sG[c * 16 + (g) * 2];

// FUSED kernel: blocks 0..511 = delta-rule scan (single wave; threads>=64
// exit; NO barriers). Blocks 512..767 = g-GEMM: sigmoid(x @ Wgb^T) -> gout
// (A = x fp32 cvt-staged; B = Wgb bf16 async).
__global__ __launch_bounds__(256) void scan_gemm_kernel(
    const bf16* __restrict__ q, const bf16* __restrict__ k,
    const bf16* __restrict__ v, const bf16* __restrict__ a,
    const float* __restrict__ betab, const float* __restrict__ gkk,
    bf16* __restrict__ o,
    const float* __restrict__ x, const bf16* __restrict__ Wgb,
    bf16* __restrict__ gout)
{
  __shared__ __align__(16) __bf16 skT[2][16][72];    // scan: 4608 B
  __shared__ __align__(16) __bf16 sqT[2][16][72];    // scan: 4608 B
  __shared__ __align__(16) __bf16 svaT[2][2][4][16]; // scan: 512 B
  __shared__ __align__(16) float  so[16][68];        // scan: 4352 B
  __shared__ __align__(16) __bf16 so2[16][4];        // scan
  __shared__ float sbeta[2048];                      // scan: 8 KB
  __shared__ float sG[2048];                         // scan: 8 KB
  __shared__ __align__(16) __bf16 As[128 * 32];      // gemm: 8 KB
  __shared__ __align__(16) __bf16 Bs[128 * 32];      // gemm: 8 KB

  if (blockIdx.x >= 512) {
    // ---------------- g-GEMM path (all 256 threads) ----------------
    const int gb   = blockIdx.x - 512;
    const int tid  = threadIdx.x;
    const int lane = tid & 63;
    const int wave = tid >> 6;
    const int tile_m = (gb >> 3) * 128;
    const int tile_n = (gb & 7) * 128;
    const int wm = (wave >> 1) * 64;
    const int wn = (wave & 1) * 64;
    const int srow = lane >> 2;
    const int scol = (lane & 3) * 8;

    f32x4 acc[4][4];
#pragma unroll
    for (int i = 0; i < 4; ++i)
#pragma unroll
      for (int j = 0; j < 4; ++j) acc[i][j] = {0.f, 0.f, 0.f, 0.f};

    for (int k0 = 0; k0 < 1024; k0 += 32) {
      float4 a0[2], a1[2];
#pragma unroll
      for (int s = 0; s < 2; ++s) {
        int arow = tile_m + s * 64 + wave * 16 + srow;
        const float* ap = x + (size_t)arow * 1024 + k0 + scol;
        a0[s] = *(const float4*)ap;
        a1[s] = *(const float4*)(ap + 4);
      }
      __syncthreads();
#pragma unroll
      for (int s = 0; s < 2; ++s) {
        bf16x8 ua;
        ua[0] = cvt_bf16(a0[s].x); ua[1] = cvt_bf16(a0[s].y);
        ua[2] = cvt_bf16(a0[s].z); ua[3] = cvt_bf16(a0[s].w);
        ua[4] = cvt_bf16(a1[s].x); ua[5] = cvt_bf16(a1[s].y);
        ua[6] = cvt_bf16(a1[s].z); ua[7] = cvt_bf16(a1[s].w);
        *(bf16x8*)&As[(s * 64 + wave * 16 + srow) * 32 + scol] = ua;
        int brow = tile_n + s * 64 + wave * 16 + srow;
        async_copy16((const __bf16*)Wgb + (size_t)brow * 1024 + k0 + scol,
                     &Bs[(s * 64 + wave * 16 + srow) * 32 + scol]);
      }
      __syncthreads();

      bf16x8 af[4], bfr[4];
#pragma unroll
      for (int i = 0; i < 4; ++i)
        af[i] = *(const bf16x8*)&As[(wm + i * 16 + (lane & 15)) * 32 + (lane >> 4) * 8];
#pragma unroll
      for (int j = 0; j < 4; ++j)
        bfr[j] = *(const bf16x8*)&Bs[(wn + j * 16 + (lane & 15)) * 32 + (lane >> 4) * 8];

#pragma unroll
      for (int i = 0; i < 4; ++i)
#pragma unroll
        for (int j = 0; j < 4; ++j)
          acc[i][j] = __builtin_amdgcn_mfma_f32_16x16x32_bf16(af[i], bfr[j], acc[i][j], 0, 0, 0);
    }

#pragma unroll
    for (int i = 0; i < 4; ++i)
#pragma unroll
      for (int j = 0; j < 4; ++j)
#pragma unroll
        for (int r = 0; r < 4; ++r) {
          int gm = tile_m + wm + i * 16 + (lane >> 4) * 4 + r;
          int gn = tile_n + wn + j * 16 + (lane & 15);
          float val = 1.f / (1.f + __expf(-acc[i][j][r]));
          gout[(size_t)gm * 1024 + gn] = (bf16)val;
        }
    return;
  }

  // ---------------- scan path (single wave; extra waves exit) ----------------
  if (threadIdx.x >= 64) return;

  const int blk = blockIdx.x;
  const int qd = blk >> 5;           // DV slice 0..15 (4 rows each)
  const int bh = blk & 31;
  const int b = bh >> 4, h = bh & 15;
  const int lane = threadIdx.x;      // single wave
  const int r4 = lane >> 4;          // local row 0..3
  const int sg = lane & 15;

  {
    const float* bp = betab + (size_t)h * 4096 + b * 2048;
    const float* gp = gkk   + (size_t)h * 4096 + b * 2048;
    for (int t = lane; t < 2048; t += 64) { sbeta[t] = bp[t]; sG[t] = gp[t]; }
  }

  const size_t bkq = (size_t)b * 2048 * 1024 + h * 64;   // k/q plane base
  const size_t bva = bkq + qd * 4;                       // v/a/o slice base
  const __bf16* kp = (const __bf16*)k;
  const __bf16* qp = (const __bf16*)q;

  const int g_st = lane >> 3;          // staging step-in-group 0..7
  const int g_cg = (lane & 7) * 8;     // staging col (bf16 units)
  const int sgp  = (lane & 7) * 2;     // sg-slice pair base for commit
  const int va_vh = (lane >> 4) & 1;   // lanes 0-15: v, 16-31: a
  const int va_st = lane & 15;

  bf16x8 pk0, pk1, pq0, pq1;
  bf16x4v pva;
  auto fetch = [&](int t0) {
    int st0 = t0 + g_st, st1 = t0 + 8 + g_st;
    pk0 = *(const bf16x8*)(kp + bkq + (size_t)st0 * 1024 + g_cg);
    pk1 = *(const bf16x8*)(kp + bkq + (size_t)st1 * 1024 + g_cg);
    pq0 = *(const bf16x8*)(qp + bkq + (size_t)st0 * 1024 + g_cg);
    pq1 = *(const bf16x8*)(qp + bkq + (size_t)st1 * 1024 + g_cg);
    if (lane < 32) {
      const __bf16* src = va_vh ? (const __bf16*)a : (const __bf16*)v;
      pva = *(const bf16x4v*)(src + bva + (size_t)(t0 + va_st) * 1024);
    }
  };
  auto commit = [&](int cb) {
    {
      u32x4 wk = __builtin_bit_cast(u32x4, pk0);
      u32x4 wq = __builtin_bit_cast(u32x4, pq0);
      u32x2 lo, hi;
      lo[0] = wk[0]; lo[1] = wk[1]; hi[0] = wk[2]; hi[1] = wk[3];
      *(u32x2*)&skT[cb][sgp][g_st * 4]     = lo;
      *(u32x2*)&skT[cb][sgp + 1][g_st * 4] = hi;
      lo[0] = wq[0]; lo[1] = wq[1]; hi[0] = wq[2]; hi[1] = wq[3];
      *(u32x2*)&sqT[cb][sgp][g_st * 4]     = lo;
      *(u32x2*)&sqT[cb][sgp + 1][g_st * 4] = hi;
    }
    {
      u32x4 wk = __builtin_bit_cast(u32x4, pk1);
      u32x4 wq = __builtin_bit_cast(u32x4, pq1);
      u32x2 lo, hi;
      lo[0] = wk[0]; lo[1] = wk[1]; hi[0] = wk[2]; hi[1] = wk[3];
      *(u32x2*)&skT[cb][sgp][(8 + g_st) * 4]     = lo;
      *(u32x2*)&skT[cb][sgp + 1][(8 + g_st) * 4] = hi;
      lo[0] = wq[0]; lo[1] = wq[1]; hi[0] = wq[2]; hi[1] = wq[3];
      *(u32x2*)&sqT[cb][sgp][(8 + g_st) * 4]     = lo;
      *(u32x2*)&sqT[cb][sgp + 1][(8 + g_st) * 4] = hi;
    }
    if (lane < 32) {
#pragma unroll
      for (int r = 0; r < 4; ++r) svaT[cb][va_vh][r][va_st] = pva[r];
    }
  };

  fetch(0); commit(0);

  f32x2 S20 = {0.f, 0.f}, S21 = {0.f, 0.f};
  f32x2 Sold0 = {0.f, 0.f}, Sold1 = {0.f, 0.f};
  float u = 0.f, cc = 0.f, aprev = 0.f;

  auto unpk = [&](unsigned int w) -> f32x2 {
    f32x2 r; r[0] = bcf(w << 16); r[1] = bcf(w & 0xffff0000u); return r;
  };

  for (int c = 0; c < 128; ++c) {
    const int buf = c & 1;
    const bool hasNext = (c + 1 < 128);

    if (hasNext) fetch((c + 1) * 16);   // VMEM issued first

    // ---- 3-set pipeline over eight 2-step groups ----
    u32x4 kA, qA, kB, qB, kC, qC;
    unsigned int vA, aA, vB, aB, vC, aC;
    f32x2 bA, gA, bB, gB, bC, gC;

    LOADG(kA, qA, vA, aA, bA, gA, 0)
    LOADG(kB, qB, vB, aB, bB, gB, 1)
    LOADG(kC, qC, vC, aC, bC, gC, 2)

    // chunk preamble: u for step 0 = Sold . k_0
    f32x2 k2c0 = unpk(kA[0]);
    f32x2 k2c1 = unpk(kA[1]);
    {
      f32x2 dd = Sold0 * k2c0;
      dd += Sold1 * k2c1;
      float un = dd[0] + dd[1];
      un += dpp_f<0xB1>(un);
      un += dpp_f<0x4E>(un);
      un += dpp_f<0x141>(un);
      un += dpp_f<0x140>(un);
      u = un;   // c==0: Sold=0 -> u=0, correct
    }

    SCAN_STEP(0,  kA[2], kA[3], qA[0], qA[1], vA, aA, bA[0], gA[0], false)
    SCAN_STEP(1,  kB[0], kB[1], qA[2], qA[3], vA, aA, bA[1], gA[1], false)
    LOADG(kA, qA, vA, aA, bA, gA, 3)
    SCAN_STEP(2,  kB[2], kB[3], qB[0], qB[1], vB, aB, bB[0], gB[0], false)
    SCAN_STEP(3,  kC[0], kC[1], qB[2], qB[3], vB, aB, bB[1], gB[1], false)
    LOADG(kB, qB, vB, aB, bB, gB, 4)
    SCAN_STEP(4,  kC[2], kC[3], qC[0], qC[1], vC, aC, bC[0], gC[0], false)
    SCAN_STEP(5,  kA[0], kA[1], qC[2], qC[3], vC, aC, bC[1], gC[1], false)  // kA = g3
    LOADG(kC, qC, vC, aC, bC, gC, 5)
    SCAN_STEP(6,  kA[2], kA[3], qA[0], qA[1], vA, aA, bA[0], gA[0], false)  // g3
    SCAN_STEP(7,  kB[0], kB[1], qA[2], qA[3], vA, aA, bA[1], gA[1], false)  // kB = g4
    LOADG(kA, qA, vA, aA, bA, gA, 6)
    SCAN_STEP(8,  kB[2], kB[3], qB[0], qB[1], vB, aB, bB[0], gB[0], false)  // g4
    SCAN_STEP(9,  kC[0], kC[1], qB[2], qB[3], vB, aB, bB[1], gB[1], false)  // kC = g5
    LOADG(kB, qB, vB, aB, bB, gB, 7)
    SCAN_STEP(10, kC[2], kC[3], qC[0], qC[1], vC, aC, bC[0], gC[0], false)  // g5
    SCAN_STEP(11, kA[0], kA[1], qC[2], qC[3], vC, aC, bC[1], gC[1], false)  // kA = g6
    SCAN_STEP(12, kA[2], kA[3], qA[0], qA[1], vA, aA, bA[0], gA[0], false)  // g6
    SCAN_STEP(13, kB[0], kB[1], qA[2], qA[3], vA, aA, bA[1], gA[1], false)  // kB = g7
    SCAN_STEP(14, kB[2], kB[3], qB[0], qB[1], vB, aB, bB[0], gB[0], false)  // g7
    SCAN_STEP(15, kB[2], kB[3], qB[2], qB[3], vB, aB, bB[1], gB[1], true)   // LAST

    // deferred output reduction + coalesced store (single wave: ds-ordered)
    {
      int st = lane >> 2, rr = lane & 3;      // 64 outputs: 16 steps x 4 rows
      float4 A0 = *(const float4*)&so[st][rr * 16];
      float4 A1 = *(const float4*)&so[st][rr * 16 + 4];
      float4 A2 = *(const float4*)&so[st][rr * 16 + 8];
      float4 A3 = *(const float4*)&so[st][rr * 16 + 12];
      float s = (((A0.x + A0.y) + (A0.z + A0.w)) + ((A1.x + A1.y) + (A1.z + A1.w)))
              + (((A2.x + A2.y) + (A2.z + A2.w)) + ((A3.x + A3.y) + (A3.z + A3.w)));
      so2[st][rr] = cvt_bf16(s);
    }
    if (lane < 16)
      *(bf16x4v*)((__bf16*)o + bva + (size_t)(c * 16 + lane) * 1024) =
          *(const bf16x4v*)&so2[lane][0];

    if (hasNext) commit(buf ^ 1);
  }
}

// LayerNorm over DV=64 per (b,t,h) row, *ln_w+ln_b, *gate -> bf16
__global__ __launch_bounds__(256) void ln_gate_kernel(
    const bf16* __restrict__ o, const bf16* __restrict__ g,
    const float* __restrict__ lnw, const float* __restrict__ lnb,
    bf16* __restrict__ out)
{
  int row = blockIdx.x * 4 + (threadIdx.x >> 6);
  int lane = threadIdx.x & 63;
  size_t idx = (size_t)row * 64 + lane;
  float xv = (float)o[idx];
  float mu = xv;
#pragma unroll
  for (int s = 1; s < 64; s <<= 1) mu += __shfl_xor(mu, s);
  mu *= (1.f / 64.f);
  float d = xv - mu;
  float vv = d * d;
#pragma unroll
  for (int s = 1; s < 64; s <<= 1) vv += __shfl_xor(vv, s);
  vv *= (1.f / 64.f);
  float y = d * rsqrtf(vv + 1e-5f) * lnw[lane] + lnb[lane];
  y *= (float)g[idx];
  out[idx] = (bf16)y;
}

extern "C" void kernel_launch(void* const* d_in, const int* in_sizes, int n_in,
                              void* d_out, int out_size, void* d_ws, size_t ws_size,
                              hipStream_t stream)
{
  const float* x   = (const float*)d_in[0];
  const float* Wq  = (const float*)d_in[1];
  const float* Wk  = (const float*)d_in[2];
  const float* Wv  = (const float*)d_in[3];
  const float* Wa  = (const float*)d_in[4];
  const float* ba  = (const float*)d_in[5];
  const float* Wb  = (const float*)d_in[6];
  const float* bb  = (const float*)d_in[7];
  const float* Wg  = (const float*)d_in[8];
  const float* Wo  = (const float*)d_in[9];
  const float* qcw = (const float*)d_in[10];
  const float* qcb = (const float*)d_in[11];
  const float* kcw = (const float*)d_in[12];
  const float* kcb = (const float*)d_in[13];
  const float* vcw = (const float*)d_in[14];
  const float* vcb = (const float*)d_in[15];
  const float* lnw = (const float*)d_in[16];
  const float* lnb = (const float*)d_in[17];

  const int M = 4096, HID = 1024;
  const size_t PLANE = (size_t)M * HID;
  const size_t PB = PLANE * sizeof(bf16);          // 8 MB bf16 plane

  char* ws = (char*)d_ws;
  float* outf = (float*)d_out;
  const bool rich = (ws_size >= 5 * PB + 1024);

  dim3 blk(256);
  dim3 g8(8, 32);
  int nconv = (int)((size_t)M * 128 / 256);          // x8-vectorized conv grid

  if (rich) {
    bf16* P0 = (bf16*)(ws);
    bf16* P1 = (bf16*)(ws + PB);
    bf16* P2 = (bf16*)(ws + 2 * PB);
    bf16* P3 = (bf16*)(ws + 3 * PB);
    bf16* P4 = (bf16*)(ws + 4 * PB);
    bf16*  xb    = (bf16*)d_out;                          // [0,8M): x bf16, dead after mega
    bf16*  W4b   = (bf16*)((char*)d_out + 8 * 1024 * 1024); // [8M,16M): dead after mega
    bf16*  Kb    = xb;                                    // k-plane reuses [0,8M)
    bf16*  Qb    = W4b;                                   // q-plane reuses [8M,16M)
    float* betab = (float*)P4;                            // P4[0,256K)
    float* gkk   = (float*)((char*)P4 + 256 * 1024);      // P4[256K,512K)
    bf16*  Wgb   = (bf16*)((char*)P4 + 1024 * 1024);      // P4[1M,3M)
    bf16*  Wob   = (bf16*)((char*)P4 + 3 * 1024 * 1024);  // P4[3M,5M)

    // 1. convert x + 6 weight matrices to bf16
    cvtw_kernel<<<10240, blk, 0, stream>>>(x, Wq, Wk, Wv, Wa, Wg, Wo,
                                           xb, W4b, Wgb, Wob);
    // 2. fused 4-projection + beta GEMM: zq->P0 zk->P1 zv->P2 a->P3, betab->P4
    mega_gemm2<<<dim3(33, 32), blk, 0, stream>>>(xb, W4b, Wb, bb, ba, P0, betab);
    // 3-5. convs (xb, W4b dead now)
    conv_silu_kernel<<<nconv, blk, 0, stream>>>(P0, qcw, qcb, Qb, 1.f);     // q->[8M,16M)
    conv_silu_kernel<<<nconv, blk, 0, stream>>>(P1, kcw, kcb, Kb, 0.125f);  // k->[0,8M)
    conv_silu_kernel<<<nconv, blk, 0, stream>>>(P2, vcw, vcb, P1, 1.f);     // v->P1
    // 6. G = beta * (k_{t-1}.k_t)
    kk_kernel<<<1024, blk, 0, stream>>>(Kb, betab, gkk);
    // 7. FUSED scan (o->P0) + g-GEMM (sigmoid(x@Wgb^T)->P2)
    scan_gemm_kernel<<<768, blk, 0, stream>>>(Qb, Kb, P1, P3, betab, gkk, P0,
                                              x, Wgb, P2);
    // 8. LN + gate -> P1
    ln_gate_kernel<<<M * 16 / 4, blk, 0, stream>>>(P0, P2, lnw, lnb, P1);
    // 9. final: out = P1 @ Wob^T (both bf16 async; overwrites d_out scratch)
    gemm_bb<<<g8, blk, 0, stream>>>(P1, Wob, outf);
  } else {
    bf16* P  = (bf16*)(ws);
    bf16* qb = (bf16*)(ws + PB);
    bf16* kb = (bf16*)(ws + 2 * PB);
    bf16* vb = (bf16*)(ws + 3 * PB);
    float* betab = (float*)d_out;
    float* gkk   = (float*)((char*)d_out + 256 * 1024);
    bf16*  ob    = (bf16*)((char*)d_out + 8 * 1024 * 1024);

    gemm_bt<2, true><<<g8, blk, 0, stream>>>(x, Wq, nullptr, nullptr, P, M, HID, HID);
    conv_silu_kernel<<<nconv, blk, 0, stream>>>(P, qcw, qcb, qb, 1.f);
    gemm_bt<2, true><<<g8, blk, 0, stream>>>(x, Wk, nullptr, nullptr, P, M, HID, HID);
    conv_silu_kernel<<<nconv, blk, 0, stream>>>(P, kcw, kcb, kb, 0.125f);
    gemm_bt<2, true><<<g8, blk, 0, stream>>>(x, Wv, nullptr, nullptr, P, M, HID, HID);
    conv_silu_kernel<<<nconv, blk, 0, stream>>>(P, vcw, vcb, vb, 1.f);
    gemm_bt<3, true><<<g8, blk, 0, stream>>>(x, Wa, ba, nullptr, P, M, HID, HID);
    gemm_bt<5, true><<<dim3(1, 32), blk, 0, stream>>>(x, Wb, bb, betab, nullptr, M, 16, HID);
    kk_kernel<<<1024, blk, 0, stream>>>(kb, betab, gkk);
    scan_gemm_kernel<<<512, blk, 0, stream>>>(qb, kb, vb, P, betab, gkk, ob,
                                              x, nullptr, nullptr);
    gemm_bt<3, true><<<g8, blk, 0, stream>>>(x, Wg, nullptr, nullptr, qb, M, HID, HID);
    ln_gate_kernel<<<M * 16 / 4, blk, 0, stream>>>(ob, qb, lnw, lnb, kb);
    gemm_bt<4, false><<<g8, blk, 0, stream>>>(kb, Wo, nullptr, outf, nullptr, M, HID, HID);
  }
}

// Round 12
// 457.381 us; speedup vs baseline: 1.5270x; 1.0074x over previous
//
#include <hip/hip_runtime.h>
#include <hip/hip_bf16.h>
#include <cstdint>

// B=2, T=2048, HID=1024, H=16, DK=DV=64, K(conv)=4. fp32 in/out.
// RICH memory plan (ws >= 40MB): ws = P0..P4 (8MB bf16 planes).
//  d_out[0,8M): xb -> Kb (k-plane);  d_out[8M,16M): W4b -> Qb (q-plane)
//  P4: [0,256K) betab fp32; [256K,512K) gkk; [1M,3M) Wgb; [3M,5M) Wob
//  P0: zq -> scan o;  P1: zk -> v-plane;  P2: zv -> g-plane;  P3: a plane
// Launches (6): cvtw -> mega_gemm2(+beta) -> conv2(q,k) -> convv_kk
//   -> FUSED scan+g-GEMM -> gemm_bb_ln (final GEMM with LN+gate fused).
//
// R12: dispatch consolidation 9->6. conv_q+conv_k one launch (disjoint
// planes); conv_v+kk one launch (kk reads prior launch's k); ln_gate folded
// into the final GEMM's A-staging (per-head 64-slab LN into padded As2).
// Scan: R9-proven form, untouched.

using bf16 = __hip_bfloat16;
typedef __bf16 bf16x8 __attribute__((ext_vector_type(8)));
typedef __bf16 bf16x4v __attribute__((ext_vector_type(4)));
typedef float f32x4 __attribute__((ext_vector_type(4)));
typedef float f32x2 __attribute__((ext_vector_type(2)));
typedef unsigned int u32x4 __attribute__((ext_vector_type(4)));
typedef unsigned int u32x2 __attribute__((ext_vector_type(2)));

__device__ __forceinline__ __bf16 cvt_bf16(float f) {
  __hip_bfloat16 h = (__hip_bfloat16)f;
  return *reinterpret_cast<__bf16*>(&h);
}
__device__ __forceinline__ void async_copy16(const void* g, void* l) {
  __builtin_amdgcn_global_load_lds((const __attribute__((address_space(1))) void*)g,
                                   (__attribute__((address_space(3))) void*)l,
                                   16, 0, 0);
}
__device__ __forceinline__ float bcf(unsigned int u) { return __builtin_bit_cast(float, u); }
template <int CTRL>
__device__ __forceinline__ float dpp_f(float x) {
  int y = __builtin_amdgcn_update_dpp(0, __builtin_bit_cast(int, x), CTRL, 0xF, 0xF, true);
  return __builtin_bit_cast(float, y);
}

// fp32 -> bf16: x (blocks 0..4095), W4 (4096..8191), Wg (8192..9215),
// Wo (9216..10239).
__global__ __launch_bounds__(256) void cvtw_kernel(
    const float* __restrict__ x, const float* __restrict__ Wq,
    const float* __restrict__ Wk, const float* __restrict__ Wv,
    const float* __restrict__ Wa, const float* __restrict__ Wg,
    const float* __restrict__ Wo, bf16* __restrict__ xb,
    bf16* __restrict__ w4b, bf16* __restrict__ wgb, bf16* __restrict__ wob)
{
  int blk = blockIdx.x;
  const float* src;
  __bf16* dst;
  size_t off;
  if (blk < 4096) {
    src = x; dst = (__bf16*)xb;
    off = (size_t)blk * 1024 + threadIdx.x * 4;
  } else if (blk < 8192) {
    int wb = blk - 4096;
    int wi = wb >> 10;
    src = (wi == 0) ? Wq : (wi == 1) ? Wk : (wi == 2) ? Wv : Wa;
    dst = (__bf16*)w4b + (size_t)wi * 1024 * 1024;
    off = (size_t)(wb & 1023) * 1024 + threadIdx.x * 4;
  } else if (blk < 9216) {
    src = Wg; dst = (__bf16*)wgb;
    off = (size_t)(blk - 8192) * 1024 + threadIdx.x * 4;
  } else {
    src = Wo; dst = (__bf16*)wob;
    off = (size_t)(blk - 9216) * 1024 + threadIdx.x * 4;
  }
  float4 f = *(const float4*)(src + off);
  bf16x4v t;
  t[0] = cvt_bf16(f.x); t[1] = cvt_bf16(f.y); t[2] = cvt_bf16(f.z); t[3] = cvt_bf16(f.w);
  *(bf16x4v*)(dst + off) = t;
}

// C = A * Bt^T. A: MxK (bf16 async-staged unless A_FP32); Bt: NxK fp32.
// MODE 2: raw->bf16; 3: sigmoid(acc+bias)->bf16; 4: raw->fp32; 5: sigmoid(acc+bias)->fp32 TRANSPOSED
template <int MODE, bool A_FP32>
__global__ __launch_bounds__(256) void gemm_bt(
    const void* __restrict__ Av, const float* __restrict__ Bt,
    const float* __restrict__ bias, float* __restrict__ Cf, bf16* __restrict__ Cb,
    int M, int N, int K)
{
  __shared__ __align__(16) __bf16 As[128 * 32];
  __shared__ __align__(16) __bf16 Bs[128 * 32];

  const int tid  = threadIdx.x;
  const int lane = tid & 63;
  const int wave = tid >> 6;
  const int tile_m = blockIdx.y * 128;
  const int tile_n = blockIdx.x * 128;
  const int wm = (wave >> 1) * 64;
  const int wn = (wave & 1) * 64;

  const int srow = lane >> 2;
  const int scol = (lane & 3) * 8;

  f32x4 acc[4][4];
#pragma unroll
  for (int i = 0; i < 4; ++i)
#pragma unroll
    for (int j = 0; j < 4; ++j) acc[i][j] = {0.f, 0.f, 0.f, 0.f};

  for (int k0 = 0; k0 < K; k0 += 32) {
    float4 b0[2], b1[2], a0[2], a1[2];
#pragma unroll
    for (int s = 0; s < 2; ++s) {
      int brow = tile_n + s * 64 + wave * 16 + srow;
      if (brow > N - 1) brow = N - 1;
      const float* bp = Bt + (size_t)brow * K + k0 + scol;
      b0[s] = *(const float4*)bp;
      b1[s] = *(const float4*)(bp + 4);
      if (A_FP32) {
        int arow = tile_m + s * 64 + wave * 16 + srow;
        const float* ap = (const float*)Av + (size_t)arow * K + k0 + scol;
        a0[s] = *(const float4*)ap;
        a1[s] = *(const float4*)(ap + 4);
      }
    }
    __syncthreads();
#pragma unroll
    for (int s = 0; s < 2; ++s) {
      if (!A_FP32) {
        int arow = tile_m + s * 64 + wave * 16 + srow;
        async_copy16((const __bf16*)Av + (size_t)arow * K + k0 + scol,
                     &As[(s * 64 + wave * 16 + srow) * 32 + scol]);
      } else {
        bf16x8 ua;
        ua[0] = cvt_bf16(a0[s].x); ua[1] = cvt_bf16(a0[s].y);
        ua[2] = cvt_bf16(a0[s].z); ua[3] = cvt_bf16(a0[s].w);
        ua[4] = cvt_bf16(a1[s].x); ua[5] = cvt_bf16(a1[s].y);
        ua[6] = cvt_bf16(a1[s].z); ua[7] = cvt_bf16(a1[s].w);
        *(bf16x8*)&As[(s * 64 + wave * 16 + srow) * 32 + scol] = ua;
      }
      bf16x8 u;
      u[0] = cvt_bf16(b0[s].x); u[1] = cvt_bf16(b0[s].y);
      u[2] = cvt_bf16(b0[s].z); u[3] = cvt_bf16(b0[s].w);
      u[4] = cvt_bf16(b1[s].x); u[5] = cvt_bf16(b1[s].y);
      u[6] = cvt_bf16(b1[s].z); u[7] = cvt_bf16(b1[s].w);
      *(bf16x8*)&Bs[(s * 64 + wave * 16 + srow) * 32 + scol] = u;
    }
    __syncthreads();

    bf16x8 af[4], bfr[4];
#pragma unroll
    for (int i = 0; i < 4; ++i)
      af[i] = *(const bf16x8*)&As[(wm + i * 16 + (lane & 15)) * 32 + (lane >> 4) * 8];
#pragma unroll
    for (int j = 0; j < 4; ++j)
      bfr[j] = *(const bf16x8*)&Bs[(wn + j * 16 + (lane & 15)) * 32 + (lane >> 4) * 8];

#pragma unroll
    for (int i = 0; i < 4; ++i)
#pragma unroll
      for (int j = 0; j < 4; ++j)
        acc[i][j] = __builtin_amdgcn_mfma_f32_16x16x32_bf16(af[i], bfr[j], acc[i][j], 0, 0, 0);
  }

#pragma unroll
  for (int i = 0; i < 4; ++i) {
#pragma unroll
    for (int j = 0; j < 4; ++j) {
#pragma unroll
      for (int r = 0; r < 4; ++r) {
        int gm = tile_m + wm + i * 16 + (lane >> 4) * 4 + r;
        int gn = tile_n + wn + j * 16 + (lane & 15);
        if (gn < N) {
          float val = acc[i][j][r];
          if (MODE == 3 || MODE == 5) {
            float bv = bias ? bias[gn] : 0.f;
            val = 1.f / (1.f + __expf(-(val + bv)));
          }
          if (MODE == 4)      Cf[(size_t)gm * N + gn] = val;
          else if (MODE == 5) Cf[(size_t)gn * M + gm] = val;
          else                Cb[(size_t)gm * N + gn] = (bf16)val;
        }
      }
    }
  }
}

// Final GEMM with fused LN+gate on the A operand.
// C(fp32)[4096][1024] = LN_gate(o,g)[4096][1024] @ Wob[1024][1024]^T.
// Per 64-wide k-slab (= head h): load o/g slab (128 rows x 64), LN per row
// (two-pass, same numerics as ln_gate), *gate -> As2[128][72] (padded),
// then 2 k-steps of MFMA vs async-staged Wob. Grid (8,32).
__global__ __launch_bounds__(256) void gemm_bb_ln(
    const bf16* __restrict__ o, const bf16* __restrict__ g,
    const float* __restrict__ lnw, const float* __restrict__ lnb,
    const bf16* __restrict__ Bw, float* __restrict__ C)
{
  __shared__ __align__(16) __bf16 As2[128][72];   // 18 KB (72-pad: ~2-way banks)
  __shared__ __align__(16) __bf16 Bs[128 * 32];   // 8 KB
  __shared__ float sW[64], sB[64];

  const int tid  = threadIdx.x;
  const int lane = tid & 63;
  const int wave = tid >> 6;
  const int tile_m = blockIdx.y * 128;
  const int tile_n = blockIdx.x * 128;
  const int wm = (wave >> 1) * 64;
  const int wn = (wave & 1) * 64;
  const int srow = lane >> 2;
  const int scol = (lane & 3) * 8;
  const int rl = tid >> 1;            // local A row 0..127
  const int half = tid & 1;           // column half (0..31 / 32..63)

  if (tid < 64) { sW[tid] = lnw[tid]; sB[tid] = lnb[tid]; }

  f32x4 acc[4][4];
#pragma unroll
  for (int i = 0; i < 4; ++i)
#pragma unroll
    for (int j = 0; j < 4; ++j) acc[i][j] = {0.f, 0.f, 0.f, 0.f};

  for (int h = 0; h < 16; ++h) {
    __syncthreads();   // prior slab's reads of As2/Bs complete (+ sW visible)

    // ---- LN + gate for slab h -> As2 ----
    const __bf16* op = (const __bf16*)o + (size_t)(tile_m + rl) * 1024 + h * 64 + half * 32;
    const __bf16* gp = (const __bf16*)g + (size_t)(tile_m + rl) * 1024 + h * 64 + half * 32;
    bf16x8 ov0 = *(const bf16x8*)(op);
    bf16x8 ov1 = *(const bf16x8*)(op + 8);
    bf16x8 ov2 = *(const bf16x8*)(op + 16);
    bf16x8 ov3 = *(const bf16x8*)(op + 24);
    bf16x8 gv0 = *(const bf16x8*)(gp);
    bf16x8 gv1 = *(const bf16x8*)(gp + 8);
    bf16x8 gv2 = *(const bf16x8*)(gp + 16);
    bf16x8 gv3 = *(const bf16x8*)(gp + 24);

    float sum = 0.f;
#pragma unroll
    for (int e = 0; e < 8; ++e)
      sum += (float)ov0[e] + (float)ov1[e] + (float)ov2[e] + (float)ov3[e];
    sum += __shfl_xor(sum, 1);
    float mu = sum * (1.f / 64.f);
    float vv = 0.f;
#pragma unroll
    for (int e = 0; e < 8; ++e) {
      float d0 = (float)ov0[e] - mu, d1 = (float)ov1[e] - mu;
      float d2 = (float)ov2[e] - mu, d3 = (float)ov3[e] - mu;
      vv += d0 * d0 + d1 * d1 + d2 * d2 + d3 * d3;
    }
    vv += __shfl_xor(vv, 1);
    float rstd = rsqrtf(vv * (1.f / 64.f) + 1e-5f);

    bf16x8 res0, res1, res2, res3;
#pragma unroll
    for (int e = 0; e < 8; ++e) {
      int c0 = half * 32 + e;
      res0[e] = cvt_bf16((((float)ov0[e] - mu) * rstd * sW[c0] + sB[c0]) * (float)gv0[e]);
      res1[e] = cvt_bf16((((float)ov1[e] - mu) * rstd * sW[c0 + 8] + sB[c0 + 8]) * (float)gv1[e]);
      res2[e] = cvt_bf16((((float)ov2[e] - mu) * rstd * sW[c0 + 16] + sB[c0 + 16]) * (float)gv2[e]);
      res3[e] = cvt_bf16((((float)ov3[e] - mu) * rstd * sW[c0 + 24] + sB[c0 + 24]) * (float)gv3[e]);
    }
    *(bf16x8*)&As2[rl][half * 32 + 0]  = res0;
    *(bf16x8*)&As2[rl][half * 32 + 8]  = res1;
    *(bf16x8*)&As2[rl][half * 32 + 16] = res2;
    *(bf16x8*)&As2[rl][half * 32 + 24] = res3;

#pragma unroll
    for (int sub = 0; sub < 2; ++sub) {
      if (sub) __syncthreads();      // protect Bs restage from sub0 reads
      int k0 = h * 64 + sub * 32;
#pragma unroll
      for (int s = 0; s < 2; ++s) {
        int brow = tile_n + s * 64 + wave * 16 + srow;
        async_copy16((const __bf16*)Bw + (size_t)brow * 1024 + k0 + scol,
                     &Bs[(s * 64 + wave * 16 + srow) * 32 + scol]);
      }
      __syncthreads();               // Bs landed + As2 visible

      bf16x8 af[4], bfr[4];
#pragma unroll
      for (int i = 0; i < 4; ++i)
        af[i] = *(const bf16x8*)&As2[wm + i * 16 + (lane & 15)][(lane >> 4) * 8 + sub * 32];
#pragma unroll
      for (int j = 0; j < 4; ++j)
        bfr[j] = *(const bf16x8*)&Bs[(wn + j * 16 + (lane & 15)) * 32 + (lane >> 4) * 8];

#pragma unroll
      for (int i = 0; i < 4; ++i)
#pragma unroll
        for (int j = 0; j < 4; ++j)
          acc[i][j] = __builtin_amdgcn_mfma_f32_16x16x32_bf16(af[i], bfr[j], acc[i][j], 0, 0, 0);
    }
  }

#pragma unroll
  for (int i = 0; i < 4; ++i)
#pragma unroll
    for (int j = 0; j < 4; ++j)
#pragma unroll
      for (int r = 0; r < 4; ++r) {
        int gm = tile_m + wm + i * 16 + (lane >> 4) * 4 + r;
        int gn = tile_n + wn + j * 16 + (lane & 15);
        C[(size_t)gm * 1024 + gn] = acc[i][j][r];
      }
}

// Fused 4-projection + beta GEMM. Grid (33,32).
__global__ __launch_bounds__(256) void mega_gemm2(
    const bf16* __restrict__ Av, const bf16* __restrict__ W4b,
    const float* __restrict__ Wb, const float* __restrict__ bb,
    const float* __restrict__ ba, bf16* __restrict__ C4,
    float* __restrict__ betab)
{
  __shared__ __align__(16) __bf16 As[128 * 32];
  __shared__ __align__(16) __bf16 Bs[128 * 32];

  const int tid  = threadIdx.x;
  const int lane = tid & 63;
  const int wave = tid >> 6;
  const int tile_m = blockIdx.y * 128;
  const bool isbeta = (blockIdx.x >= 32);
  const int tile_n = isbeta ? 0 : blockIdx.x * 128;
  const int grp = tile_n >> 10;
  const int tnl = tile_n & 1023;
  const int wm = (wave >> 1) * 64;
  const int wn = (wave & 1) * 64;

  const int srow = lane >> 2;
  const int scol = (lane & 3) * 8;

  f32x4 acc[4][4];
#pragma unroll
  for (int i = 0; i < 4; ++i)
#pragma unroll
    for (int j = 0; j < 4; ++j) acc[i][j] = {0.f, 0.f, 0.f, 0.f};

  const __bf16* Wp = (const __bf16*)W4b + (size_t)grp * 1024 * 1024;

  for (int k0 = 0; k0 < 1024; k0 += 32) {
    float4 b0[2], b1[2];
    if (isbeta) {
#pragma unroll
      for (int s = 0; s < 2; ++s) {
        int brow = s * 64 + wave * 16 + srow;
        if (brow > 15) brow = 15;
        const float* bp = Wb + (size_t)brow * 1024 + k0 + scol;
        b0[s] = *(const float4*)bp;
        b1[s] = *(const float4*)(bp + 4);
      }
    }
    __syncthreads();
#pragma unroll
    for (int s = 0; s < 2; ++s) {
      int arow = tile_m + s * 64 + wave * 16 + srow;
      async_copy16((const __bf16*)Av + (size_t)arow * 1024 + k0 + scol,
                   &As[(s * 64 + wave * 16 + srow) * 32 + scol]);
      if (!isbeta) {
        int brow = tnl + s * 64 + wave * 16 + srow;
        async_copy16(Wp + (size_t)brow * 1024 + k0 + scol,
                     &Bs[(s * 64 + wave * 16 + srow) * 32 + scol]);
      } else {
        bf16x8 u;
        u[0] = cvt_bf16(b0[s].x); u[1] = cvt_bf16(b0[s].y);
        u[2] = cvt_bf16(b0[s].z); u[3] = cvt_bf16(b0[s].w);
        u[4] = cvt_bf16(b1[s].x); u[5] = cvt_bf16(b1[s].y);
        u[6] = cvt_bf16(b1[s].z); u[7] = cvt_bf16(b1[s].w);
        *(bf16x8*)&Bs[(s * 64 + wave * 16 + srow) * 32 + scol] = u;
      }
    }
    __syncthreads();

    bf16x8 af[4], bfr[4];
#pragma unroll
    for (int i = 0; i < 4; ++i)
      af[i] = *(const bf16x8*)&As[(wm + i * 16 + (lane & 15)) * 32 + (lane >> 4) * 8];
#pragma unroll
    for (int j = 0; j < 4; ++j)
      bfr[j] = *(const bf16x8*)&Bs[(wn + j * 16 + (lane & 15)) * 32 + (lane >> 4) * 8];

#pragma unroll
    for (int i = 0; i < 4; ++i)
#pragma unroll
      for (int j = 0; j < 4; ++j)
        acc[i][j] = __builtin_amdgcn_mfma_f32_16x16x32_bf16(af[i], bfr[j], acc[i][j], 0, 0, 0);
  }

  if (!isbeta) {
    bf16* Cp = (bf16*)((__bf16*)C4 + (size_t)grp * 4096 * 1024);
#pragma unroll
    for (int i = 0; i < 4; ++i)
#pragma unroll
      for (int j = 0; j < 4; ++j)
#pragma unroll
        for (int r = 0; r < 4; ++r) {
          int gm = tile_m + wm + i * 16 + (lane >> 4) * 4 + r;
          int col = tnl + wn + j * 16 + (lane & 15);
          float val = acc[i][j][r];
          if (grp == 3) val = 1.f / (1.f + __expf(-(val + ba[col])));
          ((__bf16*)Cp)[(size_t)gm * 1024 + col] = cvt_bf16(val);
        }
  } else {
#pragma unroll
    for (int i = 0; i < 4; ++i)
#pragma unroll
      for (int j = 0; j < 4; ++j)
#pragma unroll
        for (int r = 0; r < 4; ++r) {
          int gm = tile_m + wm + i * 16 + (lane >> 4) * 4 + r;
          int gn = wn + j * 16 + (lane & 15);
          if (gn < 16) {
            float val = 1.f / (1.f + __expf(-(acc[i][j][r] + bb[gn])));
            betab[(size_t)gn * 4096 + gm] = val;
          }
        }
  }
}

// shared conv body: causal depthwise K=4 + bias + SiLU (+scale), x8 vec.
__device__ __forceinline__ void conv_body(
    int idx, const bf16* __restrict__ z, const float* __restrict__ w,
    const float* __restrict__ bias, bf16* __restrict__ out, float scale)
{
  int c8 = idx & 127;
  int m  = idx >> 7;
  int t  = m & 2047;
  int c0 = c8 * 8;

  const __bf16* base = (const __bf16*)z + (size_t)m * 1024 + c0;
  const bf16x8 zzero = __builtin_bit_cast(bf16x8, (u32x4){0u, 0u, 0u, 0u});
  bf16x8 z3 = *(const bf16x8*)base;
  bf16x8 z2 = (t >= 1) ? *(const bf16x8*)(base - 1024) : zzero;
  bf16x8 z1 = (t >= 2) ? *(const bf16x8*)(base - 2048) : zzero;
  bf16x8 z0 = (t >= 3) ? *(const bf16x8*)(base - 3072) : zzero;

  const float* wp = w + c0 * 4;
  bf16x8 res;
#pragma unroll
  for (int e = 0; e < 8; ++e) {
    float4 we = *(const float4*)(wp + e * 4);
    float acc = bias[c0 + e] + (float)z3[e] * we.w;
    acc += (float)z2[e] * we.z;
    acc += (float)z1[e] * we.y;
    acc += (float)z0[e] * we.x;
    float s = acc / (1.f + __expf(-acc));
    res[e] = cvt_bf16(s * scale);
  }
  *(bf16x8*)((__bf16*)out + (size_t)m * 1024 + c0) = res;
}

// standalone conv (fallback path)
__global__ __launch_bounds__(256) void conv_silu_kernel(
    const bf16* __restrict__ z, const float* __restrict__ w,
    const float* __restrict__ bias, bf16* __restrict__ out, float scale)
{
  conv_body(blockIdx.x * 256 + threadIdx.x, z, w, bias, out, scale);
}

// conv_q + conv_k in one launch (disjoint planes). Grid 4096.
__global__ __launch_bounds__(256) void conv2_kernel(
    const bf16* __restrict__ zq, const bf16* __restrict__ zk,
    const float* __restrict__ qcw, const float* __restrict__ qcb,
    const float* __restrict__ kcw, const float* __restrict__ kcb,
    bf16* __restrict__ oq, bf16* __restrict__ ok)
{
  int sec = blockIdx.x >> 11;
  int bx  = blockIdx.x & 2047;
  int idx = bx * 256 + threadIdx.x;
  if (sec == 0) conv_body(idx, zq, qcw, qcb, oq, 1.f);
  else          conv_body(idx, zk, kcw, kcb, ok, 0.125f);
}

// conv_v + kk in one launch (kk reads k from PREVIOUS launch). Grid 3072.
__global__ __launch_bounds__(256) void convv_kk_kernel(
    const bf16* __restrict__ zv, const float* __restrict__ vcw,
    const float* __restrict__ vcb, bf16* __restrict__ ov,
    const bf16* __restrict__ k, const float* __restrict__ betab,
    float* __restrict__ G)
{
  if (blockIdx.x < 2048) {
    conv_body(blockIdx.x * 256 + threadIdx.x, zv, vcw, vcb, ov, 1.f);
    return;
  }
  int gtid = (blockIdx.x - 2048) * 256 + threadIdx.x;
  int out = gtid >> 2;           // h*4096 + m
  int j   = gtid & 3;
  int h = out >> 12;
  int m = out & 4095;
  int t = m & 2047;
  float s = 0.f;
  if (t > 0) {
    const __bf16* r1 = (const __bf16*)k + (size_t)m * 1024 + h * 64 + j * 16;
    const __bf16* r0 = r1 - 1024;
    bf16x8 a0 = *(const bf16x8*)r0;
    bf16x8 a1 = *(const bf16x8*)(r0 + 8);
    bf16x8 b0 = *(const bf16x8*)r1;
    bf16x8 b1 = *(const bf16x8*)(r1 + 8);
#pragma unroll
    for (int e = 0; e < 8; ++e)
      s += (float)a0[e] * (float)b0[e] + (float)a1[e] * (float)b1[e];
  }
  s += __shfl_xor(s, 1);
  s += __shfl_xor(s, 2);
  if (j == 0) G[out] = betab[out] * s;
}

// kk standalone (fallback)
__global__ __launch_bounds__(256) void kk_kernel(
    const bf16* __restrict__ k, const float* __restrict__ betab,
    float* __restrict__ G)
{
  int tid = blockIdx.x * 256 + threadIdx.x;
  int out = tid >> 2;
  int j   = tid & 3;
  int h = out >> 12;
  int m = out & 4095;
  int t = m & 2047;
  float s = 0.f;
  if (t > 0) {
    const __bf16* r1 = (const __bf16*)k + (size_t)m * 1024 + h * 64 + j * 16;
    const __bf16* r0 = r1 - 1024;
    bf16x8 a0 = *(const bf16x8*)r0;
    bf16x8 a1 = *(const bf16x8*)(r0 + 8);
    bf16x8 b0 = *(const bf16x8*)r1;
    bf16x8 b1 = *(const bf16x8*)(r1 + 8);
#pragma unroll
    for (int e = 0; e < 8; ++e)
      s += (float)a0[e] * (float)b0[e] + (float)a1[e] * (float)b1[e];
  }
  s += __shfl_xor(s, 1);
  s += __shfl_xor(s, 2);
  if (j == 0) G[out] = betab[out] * s;
}

// One scan step (constant word indices only).
#define SCAN_STEP(i, KN0, KN1, Q0, Q1, WV, WA, BT, GT, LAST)                  \
  {                                                                           \
    const float vr = ((i) & 1) ? bcf((WV) & 0xffff0000u) : bcf((WV) << 16);   \
    const float ar = ((i) & 1) ? bcf((WA) & 0xffff0000u) : bcf((WA) << 16);   \
    float unxt = 0.f;                                                         \
    f32x2 k2n0 = {0.f, 0.f}, k2n1 = {0.f, 0.f};                               \
    if (!(LAST)) {                                                            \
      k2n0 = unpk(KN0); k2n1 = unpk(KN1);                                     \
      f32x2 dd = S20 * k2n0; dd += S21 * k2n1;                                \
      unxt = dd[0] + dd[1];                                                   \
      unxt += dpp_f<0xB1>(unxt);  unxt += dpp_f<0x4E>(unxt);                  \
      unxt += dpp_f<0x141>(unxt); unxt += dpp_f<0x140>(unxt);                 \
    } else { Sold0 = S20; Sold1 = S21; }                                      \
    float A_ = (BT) * __builtin_fmaf(aprev, u, -vr);                          \
    cc = __builtin_fmaf(-cc, (GT), A_);                                       \
    f32x2 q20 = unpk(Q0), q21 = unpk(Q1);                                     \
    const f32x2 cc2 = {cc, cc}, arv = {ar, ar};                               \
    f32x2 oo;                                                                 \
    { f32x2 t0 = cc2 * k2c0; S20 = arv * S20 - t0; oo = S20 * q20;            \
      f32x2 t1 = cc2 * k2c1; S21 = arv * S21 - t1; oo += S21 * q21; }         \
    so[(i)][lane] = oo[0] + oo[1];                                            \
    aprev = ar;                                                               \
    if (!(LAST)) { k2c0 = k2n0; k2c1 = k2n1; u = unxt; }                      \
  }

// Load one 2-step group (g = 0..7) into a named set (14 regs).
#define LOADG(KS, QS, VS, AS, BS, GS, g)                                      \
  KS = *(const u32x4*)&skT[buf][sg][(g) * 8];                                 \
  QS = *(const u32x4*)&sqT[buf][sg][(g) * 8];                                 \
  VS = *(const unsigned int*)&svaT[buf][0][r4][(g) * 2];                      \
  AS = *(const unsigned int*)&svaT[buf][1][r4][(g) * 2];                      \
  BS = *(const f32x2*)&sbeta[c * 16 + (g) * 2];                               \
  GS = *(const f32x2*)&sG[c * 16 + (g) * 2];

// FUSED kernel: blocks 0..511 = delta-rule scan (single wave; threads>=64
// exit; NO barriers). Blocks 512..767 = g-GEMM: sigmoid(x @ Wgb^T) -> gout.
__global__ __launch_bounds__(256) void scan_gemm_kernel(
    const bf16* __restrict__ q, const bf16* __restrict__ k,
    const bf16* __restrict__ v, const bf16* __restrict__ a,
    const float* __restrict__ betab, const float* __restrict__ gkk,
    bf16* __restrict__ o,
    const float* __restrict__ x, const bf16* __restrict__ Wgb,
    bf16* __restrict__ gout)
{
  __shared__ __align__(16) __bf16 skT[2][16][72];
  __shared__ __align__(16) __bf16 sqT[2][16][72];
  __shared__ __align__(16) __bf16 svaT[2][2][4][16];
  __shared__ __align__(16) float  so[16][68];
  __shared__ __align__(16) __bf16 so2[16][4];
  __shared__ float sbeta[2048];
  __shared__ float sG[2048];
  __shared__ __align__(16) __bf16 As[128 * 32];
  __shared__ __align__(16) __bf16 Bs[128 * 32];

  if (blockIdx.x >= 512) {
    const int gb   = blockIdx.x - 512;
    const int tid  = threadIdx.x;
    const int lane = tid & 63;
    const int wave = tid >> 6;
    const int tile_m = (gb >> 3) * 128;
    const int tile_n = (gb & 7) * 128;
    const int wm = (wave >> 1) * 64;
    const int wn = (wave & 1) * 64;
    const int srow = lane >> 2;
    const int scol = (lane & 3) * 8;

    f32x4 acc[4][4];
#pragma unroll
    for (int i = 0; i < 4; ++i)
#pragma unroll
      for (int j = 0; j < 4; ++j) acc[i][j] = {0.f, 0.f, 0.f, 0.f};

    for (int k0 = 0; k0 < 1024; k0 += 32) {
      float4 a0[2], a1[2];
#pragma unroll
      for (int s = 0; s < 2; ++s) {
        int arow = tile_m + s * 64 + wave * 16 + srow;
        const float* ap = x + (size_t)arow * 1024 + k0 + scol;
        a0[s] = *(const float4*)ap;
        a1[s] = *(const float4*)(ap + 4);
      }
      __syncthreads();
#pragma unroll
      for (int s = 0; s < 2; ++s) {
        bf16x8 ua;
        ua[0] = cvt_bf16(a0[s].x); ua[1] = cvt_bf16(a0[s].y);
        ua[2] = cvt_bf16(a0[s].z); ua[3] = cvt_bf16(a0[s].w);
        ua[4] = cvt_bf16(a1[s].x); ua[5] = cvt_bf16(a1[s].y);
        ua[6] = cvt_bf16(a1[s].z); ua[7] = cvt_bf16(a1[s].w);
        *(bf16x8*)&As[(s * 64 + wave * 16 + srow) * 32 + scol] = ua;
        int brow = tile_n + s * 64 + wave * 16 + srow;
        async_copy16((const __bf16*)Wgb + (size_t)brow * 1024 + k0 + scol,
                     &Bs[(s * 64 + wave * 16 + srow) * 32 + scol]);
      }
      __syncthreads();

      bf16x8 af[4], bfr[4];
#pragma unroll
      for (int i = 0; i < 4; ++i)
        af[i] = *(const bf16x8*)&As[(wm + i * 16 + (lane & 15)) * 32 + (lane >> 4) * 8];
#pragma unroll
      for (int j = 0; j < 4; ++j)
        bfr[j] = *(const bf16x8*)&Bs[(wn + j * 16 + (lane & 15)) * 32 + (lane >> 4) * 8];

#pragma unroll
      for (int i = 0; i < 4; ++i)
#pragma unroll
        for (int j = 0; j < 4; ++j)
          acc[i][j] = __builtin_amdgcn_mfma_f32_16x16x32_bf16(af[i], bfr[j], acc[i][j], 0, 0, 0);
    }

#pragma unroll
    for (int i = 0; i < 4; ++i)
#pragma unroll
      for (int j = 0; j < 4; ++j)
#pragma unroll
        for (int r = 0; r < 4; ++r) {
          int gm = tile_m + wm + i * 16 + (lane >> 4) * 4 + r;
          int gn = tile_n + wn + j * 16 + (lane & 15);
          float val = 1.f / (1.f + __expf(-acc[i][j][r]));
          gout[(size_t)gm * 1024 + gn] = (bf16)val;
        }
    return;
  }

  // ---------------- scan path (single wave; extra waves exit) ----------------
  if (threadIdx.x >= 64) return;

  const int blk = blockIdx.x;
  const int qd = blk >> 5;
  const int bh = blk & 31;
  const int b = bh >> 4, h = bh & 15;
  const int lane = threadIdx.x;
  const int r4 = lane >> 4;
  const int sg = lane & 15;

  {
    const float* bp = betab + (size_t)h * 4096 + b * 2048;
    const float* gp = gkk   + (size_t)h * 4096 + b * 2048;
    for (int t = lane; t < 2048; t += 64) { sbeta[t] = bp[t]; sG[t] = gp[t]; }
  }

  const size_t bkq = (size_t)b * 2048 * 1024 + h * 64;
  const size_t bva = bkq + qd * 4;
  const __bf16* kp = (const __bf16*)k;
  const __bf16* qp = (const __bf16*)q;

  const int g_st = lane >> 3;
  const int g_cg = (lane & 7) * 8;
  const int sgp  = (lane & 7) * 2;
  const int va_vh = (lane >> 4) & 1;
  const int va_st = lane & 15;

  bf16x8 pk0, pk1, pq0, pq1;
  bf16x4v pva;
  auto fetch = [&](int t0) {
    int st0 = t0 + g_st, st1 = t0 + 8 + g_st;
    pk0 = *(const bf16x8*)(kp + bkq + (size_t)st0 * 1024 + g_cg);
    pk1 = *(const bf16x8*)(kp + bkq + (size_t)st1 * 1024 + g_cg);
    pq0 = *(const bf16x8*)(qp + bkq + (size_t)st0 * 1024 + g_cg);
    pq1 = *(const bf16x8*)(qp + bkq + (size_t)st1 * 1024 + g_cg);
    if (lane < 32) {
      const __bf16* src = va_vh ? (const __bf16*)a : (const __bf16*)v;
      pva = *(const bf16x4v*)(src + bva + (size_t)(t0 + va_st) * 1024);
    }
  };
  auto commit = [&](int cb) {
    {
      u32x4 wk = __builtin_bit_cast(u32x4, pk0);
      u32x4 wq = __builtin_bit_cast(u32x4, pq0);
      u32x2 lo, hi;
      lo[0] = wk[0]; lo[1] = wk[1]; hi[0] = wk[2]; hi[1] = wk[3];
      *(u32x2*)&skT[cb][sgp][g_st * 4]     = lo;
      *(u32x2*)&skT[cb][sgp + 1][g_st * 4] = hi;
      lo[0] = wq[0]; lo[1] = wq[1]; hi[0] = wq[2]; hi[1] = wq[3];
      *(u32x2*)&sqT[cb][sgp][g_st * 4]     = lo;
      *(u32x2*)&sqT[cb][sgp + 1][g_st * 4] = hi;
    }
    {
      u32x4 wk = __builtin_bit_cast(u32x4, pk1);
      u32x4 wq = __builtin_bit_cast(u32x4, pq1);
      u32x2 lo, hi;
      lo[0] = wk[0]; lo[1] = wk[1]; hi[0] = wk[2]; hi[1] = wk[3];
      *(u32x2*)&skT[cb][sgp][(8 + g_st) * 4]     = lo;
      *(u32x2*)&skT[cb][sgp + 1][(8 + g_st) * 4] = hi;
      lo[0] = wq[0]; lo[1] = wq[1]; hi[0] = wq[2]; hi[1] = wq[3];
      *(u32x2*)&sqT[cb][sgp][(8 + g_st) * 4]     = lo;
      *(u32x2*)&sqT[cb][sgp + 1][(8 + g_st) * 4] = hi;
    }
    if (lane < 32) {
#pragma unroll
      for (int r = 0; r < 4; ++r) svaT[cb][va_vh][r][va_st] = pva[r];
    }
  };

  fetch(0); commit(0);

  f32x2 S20 = {0.f, 0.f}, S21 = {0.f, 0.f};
  f32x2 Sold0 = {0.f, 0.f}, Sold1 = {0.f, 0.f};
  float u = 0.f, cc = 0.f, aprev = 0.f;

  auto unpk = [&](unsigned int w) -> f32x2 {
    f32x2 r; r[0] = bcf(w << 16); r[1] = bcf(w & 0xffff0000u); return r;
  };

  for (int c = 0; c < 128; ++c) {
    const int buf = c & 1;
    const bool hasNext = (c + 1 < 128);

    if (hasNext) fetch((c + 1) * 16);

    u32x4 kA, qA, kB, qB, kC, qC;
    unsigned int vA, aA, vB, aB, vC, aC;
    f32x2 bA, gA, bB, gB, bC, gC;

    LOADG(kA, qA, vA, aA, bA, gA, 0)
    LOADG(kB, qB, vB, aB, bB, gB, 1)
    LOADG(kC, qC, vC, aC, bC, gC, 2)

    f32x2 k2c0 = unpk(kA[0]);
    f32x2 k2c1 = unpk(kA[1]);
    {
      f32x2 dd = Sold0 * k2c0;
      dd += Sold1 * k2c1;
      float un = dd[0] + dd[1];
      un += dpp_f<0xB1>(un);
      un += dpp_f<0x4E>(un);
      un += dpp_f<0x141>(un);
      un += dpp_f<0x140>(un);
      u = un;
    }

    SCAN_STEP(0,  kA[2], kA[3], qA[0], qA[1], vA, aA, bA[0], gA[0], false)
    SCAN_STEP(1,  kB[0], kB[1], qA[2], qA[3], vA, aA, bA[1], gA[1], false)
    LOADG(kA, qA, vA, aA, bA, gA, 3)
    SCAN_STEP(2,  kB[2], kB[3], qB[0], qB[1], vB, aB, bB[0], gB[0], false)
    SCAN_STEP(3,  kC[0], kC[1], qB[2], qB[3], vB, aB, bB[1], gB[1], false)
    LOADG(kB, qB, vB, aB, bB, gB, 4)
    SCAN_STEP(4,  kC[2], kC[3], qC[0], qC[1], vC, aC, bC[0], gC[0], false)
    SCAN_STEP(5,  kA[0], kA[1], qC[2], qC[3], vC, aC, bC[1], gC[1], false)
    LOADG(kC, qC, vC, aC, bC, gC, 5)
    SCAN_STEP(6,  kA[2], kA[3], qA[0], qA[1], vA, aA, bA[0], gA[0], false)
    SCAN_STEP(7,  kB[0], kB[1], qA[2], qA[3], vA, aA, bA[1], gA[1], false)
    LOADG(kA, qA, vA, aA, bA, gA, 6)
    SCAN_STEP(8,  kB[2], kB[3], qB[0], qB[1], vB, aB, bB[0], gB[0], false)
    SCAN_STEP(9,  kC[0], kC[1], qB[2], qB[3], vB, aB, bB[1], gB[1], false)
    LOADG(kB, qB, vB, aB, bB, gB, 7)
    SCAN_STEP(10, kC[2], kC[3], qC[0], qC[1], vC, aC, bC[0], gC[0], false)
    SCAN_STEP(11, kA[0], kA[1], qC[2], qC[3], vC, aC, bC[1], gC[1], false)
    SCAN_STEP(12, kA[2], kA[3], qA[0], qA[1], vA, aA, bA[0], gA[0], false)
    SCAN_STEP(13, kB[0], kB[1], qA[2], qA[3], vA, aA, bA[1], gA[1], false)
    SCAN_STEP(14, kB[2], kB[3], qB[0], qB[1], vB, aB, bB[0], gB[0], false)
    SCAN_STEP(15, kB[2], kB[3], qB[2], qB[3], vB, aB, bB[1], gB[1], true)

    {
      int st = lane >> 2, rr = lane & 3;
      float4 A0 = *(const float4*)&so[st][rr * 16];
      float4 A1 = *(const float4*)&so[st][rr * 16 + 4];
      float4 A2 = *(const float4*)&so[st][rr * 16 + 8];
      float4 A3 = *(const float4*)&so[st][rr * 16 + 12];
      float s = (((A0.x + A0.y) + (A0.z + A0.w)) + ((A1.x + A1.y) + (A1.z + A1.w)))
              + (((A2.x + A2.y) + (A2.z + A2.w)) + ((A3.x + A3.y) + (A3.z + A3.w)));
      so2[st][rr] = cvt_bf16(s);
    }
    if (lane < 16)
      *(bf16x4v*)((__bf16*)o + bva + (size_t)(c * 16 + lane) * 1024) =
          *(const bf16x4v*)&so2[lane][0];

    if (hasNext) commit(buf ^ 1);
  }
}

// LayerNorm over DV=64 per (b,t,h) row, *ln_w+ln_b, *gate -> bf16 (fallback)
__global__ __launch_bounds__(256) void ln_gate_kernel(
    const bf16* __restrict__ o, const bf16* __restrict__ g,
    const float* __restrict__ lnw, const float* __restrict__ lnb,
    bf16* __restrict__ out)
{
  int row = blockIdx.x * 4 + (threadIdx.x >> 6);
  int lane = threadIdx.x & 63;
  size_t idx = (size_t)row * 64 + lane;
  float xv = (float)o[idx];
  float mu = xv;
#pragma unroll
  for (int s = 1; s < 64; s <<= 1) mu += __shfl_xor(mu, s);
  mu *= (1.f / 64.f);
  float d = xv - mu;
  float vv = d * d;
#pragma unroll
  for (int s = 1; s < 64; s <<= 1) vv += __shfl_xor(vv, s);
  vv *= (1.f / 64.f);
  float y = d * rsqrtf(vv + 1e-5f) * lnw[lane] + lnb[lane];
  y *= (float)g[idx];
  out[idx] = (bf16)y;
}

extern "C" void kernel_launch(void* const* d_in, const int* in_sizes, int n_in,
                              void* d_out, int out_size, void* d_ws, size_t ws_size,
                              hipStream_t stream)
{
  const float* x   = (const float*)d_in[0];
  const float* Wq  = (const float*)d_in[1];
  const float* Wk  = (const float*)d_in[2];
  const float* Wv  = (const float*)d_in[3];
  const float* Wa  = (const float*)d_in[4];
  const float* ba  = (const float*)d_in[5];
  const float* Wb  = (const float*)d_in[6];
  const float* bb  = (const float*)d_in[7];
  const float* Wg  = (const float*)d_in[8];
  const float* Wo  = (const float*)d_in[9];
  const float* qcw = (const float*)d_in[10];
  const float* qcb = (const float*)d_in[11];
  const float* kcw = (const float*)d_in[12];
  const float* kcb = (const float*)d_in[13];
  const float* vcw = (const float*)d_in[14];
  const float* vcb = (const float*)d_in[15];
  const float* lnw = (const float*)d_in[16];
  const float* lnb = (const float*)d_in[17];

  const int M = 4096, HID = 1024;
  const size_t PLANE = (size_t)M * HID;
  const size_t PB = PLANE * sizeof(bf16);          // 8 MB bf16 plane

  char* ws = (char*)d_ws;
  float* outf = (float*)d_out;
  const bool rich = (ws_size >= 5 * PB + 1024);

  dim3 blk(256);
  dim3 g8(8, 32);
  int nconv = (int)((size_t)M * 128 / 256);

  if (rich) {
    bf16* P0 = (bf16*)(ws);
    bf16* P1 = (bf16*)(ws + PB);
    bf16* P2 = (bf16*)(ws + 2 * PB);
    bf16* P3 = (bf16*)(ws + 3 * PB);
    bf16* P4 = (bf16*)(ws + 4 * PB);
    bf16*  xb    = (bf16*)d_out;                            // [0,8M)
    bf16*  W4b   = (bf16*)((char*)d_out + 8 * 1024 * 1024); // [8M,16M)
    bf16*  Kb    = xb;                                      // k-plane
    bf16*  Qb    = W4b;                                     // q-plane
    float* betab = (float*)P4;
    float* gkk   = (float*)((char*)P4 + 256 * 1024);
    bf16*  Wgb   = (bf16*)((char*)P4 + 1024 * 1024);
    bf16*  Wob   = (bf16*)((char*)P4 + 3 * 1024 * 1024);

    // 1. convert x + 6 weight matrices to bf16
    cvtw_kernel<<<10240, blk, 0, stream>>>(x, Wq, Wk, Wv, Wa, Wg, Wo,
                                           xb, W4b, Wgb, Wob);
    // 2. fused 4-projection + beta GEMM
    mega_gemm2<<<dim3(33, 32), blk, 0, stream>>>(xb, W4b, Wb, bb, ba, P0, betab);
    // 3. conv q (P0->Qb) + conv k (P1->Kb) -- disjoint planes
    conv2_kernel<<<4096, blk, 0, stream>>>(P0, P1, qcw, qcb, kcw, kcb, Qb, Kb);
    // 4. conv v (P2->P1) + kk (reads Kb from launch 3)
    convv_kk_kernel<<<3072, blk, 0, stream>>>(P2, vcw, vcb, P1, Kb, betab, gkk);
    // 5. FUSED scan (o->P0) + g-GEMM (sigmoid(x@Wgb^T)->P2)
    scan_gemm_kernel<<<768, blk, 0, stream>>>(Qb, Kb, P1, P3, betab, gkk, P0,
                                              x, Wgb, P2);
    // 6. final GEMM with fused LN+gate: out = LNgate(P0,P2) @ Wob^T
    gemm_bb_ln<<<g8, blk, 0, stream>>>(P0, P2, lnw, lnb, Wob, outf);
  } else {
    bf16* P  = (bf16*)(ws);
    bf16* qb = (bf16*)(ws + PB);
    bf16* kb = (bf16*)(ws + 2 * PB);
    bf16* vb = (bf16*)(ws + 3 * PB);
    float* betab = (float*)d_out;
    float* gkk   = (float*)((char*)d_out + 256 * 1024);
    bf16*  ob    = (bf16*)((char*)d_out + 8 * 1024 * 1024);

    gemm_bt<2, true><<<g8, blk, 0, stream>>>(x, Wq, nullptr, nullptr, P, M, HID, HID);
    conv_silu_kernel<<<nconv, blk, 0, stream>>>(P, qcw, qcb, qb, 1.f);
    gemm_bt<2, true><<<g8, blk, 0, stream>>>(x, Wk, nullptr, nullptr, P, M, HID, HID);
    conv_silu_kernel<<<nconv, blk, 0, stream>>>(P, kcw, kcb, kb, 0.125f);
    gemm_bt<2, true><<<g8, blk, 0, stream>>>(x, Wv, nullptr, nullptr, P, M, HID, HID);
    conv_silu_kernel<<<nconv, blk, 0, stream>>>(P, vcw, vcb, vb, 1.f);
    gemm_bt<3, true><<<g8, blk, 0, stream>>>(x, Wa, ba, nullptr, P, M, HID, HID);
    gemm_bt<5, true><<<dim3(1, 32), blk, 0, stream>>>(x, Wb, bb, betab, nullptr, M, 16, HID);
    kk_kernel<<<1024, blk, 0, stream>>>(kb, betab, gkk);
    scan_gemm_kernel<<<512, blk, 0, stream>>>(qb, kb, vb, P, betab, gkk, ob,
                                              x, nullptr, nullptr);
    gemm_bt<3, true><<<g8, blk, 0, stream>>>(x, Wg, nullptr, nullptr, qb, M, HID, HID);
    ln_gate_kernel<<<M * 16 / 4, blk, 0, stream>>>(ob, qb, lnw, lnb, kb);
    gemm_bt<4, false><<<g8, blk, 0, stream>>>(kb, Wo, nullptr, outf, nullptr, M, HID, HID);
  }
}

// Round 13
// 438.990 us; speedup vs baseline: 1.5910x; 1.0419x over previous
//
#include <hip/hip_runtime.h>
#include <hip/hip_bf16.h>
#include <cstdint>

// B=2, T=2048, HID=1024, H=16, DK=DV=64, K(conv)=4. fp32 in/out.
// RICH memory plan (ws >= 40MB): ws = P0..P4 (8MB bf16 planes).
//  d_out[0,8M): xb -> Kb (k-plane);  d_out[8M,16M): W4b -> Qb (q-plane)
//  P4: [0,256K) betab fp32; [256K,512K) gkk; [1M,3M) Wgb; [3M,5M) Wob
//  P0: zq -> scan o;  P1: zk -> v-plane;  P2: zv -> g-plane;  P3: a plane
// Launches (6): cvtw -> mega_gemm2(+beta) -> conv2(q,k) -> convv_kk
//   -> FUSED scan+g-GEMM -> gemm_bb_ln (final GEMM with LN+gate fused).
//
// R13: (1) XCD-bijective block swizzle on mega_gemm2 / gemm_bb_ln (each
// XCD's blocks share A/o/g M-panels -> L2-local panel reuse, T1);
// (2) s_setprio(1) on scan waves (role-diverse co-residency with g-GEMM,
// T5 / m191 regime); (3) gemm_bb_ln head-loop software pipeline (next
// head's o/g loads in flight across current head's MFMA, T14) + float4
// beta/G preload in scan. Scan core: R9-proven form, untouched.

using bf16 = __hip_bfloat16;
typedef __bf16 bf16x8 __attribute__((ext_vector_type(8)));
typedef __bf16 bf16x4v __attribute__((ext_vector_type(4)));
typedef float f32x4 __attribute__((ext_vector_type(4)));
typedef float f32x2 __attribute__((ext_vector_type(2)));
typedef unsigned int u32x4 __attribute__((ext_vector_type(4)));
typedef unsigned int u32x2 __attribute__((ext_vector_type(2)));

__device__ __forceinline__ __bf16 cvt_bf16(float f) {
  __hip_bfloat16 h = (__hip_bfloat16)f;
  return *reinterpret_cast<__bf16*>(&h);
}
__device__ __forceinline__ void async_copy16(const void* g, void* l) {
  __builtin_amdgcn_global_load_lds((const __attribute__((address_space(1))) void*)g,
                                   (__attribute__((address_space(3))) void*)l,
                                   16, 0, 0);
}
__device__ __forceinline__ float bcf(unsigned int u) { return __builtin_bit_cast(float, u); }
template <int CTRL>
__device__ __forceinline__ float dpp_f(float x) {
  int y = __builtin_amdgcn_update_dpp(0, __builtin_bit_cast(int, x), CTRL, 0xF, 0xF, true);
  return __builtin_bit_cast(float, y);
}

// fp32 -> bf16: x (blocks 0..4095), W4 (4096..8191), Wg (8192..9215),
// Wo (9216..10239).
__global__ __launch_bounds__(256) void cvtw_kernel(
    const float* __restrict__ x, const float* __restrict__ Wq,
    const float* __restrict__ Wk, const float* __restrict__ Wv,
    const float* __restrict__ Wa, const float* __restrict__ Wg,
    const float* __restrict__ Wo, bf16* __restrict__ xb,
    bf16* __restrict__ w4b, bf16* __restrict__ wgb, bf16* __restrict__ wob)
{
  int blk = blockIdx.x;
  const float* src;
  __bf16* dst;
  size_t off;
  if (blk < 4096) {
    src = x; dst = (__bf16*)xb;
    off = (size_t)blk * 1024 + threadIdx.x * 4;
  } else if (blk < 8192) {
    int wb = blk - 4096;
    int wi = wb >> 10;
    src = (wi == 0) ? Wq : (wi == 1) ? Wk : (wi == 2) ? Wv : Wa;
    dst = (__bf16*)w4b + (size_t)wi * 1024 * 1024;
    off = (size_t)(wb & 1023) * 1024 + threadIdx.x * 4;
  } else if (blk < 9216) {
    src = Wg; dst = (__bf16*)wgb;
    off = (size_t)(blk - 8192) * 1024 + threadIdx.x * 4;
  } else {
    src = Wo; dst = (__bf16*)wob;
    off = (size_t)(blk - 9216) * 1024 + threadIdx.x * 4;
  }
  float4 f = *(const float4*)(src + off);
  bf16x4v t;
  t[0] = cvt_bf16(f.x); t[1] = cvt_bf16(f.y); t[2] = cvt_bf16(f.z); t[3] = cvt_bf16(f.w);
  *(bf16x4v*)(dst + off) = t;
}

// C = A * Bt^T. A: MxK (bf16 async-staged unless A_FP32); Bt: NxK fp32.
// MODE 2: raw->bf16; 3: sigmoid(acc+bias)->bf16; 4: raw->fp32; 5: sigmoid(acc+bias)->fp32 TRANSPOSED
template <int MODE, bool A_FP32>
__global__ __launch_bounds__(256) void gemm_bt(
    const void* __restrict__ Av, const float* __restrict__ Bt,
    const float* __restrict__ bias, float* __restrict__ Cf, bf16* __restrict__ Cb,
    int M, int N, int K)
{
  __shared__ __align__(16) __bf16 As[128 * 32];
  __shared__ __align__(16) __bf16 Bs[128 * 32];

  const int tid  = threadIdx.x;
  const int lane = tid & 63;
  const int wave = tid >> 6;
  const int tile_m = blockIdx.y * 128;
  const int tile_n = blockIdx.x * 128;
  const int wm = (wave >> 1) * 64;
  const int wn = (wave & 1) * 64;

  const int srow = lane >> 2;
  const int scol = (lane & 3) * 8;

  f32x4 acc[4][4];
#pragma unroll
  for (int i = 0; i < 4; ++i)
#pragma unroll
    for (int j = 0; j < 4; ++j) acc[i][j] = {0.f, 0.f, 0.f, 0.f};

  for (int k0 = 0; k0 < K; k0 += 32) {
    float4 b0[2], b1[2], a0[2], a1[2];
#pragma unroll
    for (int s = 0; s < 2; ++s) {
      int brow = tile_n + s * 64 + wave * 16 + srow;
      if (brow > N - 1) brow = N - 1;
      const float* bp = Bt + (size_t)brow * K + k0 + scol;
      b0[s] = *(const float4*)bp;
      b1[s] = *(const float4*)(bp + 4);
      if (A_FP32) {
        int arow = tile_m + s * 64 + wave * 16 + srow;
        const float* ap = (const float*)Av + (size_t)arow * K + k0 + scol;
        a0[s] = *(const float4*)ap;
        a1[s] = *(const float4*)(ap + 4);
      }
    }
    __syncthreads();
#pragma unroll
    for (int s = 0; s < 2; ++s) {
      if (!A_FP32) {
        int arow = tile_m + s * 64 + wave * 16 + srow;
        async_copy16((const __bf16*)Av + (size_t)arow * K + k0 + scol,
                     &As[(s * 64 + wave * 16 + srow) * 32 + scol]);
      } else {
        bf16x8 ua;
        ua[0] = cvt_bf16(a0[s].x); ua[1] = cvt_bf16(a0[s].y);
        ua[2] = cvt_bf16(a0[s].z); ua[3] = cvt_bf16(a0[s].w);
        ua[4] = cvt_bf16(a1[s].x); ua[5] = cvt_bf16(a1[s].y);
        ua[6] = cvt_bf16(a1[s].z); ua[7] = cvt_bf16(a1[s].w);
        *(bf16x8*)&As[(s * 64 + wave * 16 + srow) * 32 + scol] = ua;
      }
      bf16x8 u;
      u[0] = cvt_bf16(b0[s].x); u[1] = cvt_bf16(b0[s].y);
      u[2] = cvt_bf16(b0[s].z); u[3] = cvt_bf16(b0[s].w);
      u[4] = cvt_bf16(b1[s].x); u[5] = cvt_bf16(b1[s].y);
      u[6] = cvt_bf16(b1[s].z); u[7] = cvt_bf16(b1[s].w);
      *(bf16x8*)&Bs[(s * 64 + wave * 16 + srow) * 32 + scol] = u;
    }
    __syncthreads();

    bf16x8 af[4], bfr[4];
#pragma unroll
    for (int i = 0; i < 4; ++i)
      af[i] = *(const bf16x8*)&As[(wm + i * 16 + (lane & 15)) * 32 + (lane >> 4) * 8];
#pragma unroll
    for (int j = 0; j < 4; ++j)
      bfr[j] = *(const bf16x8*)&Bs[(wn + j * 16 + (lane & 15)) * 32 + (lane >> 4) * 8];

#pragma unroll
    for (int i = 0; i < 4; ++i)
#pragma unroll
      for (int j = 0; j < 4; ++j)
        acc[i][j] = __builtin_amdgcn_mfma_f32_16x16x32_bf16(af[i], bfr[j], acc[i][j], 0, 0, 0);
  }

#pragma unroll
  for (int i = 0; i < 4; ++i) {
#pragma unroll
    for (int j = 0; j < 4; ++j) {
#pragma unroll
      for (int r = 0; r < 4; ++r) {
        int gm = tile_m + wm + i * 16 + (lane >> 4) * 4 + r;
        int gn = tile_n + wn + j * 16 + (lane & 15);
        if (gn < N) {
          float val = acc[i][j][r];
          if (MODE == 3 || MODE == 5) {
            float bv = bias ? bias[gn] : 0.f;
            val = 1.f / (1.f + __expf(-(val + bv)));
          }
          if (MODE == 4)      Cf[(size_t)gm * N + gn] = val;
          else if (MODE == 5) Cf[(size_t)gn * M + gm] = val;
          else                Cb[(size_t)gm * N + gn] = (bf16)val;
        }
      }
    }
  }
}

// Final GEMM with fused LN+gate on the A operand. 1-D grid 256 blocks,
// XCD-bijective swizzle: xcd = bx&7 owns 4 contiguous M-panels (o/g reads
// L2-local). Head loop software-pipelined: head h+1's o/g global loads are
// issued before head h's barriers/MFMA (latency hidden under compute).
__global__ __launch_bounds__(256) void gemm_bb_ln(
    const bf16* __restrict__ o, const bf16* __restrict__ g,
    const float* __restrict__ lnw, const float* __restrict__ lnb,
    const bf16* __restrict__ Bw, float* __restrict__ C)
{
  __shared__ __align__(16) __bf16 As2[128][72];   // 18 KB (72-pad)
  __shared__ __align__(16) __bf16 Bs[128 * 32];   // 8 KB
  __shared__ float sW[64], sB[64];

  const int bx = blockIdx.x;                 // 256 blocks
  const int logical = (bx & 7) * 32 + (bx >> 3);   // bijective XCD swizzle
  const int tile_m = (logical >> 3) * 128;
  const int tile_n = (logical & 7) * 128;

  const int tid  = threadIdx.x;
  const int lane = tid & 63;
  const int wave = tid >> 6;
  const int wm = (wave >> 1) * 64;
  const int wn = (wave & 1) * 64;
  const int srow = lane >> 2;
  const int scol = (lane & 3) * 8;
  const int rl = tid >> 1;            // local A row 0..127
  const int half = tid & 1;           // column half (0..31 / 32..63)

  if (tid < 64) { sW[tid] = lnw[tid]; sB[tid] = lnb[tid]; }

  const __bf16* obase = (const __bf16*)o + (size_t)(tile_m + rl) * 1024 + half * 32;
  const __bf16* gbase = (const __bf16*)g + (size_t)(tile_m + rl) * 1024 + half * 32;

  f32x4 acc[4][4];
#pragma unroll
  for (int i = 0; i < 4; ++i)
#pragma unroll
    for (int j = 0; j < 4; ++j) acc[i][j] = {0.f, 0.f, 0.f, 0.f};

  // preload head 0
  bf16x8 ov0, ov1, ov2, ov3, gv0, gv1, gv2, gv3;
  {
    const __bf16* op = obase;
    const __bf16* gp = gbase;
    ov0 = *(const bf16x8*)(op);      ov1 = *(const bf16x8*)(op + 8);
    ov2 = *(const bf16x8*)(op + 16); ov3 = *(const bf16x8*)(op + 24);
    gv0 = *(const bf16x8*)(gp);      gv1 = *(const bf16x8*)(gp + 8);
    gv2 = *(const bf16x8*)(gp + 16); gv3 = *(const bf16x8*)(gp + 24);
  }

  for (int h = 0; h < 16; ++h) {
    // issue NEXT head's o/g loads first (in flight across barriers + MFMA)
    bf16x8 nо0, nо1, nо2, nо3, ng0, ng1, ng2, ng3;
    if (h + 1 < 16) {
      const __bf16* op = obase + (h + 1) * 64;
      const __bf16* gp = gbase + (h + 1) * 64;
      nо0 = *(const bf16x8*)(op);      nо1 = *(const bf16x8*)(op + 8);
      nо2 = *(const bf16x8*)(op + 16); nо3 = *(const bf16x8*)(op + 24);
      ng0 = *(const bf16x8*)(gp);      ng1 = *(const bf16x8*)(gp + 8);
      ng2 = *(const bf16x8*)(gp + 16); ng3 = *(const bf16x8*)(gp + 24);
    }

    __syncthreads();   // prior head's MFMA reads of As2 complete (+ sW visible)

    // ---- LN + gate for head h -> As2 ----
    float sum = 0.f;
#pragma unroll
    for (int e = 0; e < 8; ++e)
      sum += (float)ov0[e] + (float)ov1[e] + (float)ov2[e] + (float)ov3[e];
    sum += __shfl_xor(sum, 1);
    float mu = sum * (1.f / 64.f);
    float vv = 0.f;
#pragma unroll
    for (int e = 0; e < 8; ++e) {
      float d0 = (float)ov0[e] - mu, d1 = (float)ov1[e] - mu;
      float d2 = (float)ov2[e] - mu, d3 = (float)ov3[e] - mu;
      vv += d0 * d0 + d1 * d1 + d2 * d2 + d3 * d3;
    }
    vv += __shfl_xor(vv, 1);
    float rstd = rsqrtf(vv * (1.f / 64.f) + 1e-5f);

    bf16x8 res0, res1, res2, res3;
#pragma unroll
    for (int e = 0; e < 8; ++e) {
      int c0 = half * 32 + e;
      res0[e] = cvt_bf16((((float)ov0[e] - mu) * rstd * sW[c0] + sB[c0]) * (float)gv0[e]);
      res1[e] = cvt_bf16((((float)ov1[e] - mu) * rstd * sW[c0 + 8] + sB[c0 + 8]) * (float)gv1[e]);
      res2[e] = cvt_bf16((((float)ov2[e] - mu) * rstd * sW[c0 + 16] + sB[c0 + 16]) * (float)gv2[e]);
      res3[e] = cvt_bf16((((float)ov3[e] - mu) * rstd * sW[c0 + 24] + sB[c0 + 24]) * (float)gv3[e]);
    }
    *(bf16x8*)&As2[rl][half * 32 + 0]  = res0;
    *(bf16x8*)&As2[rl][half * 32 + 8]  = res1;
    *(bf16x8*)&As2[rl][half * 32 + 16] = res2;
    *(bf16x8*)&As2[rl][half * 32 + 24] = res3;

#pragma unroll
    for (int sub = 0; sub < 2; ++sub) {
      if (sub) __syncthreads();      // protect Bs restage from sub0 reads
      int k0 = h * 64 + sub * 32;
#pragma unroll
      for (int s = 0; s < 2; ++s) {
        int brow = tile_n + s * 64 + wave * 16 + srow;
        async_copy16((const __bf16*)Bw + (size_t)brow * 1024 + k0 + scol,
                     &Bs[(s * 64 + wave * 16 + srow) * 32 + scol]);
      }
      __syncthreads();               // Bs landed + As2 visible

      bf16x8 af[4], bfr[4];
#pragma unroll
      for (int i = 0; i < 4; ++i)
        af[i] = *(const bf16x8*)&As2[wm + i * 16 + (lane & 15)][(lane >> 4) * 8 + sub * 32];
#pragma unroll
      for (int j = 0; j < 4; ++j)
        bfr[j] = *(const bf16x8*)&Bs[(wn + j * 16 + (lane & 15)) * 32 + (lane >> 4) * 8];

#pragma unroll
      for (int i = 0; i < 4; ++i)
#pragma unroll
        for (int j = 0; j < 4; ++j)
          acc[i][j] = __builtin_amdgcn_mfma_f32_16x16x32_bf16(af[i], bfr[j], acc[i][j], 0, 0, 0);
    }

    if (h + 1 < 16) {
      ov0 = nо0; ov1 = nо1; ov2 = nо2; ov3 = nо3;
      gv0 = ng0; gv1 = ng1; gv2 = ng2; gv3 = ng3;
    }
  }

#pragma unroll
  for (int i = 0; i < 4; ++i)
#pragma unroll
    for (int j = 0; j < 4; ++j)
#pragma unroll
      for (int r = 0; r < 4; ++r) {
        int gm = tile_m + wm + i * 16 + (lane >> 4) * 4 + r;
        int gn = tile_n + wn + j * 16 + (lane & 15);
        C[(size_t)gm * 1024 + gn] = acc[i][j][r];
      }
}

// Fused 4-projection + beta GEMM. 1-D grid 1056 blocks:
//  bx < 1024: GEMM tiles, XCD-bijective swizzle (each XCD owns contiguous
//  M-panels -> A reads L2-local); bx >= 1024: beta tiles (32 M-panels).
__global__ __launch_bounds__(256) void mega_gemm2(
    const bf16* __restrict__ Av, const bf16* __restrict__ W4b,
    const float* __restrict__ Wb, const float* __restrict__ bb,
    const float* __restrict__ ba, bf16* __restrict__ C4,
    float* __restrict__ betab)
{
  __shared__ __align__(16) __bf16 As[128 * 32];
  __shared__ __align__(16) __bf16 Bs[128 * 32];

  const int bx = blockIdx.x;
  const bool isbeta = (bx >= 1024);
  int tile_m, tile_n;
  if (!isbeta) {
    const int logical = (bx & 7) * 128 + (bx >> 3);  // bijective XCD swizzle
    tile_m = (logical >> 5) * 128;
    tile_n = (logical & 31) * 128;
  } else {
    tile_m = (bx - 1024) * 128;
    tile_n = 0;
  }
  const int grp = tile_n >> 10;
  const int tnl = tile_n & 1023;

  const int tid  = threadIdx.x;
  const int lane = tid & 63;
  const int wave = tid >> 6;
  const int wm = (wave >> 1) * 64;
  const int wn = (wave & 1) * 64;

  const int srow = lane >> 2;
  const int scol = (lane & 3) * 8;

  f32x4 acc[4][4];
#pragma unroll
  for (int i = 0; i < 4; ++i)
#pragma unroll
    for (int j = 0; j < 4; ++j) acc[i][j] = {0.f, 0.f, 0.f, 0.f};

  const __bf16* Wp = (const __bf16*)W4b + (size_t)grp * 1024 * 1024;

  for (int k0 = 0; k0 < 1024; k0 += 32) {
    float4 b0[2], b1[2];
    if (isbeta) {
#pragma unroll
      for (int s = 0; s < 2; ++s) {
        int brow = s * 64 + wave * 16 + srow;
        if (brow > 15) brow = 15;
        const float* bp = Wb + (size_t)brow * 1024 + k0 + scol;
        b0[s] = *(const float4*)bp;
        b1[s] = *(const float4*)(bp + 4);
      }
    }
    __syncthreads();
#pragma unroll
    for (int s = 0; s < 2; ++s) {
      int arow = tile_m + s * 64 + wave * 16 + srow;
      async_copy16((const __bf16*)Av + (size_t)arow * 1024 + k0 + scol,
                   &As[(s * 64 + wave * 16 + srow) * 32 + scol]);
      if (!isbeta) {
        int brow = tnl + s * 64 + wave * 16 + srow;
        async_copy16(Wp + (size_t)brow * 1024 + k0 + scol,
                     &Bs[(s * 64 + wave * 16 + srow) * 32 + scol]);
      } else {
        bf16x8 u;
        u[0] = cvt_bf16(b0[s].x); u[1] = cvt_bf16(b0[s].y);
        u[2] = cvt_bf16(b0[s].z); u[3] = cvt_bf16(b0[s].w);
        u[4] = cvt_bf16(b1[s].x); u[5] = cvt_bf16(b1[s].y);
        u[6] = cvt_bf16(b1[s].z); u[7] = cvt_bf16(b1[s].w);
        *(bf16x8*)&Bs[(s * 64 + wave * 16 + srow) * 32 + scol] = u;
      }
    }
    __syncthreads();

    bf16x8 af[4], bfr[4];
#pragma unroll
    for (int i = 0; i < 4; ++i)
      af[i] = *(const bf16x8*)&As[(wm + i * 16 + (lane & 15)) * 32 + (lane >> 4) * 8];
#pragma unroll
    for (int j = 0; j < 4; ++j)
      bfr[j] = *(const bf16x8*)&Bs[(wn + j * 16 + (lane & 15)) * 32 + (lane >> 4) * 8];

#pragma unroll
    for (int i = 0; i < 4; ++i)
#pragma unroll
      for (int j = 0; j < 4; ++j)
        acc[i][j] = __builtin_amdgcn_mfma_f32_16x16x32_bf16(af[i], bfr[j], acc[i][j], 0, 0, 0);
  }

  if (!isbeta) {
    bf16* Cp = (bf16*)((__bf16*)C4 + (size_t)grp * 4096 * 1024);
#pragma unroll
    for (int i = 0; i < 4; ++i)
#pragma unroll
      for (int j = 0; j < 4; ++j)
#pragma unroll
        for (int r = 0; r < 4; ++r) {
          int gm = tile_m + wm + i * 16 + (lane >> 4) * 4 + r;
          int col = tnl + wn + j * 16 + (lane & 15);
          float val = acc[i][j][r];
          if (grp == 3) val = 1.f / (1.f + __expf(-(val + ba[col])));
          ((__bf16*)Cp)[(size_t)gm * 1024 + col] = cvt_bf16(val);
        }
  } else {
#pragma unroll
    for (int i = 0; i < 4; ++i)
#pragma unroll
      for (int j = 0; j < 4; ++j)
#pragma unroll
        for (int r = 0; r < 4; ++r) {
          int gm = tile_m + wm + i * 16 + (lane >> 4) * 4 + r;
          int gn = wn + j * 16 + (lane & 15);
          if (gn < 16) {
            float val = 1.f / (1.f + __expf(-(acc[i][j][r] + bb[gn])));
            betab[(size_t)gn * 4096 + gm] = val;
          }
        }
  }
}

// shared conv body: causal depthwise K=4 + bias + SiLU (+scale), x8 vec.
__device__ __forceinline__ void conv_body(
    int idx, const bf16* __restrict__ z, const float* __restrict__ w,
    const float* __restrict__ bias, bf16* __restrict__ out, float scale)
{
  int c8 = idx & 127;
  int m  = idx >> 7;
  int t  = m & 2047;
  int c0 = c8 * 8;

  const __bf16* base = (const __bf16*)z + (size_t)m * 1024 + c0;
  const bf16x8 zzero = __builtin_bit_cast(bf16x8, (u32x4){0u, 0u, 0u, 0u});
  bf16x8 z3 = *(const bf16x8*)base;
  bf16x8 z2 = (t >= 1) ? *(const bf16x8*)(base - 1024) : zzero;
  bf16x8 z1 = (t >= 2) ? *(const bf16x8*)(base - 2048) : zzero;
  bf16x8 z0 = (t >= 3) ? *(const bf16x8*)(base - 3072) : zzero;

  const float* wp = w + c0 * 4;
  bf16x8 res;
#pragma unroll
  for (int e = 0; e < 8; ++e) {
    float4 we = *(const float4*)(wp + e * 4);
    float acc = bias[c0 + e] + (float)z3[e] * we.w;
    acc += (float)z2[e] * we.z;
    acc += (float)z1[e] * we.y;
    acc += (float)z0[e] * we.x;
    float s = acc / (1.f + __expf(-acc));
    res[e] = cvt_bf16(s * scale);
  }
  *(bf16x8*)((__bf16*)out + (size_t)m * 1024 + c0) = res;
}

// standalone conv (fallback path)
__global__ __launch_bounds__(256) void conv_silu_kernel(
    const bf16* __restrict__ z, const float* __restrict__ w,
    const float* __restrict__ bias, bf16* __restrict__ out, float scale)
{
  conv_body(blockIdx.x * 256 + threadIdx.x, z, w, bias, out, scale);
}

// conv_q + conv_k in one launch (disjoint planes). Grid 4096.
__global__ __launch_bounds__(256) void conv2_kernel(
    const bf16* __restrict__ zq, const bf16* __restrict__ zk,
    const float* __restrict__ qcw, const float* __restrict__ qcb,
    const float* __restrict__ kcw, const float* __restrict__ kcb,
    bf16* __restrict__ oq, bf16* __restrict__ ok)
{
  int sec = blockIdx.x >> 11;
  int bx  = blockIdx.x & 2047;
  int idx = bx * 256 + threadIdx.x;
  if (sec == 0) conv_body(idx, zq, qcw, qcb, oq, 1.f);
  else          conv_body(idx, zk, kcw, kcb, ok, 0.125f);
}

// conv_v + kk in one launch (kk reads k from PREVIOUS launch). Grid 3072.
__global__ __launch_bounds__(256) void convv_kk_kernel(
    const bf16* __restrict__ zv, const float* __restrict__ vcw,
    const float* __restrict__ vcb, bf16* __restrict__ ov,
    const bf16* __restrict__ k, const float* __restrict__ betab,
    float* __restrict__ G)
{
  if (blockIdx.x < 2048) {
    conv_body(blockIdx.x * 256 + threadIdx.x, zv, vcw, vcb, ov, 1.f);
    return;
  }
  int gtid = (blockIdx.x - 2048) * 256 + threadIdx.x;
  int out = gtid >> 2;           // h*4096 + m
  int j   = gtid & 3;
  int h = out >> 12;
  int m = out & 4095;
  int t = m & 2047;
  float s = 0.f;
  if (t > 0) {
    const __bf16* r1 = (const __bf16*)k + (size_t)m * 1024 + h * 64 + j * 16;
    const __bf16* r0 = r1 - 1024;
    bf16x8 a0 = *(const bf16x8*)r0;
    bf16x8 a1 = *(const bf16x8*)(r0 + 8);
    bf16x8 b0 = *(const bf16x8*)r1;
    bf16x8 b1 = *(const bf16x8*)(r1 + 8);
#pragma unroll
    for (int e = 0; e < 8; ++e)
      s += (float)a0[e] * (float)b0[e] + (float)a1[e] * (float)b1[e];
  }
  s += __shfl_xor(s, 1);
  s += __shfl_xor(s, 2);
  if (j == 0) G[out] = betab[out] * s;
}

// kk standalone (fallback)
__global__ __launch_bounds__(256) void kk_kernel(
    const bf16* __restrict__ k, const float* __restrict__ betab,
    float* __restrict__ G)
{
  int tid = blockIdx.x * 256 + threadIdx.x;
  int out = tid >> 2;
  int j   = tid & 3;
  int h = out >> 12;
  int m = out & 4095;
  int t = m & 2047;
  float s = 0.f;
  if (t > 0) {
    const __bf16* r1 = (const __bf16*)k + (size_t)m * 1024 + h * 64 + j * 16;
    const __bf16* r0 = r1 - 1024;
    bf16x8 a0 = *(const bf16x8*)r0;
    bf16x8 a1 = *(const bf16x8*)(r0 + 8);
    bf16x8 b0 = *(const bf16x8*)r1;
    bf16x8 b1 = *(const bf16x8*)(r1 + 8);
#pragma unroll
    for (int e = 0; e < 8; ++e)
      s += (float)a0[e] * (float)b0[e] + (float)a1[e] * (float)b1[e];
  }
  s += __shfl_xor(s, 1);
  s += __shfl_xor(s, 2);
  if (j == 0) G[out] = betab[out] * s;
}

// One scan step (constant word indices only).
#define SCAN_STEP(i, KN0, KN1, Q0, Q1, WV, WA, BT, GT, LAST)                  \
  {                                                                           \
    const float vr = ((i) & 1) ? bcf((WV) & 0xffff0000u) : bcf((WV) << 16);   \
    const float ar = ((i) & 1) ? bcf((WA) & 0xffff0000u) : bcf((WA) << 16);   \
    float unxt = 0.f;                                                         \
    f32x2 k2n0 = {0.f, 0.f}, k2n1 = {0.f, 0.f};                               \
    if (!(LAST)) {                                                            \
      k2n0 = unpk(KN0); k2n1 = unpk(KN1);                                     \
      f32x2 dd = S20 * k2n0; dd += S21 * k2n1;                                \
      unxt = dd[0] + dd[1];                                                   \
      unxt += dpp_f<0xB1>(unxt);  unxt += dpp_f<0x4E>(unxt);                  \
      unxt += dpp_f<0x141>(unxt); unxt += dpp_f<0x140>(unxt);                 \
    } else { Sold0 = S20; Sold1 = S21; }                                      \
    float A_ = (BT) * __builtin_fmaf(aprev, u, -vr);                          \
    cc = __builtin_fmaf(-cc, (GT), A_);                                       \
    f32x2 q20 = unpk(Q0), q21 = unpk(Q1);                                     \
    const f32x2 cc2 = {cc, cc}, arv = {ar, ar};                               \
    f32x2 oo;                                                                 \
    { f32x2 t0 = cc2 * k2c0; S20 = arv * S20 - t0; oo = S20 * q20;            \
      f32x2 t1 = cc2 * k2c1; S21 = arv * S21 - t1; oo += S21 * q21; }         \
    so[(i)][lane] = oo[0] + oo[1];                                            \
    aprev = ar;                                                               \
    if (!(LAST)) { k2c0 = k2n0; k2c1 = k2n1; u = unxt; }                      \
  }

// Load one 2-step group (g = 0..7) into a named set (14 regs).
#define LOADG(KS, QS, VS, AS, BS, GS, g)                                      \
  KS = *(const u32x4*)&skT[buf][sg][(g) * 8];                                 \
  QS = *(const u32x4*)&sqT[buf][sg][(g) * 8];                                 \
  VS = *(const unsigned int*)&svaT[buf][0][r4][(g) * 2];                      \
  AS = *(const unsigned int*)&svaT[buf][1][r4][(g) * 2];                      \
  BS = *(const f32x2*)&sbeta[c * 16 + (g) * 2];                               \
  GS = *(const f32x2*)&sG[c * 16 + (g) * 2];

// FUSED kernel: blocks 0..511 = delta-rule scan (single wave; threads>=64
// exit; NO barriers; s_setprio(1): scan is the critical path vs co-resident
// g-GEMM waves). Blocks 512..767 = g-GEMM: sigmoid(x @ Wgb^T) -> gout.
__global__ __launch_bounds__(256) void scan_gemm_kernel(
    const bf16* __restrict__ q, const bf16* __restrict__ k,
    const bf16* __restrict__ v, const bf16* __restrict__ a,
    const float* __restrict__ betab, const float* __restrict__ gkk,
    bf16* __restrict__ o,
    const float* __restrict__ x, const bf16* __restrict__ Wgb,
    bf16* __restrict__ gout)
{
  __shared__ __align__(16) __bf16 skT[2][16][72];
  __shared__ __align__(16) __bf16 sqT[2][16][72];
  __shared__ __align__(16) __bf16 svaT[2][2][4][16];
  __shared__ __align__(16) float  so[16][68];
  __shared__ __align__(16) __bf16 so2[16][4];
  __shared__ float sbeta[2048];
  __shared__ float sG[2048];
  __shared__ __align__(16) __bf16 As[128 * 32];
  __shared__ __align__(16) __bf16 Bs[128 * 32];

  if (blockIdx.x >= 512) {
    const int gb   = blockIdx.x - 512;
    const int tid  = threadIdx.x;
    const int lane = tid & 63;
    const int wave = tid >> 6;
    const int tile_m = (gb >> 3) * 128;
    const int tile_n = (gb & 7) * 128;
    const int wm = (wave >> 1) * 64;
    const int wn = (wave & 1) * 64;
    const int srow = lane >> 2;
    const int scol = (lane & 3) * 8;

    f32x4 acc[4][4];
#pragma unroll
    for (int i = 0; i < 4; ++i)
#pragma unroll
      for (int j = 0; j < 4; ++j) acc[i][j] = {0.f, 0.f, 0.f, 0.f};

    for (int k0 = 0; k0 < 1024; k0 += 32) {
      float4 a0[2], a1[2];
#pragma unroll
      for (int s = 0; s < 2; ++s) {
        int arow = tile_m + s * 64 + wave * 16 + srow;
        const float* ap = x + (size_t)arow * 1024 + k0 + scol;
        a0[s] = *(const float4*)ap;
        a1[s] = *(const float4*)(ap + 4);
      }
      __syncthreads();
#pragma unroll
      for (int s = 0; s < 2; ++s) {
        bf16x8 ua;
        ua[0] = cvt_bf16(a0[s].x); ua[1] = cvt_bf16(a0[s].y);
        ua[2] = cvt_bf16(a0[s].z); ua[3] = cvt_bf16(a0[s].w);
        ua[4] = cvt_bf16(a1[s].x); ua[5] = cvt_bf16(a1[s].y);
        ua[6] = cvt_bf16(a1[s].z); ua[7] = cvt_bf16(a1[s].w);
        *(bf16x8*)&As[(s * 64 + wave * 16 + srow) * 32 + scol] = ua;
        int brow = tile_n + s * 64 + wave * 16 + srow;
        async_copy16((const __bf16*)Wgb + (size_t)brow * 1024 + k0 + scol,
                     &Bs[(s * 64 + wave * 16 + srow) * 32 + scol]);
      }
      __syncthreads();

      bf16x8 af[4], bfr[4];
#pragma unroll
      for (int i = 0; i < 4; ++i)
        af[i] = *(const bf16x8*)&As[(wm + i * 16 + (lane & 15)) * 32 + (lane >> 4) * 8];
#pragma unroll
      for (int j = 0; j < 4; ++j)
        bfr[j] = *(const bf16x8*)&Bs[(wn + j * 16 + (lane & 15)) * 32 + (lane >> 4) * 8];

#pragma unroll
      for (int i = 0; i < 4; ++i)
#pragma unroll
        for (int j = 0; j < 4; ++j)
          acc[i][j] = __builtin_amdgcn_mfma_f32_16x16x32_bf16(af[i], bfr[j], acc[i][j], 0, 0, 0);
    }

#pragma unroll
    for (int i = 0; i < 4; ++i)
#pragma unroll
      for (int j = 0; j < 4; ++j)
#pragma unroll
        for (int r = 0; r < 4; ++r) {
          int gm = tile_m + wm + i * 16 + (lane >> 4) * 4 + r;
          int gn = tile_n + wn + j * 16 + (lane & 15);
          float val = 1.f / (1.f + __expf(-acc[i][j][r]));
          gout[(size_t)gm * 1024 + gn] = (bf16)val;
        }
    return;
  }

  // ---------------- scan path (single wave; extra waves exit) ----------------
  if (threadIdx.x >= 64) return;
  __builtin_amdgcn_s_setprio(1);   // scan = critical path; g-GEMM waves fill slack

  const int blk = blockIdx.x;
  const int qd = blk >> 5;
  const int bh = blk & 31;
  const int b = bh >> 4, h = bh & 15;
  const int lane = threadIdx.x;
  const int r4 = lane >> 4;
  const int sg = lane & 15;

  {
    const float* bp = betab + (size_t)h * 4096 + b * 2048;
    const float* gp = gkk   + (size_t)h * 4096 + b * 2048;
    for (int t4 = lane * 4; t4 < 2048; t4 += 256) {
      *(float4*)&sbeta[t4] = *(const float4*)(bp + t4);
      *(float4*)&sG[t4]    = *(const float4*)(gp + t4);
    }
  }

  const size_t bkq = (size_t)b * 2048 * 1024 + h * 64;
  const size_t bva = bkq + qd * 4;
  const __bf16* kp = (const __bf16*)k;
  const __bf16* qp = (const __bf16*)q;

  const int g_st = lane >> 3;
  const int g_cg = (lane & 7) * 8;
  const int sgp  = (lane & 7) * 2;
  const int va_vh = (lane >> 4) & 1;
  const int va_st = lane & 15;

  bf16x8 pk0, pk1, pq0, pq1;
  bf16x4v pva;
  auto fetch = [&](int t0) {
    int st0 = t0 + g_st, st1 = t0 + 8 + g_st;
    pk0 = *(const bf16x8*)(kp + bkq + (size_t)st0 * 1024 + g_cg);
    pk1 = *(const bf16x8*)(kp + bkq + (size_t)st1 * 1024 + g_cg);
    pq0 = *(const bf16x8*)(qp + bkq + (size_t)st0 * 1024 + g_cg);
    pq1 = *(const bf16x8*)(qp + bkq + (size_t)st1 * 1024 + g_cg);
    if (lane < 32) {
      const __bf16* src = va_vh ? (const __bf16*)a : (const __bf16*)v;
      pva = *(const bf16x4v*)(src + bva + (size_t)(t0 + va_st) * 1024);
    }
  };
  auto commit = [&](int cb) {
    {
      u32x4 wk = __builtin_bit_cast(u32x4, pk0);
      u32x4 wq = __builtin_bit_cast(u32x4, pq0);
      u32x2 lo, hi;
      lo[0] = wk[0]; lo[1] = wk[1]; hi[0] = wk[2]; hi[1] = wk[3];
      *(u32x2*)&skT[cb][sgp][g_st * 4]     = lo;
      *(u32x2*)&skT[cb][sgp + 1][g_st * 4] = hi;
      lo[0] = wq[0]; lo[1] = wq[1]; hi[0] = wq[2]; hi[1] = wq[3];
      *(u32x2*)&sqT[cb][sgp][g_st * 4]     = lo;
      *(u32x2*)&sqT[cb][sgp + 1][g_st * 4] = hi;
    }
    {
      u32x4 wk = __builtin_bit_cast(u32x4, pk1);
      u32x4 wq = __builtin_bit_cast(u32x4, pq1);
      u32x2 lo, hi;
      lo[0] = wk[0]; lo[1] = wk[1]; hi[0] = wk[2]; hi[1] = wk[3];
      *(u32x2*)&skT[cb][sgp][(8 + g_st) * 4]     = lo;
      *(u32x2*)&skT[cb][sgp + 1][(8 + g_st) * 4] = hi;
      lo[0] = wq[0]; lo[1] = wq[1]; hi[0] = wq[2]; hi[1] = wq[3];
      *(u32x2*)&sqT[cb][sgp][(8 + g_st) * 4]     = lo;
      *(u32x2*)&sqT[cb][sgp + 1][(8 + g_st) * 4] = hi;
    }
    if (lane < 32) {
#pragma unroll
      for (int r = 0; r < 4; ++r) svaT[cb][va_vh][r][va_st] = pva[r];
    }
  };

  fetch(0); commit(0);

  f32x2 S20 = {0.f, 0.f}, S21 = {0.f, 0.f};
  f32x2 Sold0 = {0.f, 0.f}, Sold1 = {0.f, 0.f};
  float u = 0.f, cc = 0.f, aprev = 0.f;

  auto unpk = [&](unsigned int w) -> f32x2 {
    f32x2 r; r[0] = bcf(w << 16); r[1] = bcf(w & 0xffff0000u); return r;
  };

  for (int c = 0; c < 128; ++c) {
    const int buf = c & 1;
    const bool hasNext = (c + 1 < 128);

    if (hasNext) fetch((c + 1) * 16);

    u32x4 kA, qA, kB, qB, kC, qC;
    unsigned int vA, aA, vB, aB, vC, aC;
    f32x2 bA, gA, bB, gB, bC, gC;

    LOADG(kA, qA, vA, aA, bA, gA, 0)
    LOADG(kB, qB, vB, aB, bB, gB, 1)
    LOADG(kC, qC, vC, aC, bC, gC, 2)

    f32x2 k2c0 = unpk(kA[0]);
    f32x2 k2c1 = unpk(kA[1]);
    {
      f32x2 dd = Sold0 * k2c0;
      dd += Sold1 * k2c1;
      float un = dd[0] + dd[1];
      un += dpp_f<0xB1>(un);
      un += dpp_f<0x4E>(un);
      un += dpp_f<0x141>(un);
      un += dpp_f<0x140>(un);
      u = un;
    }

    SCAN_STEP(0,  kA[2], kA[3], qA[0], qA[1], vA, aA, bA[0], gA[0], false)
    SCAN_STEP(1,  kB[0], kB[1], qA[2], qA[3], vA, aA, bA[1], gA[1], false)
    LOADG(kA, qA, vA, aA, bA, gA, 3)
    SCAN_STEP(2,  kB[2], kB[3], qB[0], qB[1], vB, aB, bB[0], gB[0], false)
    SCAN_STEP(3,  kC[0], kC[1], qB[2], qB[3], vB, aB, bB[1], gB[1], false)
    LOADG(kB, qB, vB, aB, bB, gB, 4)
    SCAN_STEP(4,  kC[2], kC[3], qC[0], qC[1], vC, aC, bC[0], gC[0], false)
    SCAN_STEP(5,  kA[0], kA[1], qC[2], qC[3], vC, aC, bC[1], gC[1], false)
    LOADG(kC, qC, vC, aC, bC, gC, 5)
    SCAN_STEP(6,  kA[2], kA[3], qA[0], qA[1], vA, aA, bA[0], gA[0], false)
    SCAN_STEP(7,  kB[0], kB[1], qA[2], qA[3], vA, aA, bA[1], gA[1], false)
    LOADG(kA, qA, vA, aA, bA, gA, 6)
    SCAN_STEP(8,  kB[2], kB[3], qB[0], qB[1], vB, aB, bB[0], gB[0], false)
    SCAN_STEP(9,  kC[0], kC[1], qB[2], qB[3], vB, aB, bB[1], gB[1], false)
    LOADG(kB, qB, vB, aB, bB, gB, 7)
    SCAN_STEP(10, kC[2], kC[3], qC[0], qC[1], vC, aC, bC[0], gC[0], false)
    SCAN_STEP(11, kA[0], kA[1], qC[2], qC[3], vC, aC, bC[1], gC[1], false)
    SCAN_STEP(12, kA[2], kA[3], qA[0], qA[1], vA, aA, bA[0], gA[0], false)
    SCAN_STEP(13, kB[0], kB[1], qA[2], qA[3], vA, aA, bA[1], gA[1], false)
    SCAN_STEP(14, kB[2], kB[3], qB[0], qB[1], vB, aB, bB[0], gB[0], false)
    SCAN_STEP(15, kB[2], kB[3], qB[2], qB[3], vB, aB, bB[1], gB[1], true)

    {
      int st = lane >> 2, rr = lane & 3;
      float4 A0 = *(const float4*)&so[st][rr * 16];
      float4 A1 = *(const float4*)&so[st][rr * 16 + 4];
      float4 A2 = *(const float4*)&so[st][rr * 16 + 8];
      float4 A3 = *(const float4*)&so[st][rr * 16 + 12];
      float s = (((A0.x + A0.y) + (A0.z + A0.w)) + ((A1.x + A1.y) + (A1.z + A1.w)))
              + (((A2.x + A2.y) + (A2.z + A2.w)) + ((A3.x + A3.y) + (A3.z + A3.w)));
      so2[st][rr] = cvt_bf16(s);
    }
    if (lane < 16)
      *(bf16x4v*)((__bf16*)o + bva + (size_t)(c * 16 + lane) * 1024) =
          *(const bf16x4v*)&so2[lane][0];

    if (hasNext) commit(buf ^ 1);
  }
}

// LayerNorm over DV=64 per (b,t,h) row, *ln_w+ln_b, *gate -> bf16 (fallback)
__global__ __launch_bounds__(256) void ln_gate_kernel(
    const bf16* __restrict__ o, const bf16* __restrict__ g,
    const float* __restrict__ lnw, const float* __restrict__ lnb,
    bf16* __restrict__ out)
{
  int row = blockIdx.x * 4 + (threadIdx.x >> 6);
  int lane = threadIdx.x & 63;
  size_t idx = (size_t)row * 64 + lane;
  float xv = (float)o[idx];
  float mu = xv;
#pragma unroll
  for (int s = 1; s < 64; s <<= 1) mu += __shfl_xor(mu, s);
  mu *= (1.f / 64.f);
  float d = xv - mu;
  float vv = d * d;
#pragma unroll
  for (int s = 1; s < 64; s <<= 1) vv += __shfl_xor(vv, s);
  vv *= (1.f / 64.f);
  float y = d * rsqrtf(vv + 1e-5f) * lnw[lane] + lnb[lane];
  y *= (float)g[idx];
  out[idx] = (bf16)y;
}

extern "C" void kernel_launch(void* const* d_in, const int* in_sizes, int n_in,
                              void* d_out, int out_size, void* d_ws, size_t ws_size,
                              hipStream_t stream)
{
  const float* x   = (const float*)d_in[0];
  const float* Wq  = (const float*)d_in[1];
  const float* Wk  = (const float*)d_in[2];
  const float* Wv  = (const float*)d_in[3];
  const float* Wa  = (const float*)d_in[4];
  const float* ba  = (const float*)d_in[5];
  const float* Wb  = (const float*)d_in[6];
  const float* bb  = (const float*)d_in[7];
  const float* Wg  = (const float*)d_in[8];
  const float* Wo  = (const float*)d_in[9];
  const float* qcw = (const float*)d_in[10];
  const float* qcb = (const float*)d_in[11];
  const float* kcw = (const float*)d_in[12];
  const float* kcb = (const float*)d_in[13];
  const float* vcw = (const float*)d_in[14];
  const float* vcb = (const float*)d_in[15];
  const float* lnw = (const float*)d_in[16];
  const float* lnb = (const float*)d_in[17];

  const int M = 4096, HID = 1024;
  const size_t PLANE = (size_t)M * HID;
  const size_t PB = PLANE * sizeof(bf16);          // 8 MB bf16 plane

  char* ws = (char*)d_ws;
  float* outf = (float*)d_out;
  const bool rich = (ws_size >= 5 * PB + 1024);

  dim3 blk(256);
  dim3 g8(8, 32);
  int nconv = (int)((size_t)M * 128 / 256);

  if (rich) {
    bf16* P0 = (bf16*)(ws);
    bf16* P1 = (bf16*)(ws + PB);
    bf16* P2 = (bf16*)(ws + 2 * PB);
    bf16* P3 = (bf16*)(ws + 3 * PB);
    bf16* P4 = (bf16*)(ws + 4 * PB);
    bf16*  xb    = (bf16*)d_out;                            // [0,8M)
    bf16*  W4b   = (bf16*)((char*)d_out + 8 * 1024 * 1024); // [8M,16M)
    bf16*  Kb    = xb;                                      // k-plane
    bf16*  Qb    = W4b;                                     // q-plane
    float* betab = (float*)P4;
    float* gkk   = (float*)((char*)P4 + 256 * 1024);
    bf16*  Wgb   = (bf16*)((char*)P4 + 1024 * 1024);
    bf16*  Wob   = (bf16*)((char*)P4 + 3 * 1024 * 1024);

    // 1. convert x + 6 weight matrices to bf16
    cvtw_kernel<<<10240, blk, 0, stream>>>(x, Wq, Wk, Wv, Wa, Wg, Wo,
                                           xb, W4b, Wgb, Wob);
    // 2. fused 4-projection + beta GEMM (1-D grid, XCD swizzle)
    mega_gemm2<<<1056, blk, 0, stream>>>(xb, W4b, Wb, bb, ba, P0, betab);
    // 3. conv q (P0->Qb) + conv k (P1->Kb) -- disjoint planes
    conv2_kernel<<<4096, blk, 0, stream>>>(P0, P1, qcw, qcb, kcw, kcb, Qb, Kb);
    // 4. conv v (P2->P1) + kk (reads Kb from launch 3)
    convv_kk_kernel<<<3072, blk, 0, stream>>>(P2, vcw, vcb, P1, Kb, betab, gkk);
    // 5. FUSED scan (o->P0) + g-GEMM (sigmoid(x@Wgb^T)->P2)
    scan_gemm_kernel<<<768, blk, 0, stream>>>(Qb, Kb, P1, P3, betab, gkk, P0,
                                              x, Wgb, P2);
    // 6. final GEMM with fused LN+gate (1-D grid, XCD swizzle)
    gemm_bb_ln<<<256, blk, 0, stream>>>(P0, P2, lnw, lnb, Wob, outf);
  } else {
    bf16* P  = (bf16*)(ws);
    bf16* qb = (bf16*)(ws + PB);
    bf16* kb = (bf16*)(ws + 2 * PB);
    bf16* vb = (bf16*)(ws + 3 * PB);
    float* betab = (float*)d_out;
    float* gkk   = (float*)((char*)d_out + 256 * 1024);
    bf16*  ob    = (bf16*)((char*)d_out + 8 * 1024 * 1024);

    gemm_bt<2, true><<<g8, blk, 0, stream>>>(x, Wq, nullptr, nullptr, P, M, HID, HID);
    conv_silu_kernel<<<nconv, blk, 0, stream>>>(P, qcw, qcb, qb, 1.f);
    gemm_bt<2, true><<<g8, blk, 0, stream>>>(x, Wk, nullptr, nullptr, P, M, HID, HID);
    conv_silu_kernel<<<nconv, blk, 0, stream>>>(P, kcw, kcb, kb, 0.125f);
    gemm_bt<2, true><<<g8, blk, 0, stream>>>(x, Wv, nullptr, nullptr, P, M, HID, HID);
    conv_silu_kernel<<<nconv, blk, 0, stream>>>(P, vcw, vcb, vb, 1.f);
    gemm_bt<3, true><<<g8, blk, 0, stream>>>(x, Wa, ba, nullptr, P, M, HID, HID);
    gemm_bt<5, true><<<dim3(1, 32), blk, 0, stream>>>(x, Wb, bb, betab, nullptr, M, 16, HID);
    kk_kernel<<<1024, blk, 0, stream>>>(kb, betab, gkk);
    scan_gemm_kernel<<<512, blk, 0, stream>>>(qb, kb, vb, P, betab, gkk, ob,
                                              x, nullptr, nullptr);
    gemm_bt<3, true><<<g8, blk, 0, stream>>>(x, Wg, nullptr, nullptr, qb, M, HID, HID);
    ln_gate_kernel<<<M * 16 / 4, blk, 0, stream>>>(ob, qb, lnw, lnb, kb);
    gemm_bt<4, false><<<g8, blk, 0, stream>>>(kb, Wo, nullptr, outf, nullptr, M, HID, HID);
  }
}

// Round 14
// 435.735 us; speedup vs baseline: 1.6029x; 1.0075x over previous
//
#include <hip/hip_runtime.h>
#include <hip/hip_bf16.h>
#include <cstdint>

// B=2, T=2048, HID=1024, H=16, DK=DV=64, K(conv)=4. fp32 in/out.
// RICH memory plan (ws >= 40MB): ws = P0..P4 (8MB bf16 planes).
//  d_out[0,8M): xb -> Kb (k-plane);  d_out[8M,16M): W4b -> Qb (q-plane)
//  P4: [0,256K) betab fp32; [256K,512K) gkk; [1M,3M) Wgb; [3M,5M) Wob
//  P0: zq -> scan o;  P1: zk -> v-plane;  P2: zv -> g-plane;  P3: a plane
// Launches (6): cvtw -> mega_gemm2(+beta) -> conv2(q,k) -> convv_kk
//   -> FUSED scan+g-GEMM -> gemm_bb_ln (final GEMM with LN+gate fused).
//
// R14: gemm_bb_ln was 256 blocks = 1 block/CU (m97-structure worst case:
// barrier drain fully exposed, last kernel so nothing hides it). Split to
// 64-row tiles -> 512 blocks = 2/CU (acc[2][4]/wave, same MFMA total).
// Scan core + rest: R13-proven, untouched.

using bf16 = __hip_bfloat16;
typedef __bf16 bf16x8 __attribute__((ext_vector_type(8)));
typedef __bf16 bf16x4v __attribute__((ext_vector_type(4)));
typedef float f32x4 __attribute__((ext_vector_type(4)));
typedef float f32x2 __attribute__((ext_vector_type(2)));
typedef unsigned int u32x4 __attribute__((ext_vector_type(4)));
typedef unsigned int u32x2 __attribute__((ext_vector_type(2)));

__device__ __forceinline__ __bf16 cvt_bf16(float f) {
  __hip_bfloat16 h = (__hip_bfloat16)f;
  return *reinterpret_cast<__bf16*>(&h);
}
__device__ __forceinline__ void async_copy16(const void* g, void* l) {
  __builtin_amdgcn_global_load_lds((const __attribute__((address_space(1))) void*)g,
                                   (__attribute__((address_space(3))) void*)l,
                                   16, 0, 0);
}
__device__ __forceinline__ float bcf(unsigned int u) { return __builtin_bit_cast(float, u); }
template <int CTRL>
__device__ __forceinline__ float dpp_f(float x) {
  int y = __builtin_amdgcn_update_dpp(0, __builtin_bit_cast(int, x), CTRL, 0xF, 0xF, true);
  return __builtin_bit_cast(float, y);
}

// fp32 -> bf16: x (blocks 0..4095), W4 (4096..8191), Wg (8192..9215),
// Wo (9216..10239).
__global__ __launch_bounds__(256) void cvtw_kernel(
    const float* __restrict__ x, const float* __restrict__ Wq,
    const float* __restrict__ Wk, const float* __restrict__ Wv,
    const float* __restrict__ Wa, const float* __restrict__ Wg,
    const float* __restrict__ Wo, bf16* __restrict__ xb,
    bf16* __restrict__ w4b, bf16* __restrict__ wgb, bf16* __restrict__ wob)
{
  int blk = blockIdx.x;
  const float* src;
  __bf16* dst;
  size_t off;
  if (blk < 4096) {
    src = x; dst = (__bf16*)xb;
    off = (size_t)blk * 1024 + threadIdx.x * 4;
  } else if (blk < 8192) {
    int wb = blk - 4096;
    int wi = wb >> 10;
    src = (wi == 0) ? Wq : (wi == 1) ? Wk : (wi == 2) ? Wv : Wa;
    dst = (__bf16*)w4b + (size_t)wi * 1024 * 1024;
    off = (size_t)(wb & 1023) * 1024 + threadIdx.x * 4;
  } else if (blk < 9216) {
    src = Wg; dst = (__bf16*)wgb;
    off = (size_t)(blk - 8192) * 1024 + threadIdx.x * 4;
  } else {
    src = Wo; dst = (__bf16*)wob;
    off = (size_t)(blk - 9216) * 1024 + threadIdx.x * 4;
  }
  float4 f = *(const float4*)(src + off);
  bf16x4v t;
  t[0] = cvt_bf16(f.x); t[1] = cvt_bf16(f.y); t[2] = cvt_bf16(f.z); t[3] = cvt_bf16(f.w);
  *(bf16x4v*)(dst + off) = t;
}

// C = A * Bt^T. A: MxK (bf16 async-staged unless A_FP32); Bt: NxK fp32.
// MODE 2: raw->bf16; 3: sigmoid(acc+bias)->bf16; 4: raw->fp32; 5: sigmoid(acc+bias)->fp32 TRANSPOSED
template <int MODE, bool A_FP32>
__global__ __launch_bounds__(256) void gemm_bt(
    const void* __restrict__ Av, const float* __restrict__ Bt,
    const float* __restrict__ bias, float* __restrict__ Cf, bf16* __restrict__ Cb,
    int M, int N, int K)
{
  __shared__ __align__(16) __bf16 As[128 * 32];
  __shared__ __align__(16) __bf16 Bs[128 * 32];

  const int tid  = threadIdx.x;
  const int lane = tid & 63;
  const int wave = tid >> 6;
  const int tile_m = blockIdx.y * 128;
  const int tile_n = blockIdx.x * 128;
  const int wm = (wave >> 1) * 64;
  const int wn = (wave & 1) * 64;

  const int srow = lane >> 2;
  const int scol = (lane & 3) * 8;

  f32x4 acc[4][4];
#pragma unroll
  for (int i = 0; i < 4; ++i)
#pragma unroll
    for (int j = 0; j < 4; ++j) acc[i][j] = {0.f, 0.f, 0.f, 0.f};

  for (int k0 = 0; k0 < K; k0 += 32) {
    float4 b0[2], b1[2], a0[2], a1[2];
#pragma unroll
    for (int s = 0; s < 2; ++s) {
      int brow = tile_n + s * 64 + wave * 16 + srow;
      if (brow > N - 1) brow = N - 1;
      const float* bp = Bt + (size_t)brow * K + k0 + scol;
      b0[s] = *(const float4*)bp;
      b1[s] = *(const float4*)(bp + 4);
      if (A_FP32) {
        int arow = tile_m + s * 64 + wave * 16 + srow;
        const float* ap = (const float*)Av + (size_t)arow * K + k0 + scol;
        a0[s] = *(const float4*)ap;
        a1[s] = *(const float4*)(ap + 4);
      }
    }
    __syncthreads();
#pragma unroll
    for (int s = 0; s < 2; ++s) {
      if (!A_FP32) {
        int arow = tile_m + s * 64 + wave * 16 + srow;
        async_copy16((const __bf16*)Av + (size_t)arow * K + k0 + scol,
                     &As[(s * 64 + wave * 16 + srow) * 32 + scol]);
      } else {
        bf16x8 ua;
        ua[0] = cvt_bf16(a0[s].x); ua[1] = cvt_bf16(a0[s].y);
        ua[2] = cvt_bf16(a0[s].z); ua[3] = cvt_bf16(a0[s].w);
        ua[4] = cvt_bf16(a1[s].x); ua[5] = cvt_bf16(a1[s].y);
        ua[6] = cvt_bf16(a1[s].z); ua[7] = cvt_bf16(a1[s].w);
        *(bf16x8*)&As[(s * 64 + wave * 16 + srow) * 32 + scol] = ua;
      }
      bf16x8 u;
      u[0] = cvt_bf16(b0[s].x); u[1] = cvt_bf16(b0[s].y);
      u[2] = cvt_bf16(b0[s].z); u[3] = cvt_bf16(b0[s].w);
      u[4] = cvt_bf16(b1[s].x); u[5] = cvt_bf16(b1[s].y);
      u[6] = cvt_bf16(b1[s].z); u[7] = cvt_bf16(b1[s].w);
      *(bf16x8*)&Bs[(s * 64 + wave * 16 + srow) * 32 + scol] = u;
    }
    __syncthreads();

    bf16x8 af[4], bfr[4];
#pragma unroll
    for (int i = 0; i < 4; ++i)
      af[i] = *(const bf16x8*)&As[(wm + i * 16 + (lane & 15)) * 32 + (lane >> 4) * 8];
#pragma unroll
    for (int j = 0; j < 4; ++j)
      bfr[j] = *(const bf16x8*)&Bs[(wn + j * 16 + (lane & 15)) * 32 + (lane >> 4) * 8];

#pragma unroll
    for (int i = 0; i < 4; ++i)
#pragma unroll
      for (int j = 0; j < 4; ++j)
        acc[i][j] = __builtin_amdgcn_mfma_f32_16x16x32_bf16(af[i], bfr[j], acc[i][j], 0, 0, 0);
  }

#pragma unroll
  for (int i = 0; i < 4; ++i) {
#pragma unroll
    for (int j = 0; j < 4; ++j) {
#pragma unroll
      for (int r = 0; r < 4; ++r) {
        int gm = tile_m + wm + i * 16 + (lane >> 4) * 4 + r;
        int gn = tile_n + wn + j * 16 + (lane & 15);
        if (gn < N) {
          float val = acc[i][j][r];
          if (MODE == 3 || MODE == 5) {
            float bv = bias ? bias[gn] : 0.f;
            val = 1.f / (1.f + __expf(-(val + bv)));
          }
          if (MODE == 4)      Cf[(size_t)gm * N + gn] = val;
          else if (MODE == 5) Cf[(size_t)gn * M + gm] = val;
          else                Cb[(size_t)gm * N + gn] = (bf16)val;
        }
      }
    }
  }
}

// Final GEMM with fused LN+gate on the A operand. 64-row tiles -> 512
// blocks = 2 blocks/CU (R14: was 256 = 1/CU, barrier drain fully exposed).
// 1-D grid, XCD-bijective swizzle over 64 M-tiles x 8 N-tiles. Head loop
// software-pipelined (next head's o/g loads in flight across MFMA).
__global__ __launch_bounds__(256) void gemm_bb_ln(
    const bf16* __restrict__ o, const bf16* __restrict__ g,
    const float* __restrict__ lnw, const float* __restrict__ lnb,
    const bf16* __restrict__ Bw, float* __restrict__ C)
{
  __shared__ __align__(16) __bf16 As2[64][72];    // 9 KB (72-pad)
  __shared__ __align__(16) __bf16 Bs[128 * 32];   // 8 KB
  __shared__ float sW[64], sB[64];

  const int bx = blockIdx.x;                       // 512 blocks
  const int logical = (bx & 7) * 64 + (bx >> 3);   // bijective XCD swizzle
  const int tile_m = (logical >> 3) * 64;
  const int tile_n = (logical & 7) * 128;

  const int tid  = threadIdx.x;
  const int lane = tid & 63;
  const int wave = tid >> 6;
  const int wm = (wave >> 1) * 32;     // row quadrant 0/32
  const int wn = (wave & 1) * 64;      // col half 0/64
  const int srow = lane >> 2;
  const int scol = (lane & 3) * 8;
  const int rl  = tid >> 2;            // local A row 0..63
  const int qtr = tid & 3;             // column quarter (16 cols each)

  if (tid < 64) { sW[tid] = lnw[tid]; sB[tid] = lnb[tid]; }

  const __bf16* obase = (const __bf16*)o + (size_t)(tile_m + rl) * 1024 + qtr * 16;
  const __bf16* gbase = (const __bf16*)g + (size_t)(tile_m + rl) * 1024 + qtr * 16;

  f32x4 acc[2][4];
#pragma unroll
  for (int i = 0; i < 2; ++i)
#pragma unroll
    for (int j = 0; j < 4; ++j) acc[i][j] = {0.f, 0.f, 0.f, 0.f};

  // preload head 0 (16 cols per thread)
  bf16x8 ov0, ov1, gv0, gv1;
  ov0 = *(const bf16x8*)(obase);
  ov1 = *(const bf16x8*)(obase + 8);
  gv0 = *(const bf16x8*)(gbase);
  gv1 = *(const bf16x8*)(gbase + 8);

  for (int h = 0; h < 16; ++h) {
    // issue NEXT head's o/g loads first (in flight across barriers + MFMA)
    bf16x8 no0, no1, ng0, ng1;
    if (h + 1 < 16) {
      const __bf16* op = obase + (h + 1) * 64;
      const __bf16* gp = gbase + (h + 1) * 64;
      no0 = *(const bf16x8*)(op);
      no1 = *(const bf16x8*)(op + 8);
      ng0 = *(const bf16x8*)(gp);
      ng1 = *(const bf16x8*)(gp + 8);
    }

    __syncthreads();   // prior head's MFMA reads of As2 complete (+ sW visible)

    // ---- LN + gate for head h -> As2 (row rl; 4 threads per row) ----
    float sum = 0.f;
#pragma unroll
    for (int e = 0; e < 8; ++e)
      sum += (float)ov0[e] + (float)ov1[e];
    sum += __shfl_xor(sum, 1);
    sum += __shfl_xor(sum, 2);
    float mu = sum * (1.f / 64.f);
    float vv = 0.f;
#pragma unroll
    for (int e = 0; e < 8; ++e) {
      float d0 = (float)ov0[e] - mu, d1 = (float)ov1[e] - mu;
      vv += d0 * d0 + d1 * d1;
    }
    vv += __shfl_xor(vv, 1);
    vv += __shfl_xor(vv, 2);
    float rstd = rsqrtf(vv * (1.f / 64.f) + 1e-5f);

    bf16x8 res0, res1;
#pragma unroll
    for (int e = 0; e < 8; ++e) {
      int c0 = qtr * 16 + e;
      res0[e] = cvt_bf16((((float)ov0[e] - mu) * rstd * sW[c0] + sB[c0]) * (float)gv0[e]);
      res1[e] = cvt_bf16((((float)ov1[e] - mu) * rstd * sW[c0 + 8] + sB[c0 + 8]) * (float)gv1[e]);
    }
    *(bf16x8*)&As2[rl][qtr * 16 + 0] = res0;
    *(bf16x8*)&As2[rl][qtr * 16 + 8] = res1;

#pragma unroll
    for (int sub = 0; sub < 2; ++sub) {
      if (sub) __syncthreads();      // protect Bs restage from sub0 reads
      int k0 = h * 64 + sub * 32;
#pragma unroll
      for (int s = 0; s < 2; ++s) {
        int brow = tile_n + s * 64 + wave * 16 + srow;
        async_copy16((const __bf16*)Bw + (size_t)brow * 1024 + k0 + scol,
                     &Bs[(s * 64 + wave * 16 + srow) * 32 + scol]);
      }
      __syncthreads();               // Bs landed + As2 visible

      bf16x8 af[2], bfr[4];
#pragma unroll
      for (int i = 0; i < 2; ++i)
        af[i] = *(const bf16x8*)&As2[wm + i * 16 + (lane & 15)][(lane >> 4) * 8 + sub * 32];
#pragma unroll
      for (int j = 0; j < 4; ++j)
        bfr[j] = *(const bf16x8*)&Bs[(wn + j * 16 + (lane & 15)) * 32 + (lane >> 4) * 8];

#pragma unroll
      for (int i = 0; i < 2; ++i)
#pragma unroll
        for (int j = 0; j < 4; ++j)
          acc[i][j] = __builtin_amdgcn_mfma_f32_16x16x32_bf16(af[i], bfr[j], acc[i][j], 0, 0, 0);
    }

    if (h + 1 < 16) {
      ov0 = no0; ov1 = no1;
      gv0 = ng0; gv1 = ng1;
    }
  }

#pragma unroll
  for (int i = 0; i < 2; ++i)
#pragma unroll
    for (int j = 0; j < 4; ++j)
#pragma unroll
      for (int r = 0; r < 4; ++r) {
        int gm = tile_m + wm + i * 16 + (lane >> 4) * 4 + r;
        int gn = tile_n + wn + j * 16 + (lane & 15);
        C[(size_t)gm * 1024 + gn] = acc[i][j][r];
      }
}

// Fused 4-projection + beta GEMM. 1-D grid 1056 blocks:
//  bx < 1024: GEMM tiles, XCD-bijective swizzle; bx >= 1024: beta tiles.
__global__ __launch_bounds__(256) void mega_gemm2(
    const bf16* __restrict__ Av, const bf16* __restrict__ W4b,
    const float* __restrict__ Wb, const float* __restrict__ bb,
    const float* __restrict__ ba, bf16* __restrict__ C4,
    float* __restrict__ betab)
{
  __shared__ __align__(16) __bf16 As[128 * 32];
  __shared__ __align__(16) __bf16 Bs[128 * 32];

  const int bx = blockIdx.x;
  const bool isbeta = (bx >= 1024);
  int tile_m, tile_n;
  if (!isbeta) {
    const int logical = (bx & 7) * 128 + (bx >> 3);  // bijective XCD swizzle
    tile_m = (logical >> 5) * 128;
    tile_n = (logical & 31) * 128;
  } else {
    tile_m = (bx - 1024) * 128;
    tile_n = 0;
  }
  const int grp = tile_n >> 10;
  const int tnl = tile_n & 1023;

  const int tid  = threadIdx.x;
  const int lane = tid & 63;
  const int wave = tid >> 6;
  const int wm = (wave >> 1) * 64;
  const int wn = (wave & 1) * 64;

  const int srow = lane >> 2;
  const int scol = (lane & 3) * 8;

  f32x4 acc[4][4];
#pragma unroll
  for (int i = 0; i < 4; ++i)
#pragma unroll
    for (int j = 0; j < 4; ++j) acc[i][j] = {0.f, 0.f, 0.f, 0.f};

  const __bf16* Wp = (const __bf16*)W4b + (size_t)grp * 1024 * 1024;

  for (int k0 = 0; k0 < 1024; k0 += 32) {
    float4 b0[2], b1[2];
    if (isbeta) {
#pragma unroll
      for (int s = 0; s < 2; ++s) {
        int brow = s * 64 + wave * 16 + srow;
        if (brow > 15) brow = 15;
        const float* bp = Wb + (size_t)brow * 1024 + k0 + scol;
        b0[s] = *(const float4*)bp;
        b1[s] = *(const float4*)(bp + 4);
      }
    }
    __syncthreads();
#pragma unroll
    for (int s = 0; s < 2; ++s) {
      int arow = tile_m + s * 64 + wave * 16 + srow;
      async_copy16((const __bf16*)Av + (size_t)arow * 1024 + k0 + scol,
                   &As[(s * 64 + wave * 16 + srow) * 32 + scol]);
      if (!isbeta) {
        int brow = tnl + s * 64 + wave * 16 + srow;
        async_copy16(Wp + (size_t)brow * 1024 + k0 + scol,
                     &Bs[(s * 64 + wave * 16 + srow) * 32 + scol]);
      } else {
        bf16x8 u;
        u[0] = cvt_bf16(b0[s].x); u[1] = cvt_bf16(b0[s].y);
        u[2] = cvt_bf16(b0[s].z); u[3] = cvt_bf16(b0[s].w);
        u[4] = cvt_bf16(b1[s].x); u[5] = cvt_bf16(b1[s].y);
        u[6] = cvt_bf16(b1[s].z); u[7] = cvt_bf16(b1[s].w);
        *(bf16x8*)&Bs[(s * 64 + wave * 16 + srow) * 32 + scol] = u;
      }
    }
    __syncthreads();

    bf16x8 af[4], bfr[4];
#pragma unroll
    for (int i = 0; i < 4; ++i)
      af[i] = *(const bf16x8*)&As[(wm + i * 16 + (lane & 15)) * 32 + (lane >> 4) * 8];
#pragma unroll
    for (int j = 0; j < 4; ++j)
      bfr[j] = *(const bf16x8*)&Bs[(wn + j * 16 + (lane & 15)) * 32 + (lane >> 4) * 8];

#pragma unroll
    for (int i = 0; i < 4; ++i)
#pragma unroll
      for (int j = 0; j < 4; ++j)
        acc[i][j] = __builtin_amdgcn_mfma_f32_16x16x32_bf16(af[i], bfr[j], acc[i][j], 0, 0, 0);
  }

  if (!isbeta) {
    bf16* Cp = (bf16*)((__bf16*)C4 + (size_t)grp * 4096 * 1024);
#pragma unroll
    for (int i = 0; i < 4; ++i)
#pragma unroll
      for (int j = 0; j < 4; ++j)
#pragma unroll
        for (int r = 0; r < 4; ++r) {
          int gm = tile_m + wm + i * 16 + (lane >> 4) * 4 + r;
          int col = tnl + wn + j * 16 + (lane & 15);
          float val = acc[i][j][r];
          if (grp == 3) val = 1.f / (1.f + __expf(-(val + ba[col])));
          ((__bf16*)Cp)[(size_t)gm * 1024 + col] = cvt_bf16(val);
        }
  } else {
#pragma unroll
    for (int i = 0; i < 4; ++i)
#pragma unroll
      for (int j = 0; j < 4; ++j)
#pragma unroll
        for (int r = 0; r < 4; ++r) {
          int gm = tile_m + wm + i * 16 + (lane >> 4) * 4 + r;
          int gn = wn + j * 16 + (lane & 15);
          if (gn < 16) {
            float val = 1.f / (1.f + __expf(-(acc[i][j][r] + bb[gn])));
            betab[(size_t)gn * 4096 + gm] = val;
          }
        }
  }
}

// shared conv body: causal depthwise K=4 + bias + SiLU (+scale), x8 vec.
__device__ __forceinline__ void conv_body(
    int idx, const bf16* __restrict__ z, const float* __restrict__ w,
    const float* __restrict__ bias, bf16* __restrict__ out, float scale)
{
  int c8 = idx & 127;
  int m  = idx >> 7;
  int t  = m & 2047;
  int c0 = c8 * 8;

  const __bf16* base = (const __bf16*)z + (size_t)m * 1024 + c0;
  const bf16x8 zzero = __builtin_bit_cast(bf16x8, (u32x4){0u, 0u, 0u, 0u});
  bf16x8 z3 = *(const bf16x8*)base;
  bf16x8 z2 = (t >= 1) ? *(const bf16x8*)(base - 1024) : zzero;
  bf16x8 z1 = (t >= 2) ? *(const bf16x8*)(base - 2048) : zzero;
  bf16x8 z0 = (t >= 3) ? *(const bf16x8*)(base - 3072) : zzero;

  const float* wp = w + c0 * 4;
  bf16x8 res;
#pragma unroll
  for (int e = 0; e < 8; ++e) {
    float4 we = *(const float4*)(wp + e * 4);
    float acc = bias[c0 + e] + (float)z3[e] * we.w;
    acc += (float)z2[e] * we.z;
    acc += (float)z1[e] * we.y;
    acc += (float)z0[e] * we.x;
    float s = acc / (1.f + __expf(-acc));
    res[e] = cvt_bf16(s * scale);
  }
  *(bf16x8*)((__bf16*)out + (size_t)m * 1024 + c0) = res;
}

// standalone conv (fallback path)
__global__ __launch_bounds__(256) void conv_silu_kernel(
    const bf16* __restrict__ z, const float* __restrict__ w,
    const float* __restrict__ bias, bf16* __restrict__ out, float scale)
{
  conv_body(blockIdx.x * 256 + threadIdx.x, z, w, bias, out, scale);
}

// conv_q + conv_k in one launch (disjoint planes). Grid 4096.
__global__ __launch_bounds__(256) void conv2_kernel(
    const bf16* __restrict__ zq, const bf16* __restrict__ zk,
    const float* __restrict__ qcw, const float* __restrict__ qcb,
    const float* __restrict__ kcw, const float* __restrict__ kcb,
    bf16* __restrict__ oq, bf16* __restrict__ ok)
{
  int sec = blockIdx.x >> 11;
  int bx  = blockIdx.x & 2047;
  int idx = bx * 256 + threadIdx.x;
  if (sec == 0) conv_body(idx, zq, qcw, qcb, oq, 1.f);
  else          conv_body(idx, zk, kcw, kcb, ok, 0.125f);
}

// conv_v + kk in one launch (kk reads k from PREVIOUS launch). Grid 3072.
__global__ __launch_bounds__(256) void convv_kk_kernel(
    const bf16* __restrict__ zv, const float* __restrict__ vcw,
    const float* __restrict__ vcb, bf16* __restrict__ ov,
    const bf16* __restrict__ k, const float* __restrict__ betab,
    float* __restrict__ G)
{
  if (blockIdx.x < 2048) {
    conv_body(blockIdx.x * 256 + threadIdx.x, zv, vcw, vcb, ov, 1.f);
    return;
  }
  int gtid = (blockIdx.x - 2048) * 256 + threadIdx.x;
  int out = gtid >> 2;           // h*4096 + m
  int j   = gtid & 3;
  int h = out >> 12;
  int m = out & 4095;
  int t = m & 2047;
  float s = 0.f;
  if (t > 0) {
    const __bf16* r1 = (const __bf16*)k + (size_t)m * 1024 + h * 64 + j * 16;
    const __bf16* r0 = r1 - 1024;
    bf16x8 a0 = *(const bf16x8*)r0;
    bf16x8 a1 = *(const bf16x8*)(r0 + 8);
    bf16x8 b0 = *(const bf16x8*)r1;
    bf16x8 b1 = *(const bf16x8*)(r1 + 8);
#pragma unroll
    for (int e = 0; e < 8; ++e)
      s += (float)a0[e] * (float)b0[e] + (float)a1[e] * (float)b1[e];
  }
  s += __shfl_xor(s, 1);
  s += __shfl_xor(s, 2);
  if (j == 0) G[out] = betab[out] * s;
}

// kk standalone (fallback)
__global__ __launch_bounds__(256) void kk_kernel(
    const bf16* __restrict__ k, const float* __restrict__ betab,
    float* __restrict__ G)
{
  int tid = blockIdx.x * 256 + threadIdx.x;
  int out = tid >> 2;
  int j   = tid & 3;
  int h = out >> 12;
  int m = out & 4095;
  int t = m & 2047;
  float s = 0.f;
  if (t > 0) {
    const __bf16* r1 = (const __bf16*)k + (size_t)m * 1024 + h * 64 + j * 16;
    const __bf16* r0 = r1 - 1024;
    bf16x8 a0 = *(const bf16x8*)r0;
    bf16x8 a1 = *(const bf16x8*)(r0 + 8);
    bf16x8 b0 = *(const bf16x8*)r1;
    bf16x8 b1 = *(const bf16x8*)(r1 + 8);
#pragma unroll
    for (int e = 0; e < 8; ++e)
      s += (float)a0[e] * (float)b0[e] + (float)a1[e] * (float)b1[e];
  }
  s += __shfl_xor(s, 1);
  s += __shfl_xor(s, 2);
  if (j == 0) G[out] = betab[out] * s;
}

// One scan step (constant word indices only).
#define SCAN_STEP(i, KN0, KN1, Q0, Q1, WV, WA, BT, GT, LAST)                  \
  {                                                                           \
    const float vr = ((i) & 1) ? bcf((WV) & 0xffff0000u) : bcf((WV) << 16);   \
    const float ar = ((i) & 1) ? bcf((WA) & 0xffff0000u) : bcf((WA) << 16);   \
    float unxt = 0.f;                                                         \
    f32x2 k2n0 = {0.f, 0.f}, k2n1 = {0.f, 0.f};                               \
    if (!(LAST)) {                                                            \
      k2n0 = unpk(KN0); k2n1 = unpk(KN1);                                     \
      f32x2 dd = S20 * k2n0; dd += S21 * k2n1;                                \
      unxt = dd[0] + dd[1];                                                   \
      unxt += dpp_f<0xB1>(unxt);  unxt += dpp_f<0x4E>(unxt);                  \
      unxt += dpp_f<0x141>(unxt); unxt += dpp_f<0x140>(unxt);                 \
    } else { Sold0 = S20; Sold1 = S21; }                                      \
    float A_ = (BT) * __builtin_fmaf(aprev, u, -vr);                          \
    cc = __builtin_fmaf(-cc, (GT), A_);                                       \
    f32x2 q20 = unpk(Q0), q21 = unpk(Q1);                                     \
    const f32x2 cc2 = {cc, cc}, arv = {ar, ar};                               \
    f32x2 oo;                                                                 \
    { f32x2 t0 = cc2 * k2c0; S20 = arv * S20 - t0; oo = S20 * q20;            \
      f32x2 t1 = cc2 * k2c1; S21 = arv * S21 - t1; oo += S21 * q21; }         \
    so[(i)][lane] = oo[0] + oo[1];                                            \
    aprev = ar;                                                               \
    if (!(LAST)) { k2c0 = k2n0; k2c1 = k2n1; u = unxt; }                      \
  }

// Load one 2-step group (g = 0..7) into a named set (14 regs).
#define LOADG(KS, QS, VS, AS, BS, GS, g)                                      \
  KS = *(const u32x4*)&skT[buf][sg][(g) * 8];                                 \
  QS = *(const u32x4*)&sqT[buf][sg][(g) * 8];                                 \
  VS = *(const unsigned int*)&svaT[buf][0][r4][(g) * 2];                      \
  AS = *(const unsigned int*)&svaT[buf][1][r4][(g) * 2];                      \
  BS = *(const f32x2*)&sbeta[c * 16 + (g) * 2];                               \
  GS = *(const f32x2*)&sG[c * 16 + (g) * 2];

// FUSED kernel: blocks 0..511 = delta-rule scan (single wave; threads>=64
// exit; NO barriers; s_setprio(1)). Blocks 512..767 = g-GEMM.
__global__ __launch_bounds__(256) void scan_gemm_kernel(
    const bf16* __restrict__ q, const bf16* __restrict__ k,
    const bf16* __restrict__ v, const bf16* __restrict__ a,
    const float* __restrict__ betab, const float* __restrict__ gkk,
    bf16* __restrict__ o,
    const float* __restrict__ x, const bf16* __restrict__ Wgb,
    bf16* __restrict__ gout)
{
  __shared__ __align__(16) __bf16 skT[2][16][72];
  __shared__ __align__(16) __bf16 sqT[2][16][72];
  __shared__ __align__(16) __bf16 svaT[2][2][4][16];
  __shared__ __align__(16) float  so[16][68];
  __shared__ __align__(16) __bf16 so2[16][4];
  __shared__ float sbeta[2048];
  __shared__ float sG[2048];
  __shared__ __align__(16) __bf16 As[128 * 32];
  __shared__ __align__(16) __bf16 Bs[128 * 32];

  if (blockIdx.x >= 512) {
    const int gb   = blockIdx.x - 512;
    const int tid  = threadIdx.x;
    const int lane = tid & 63;
    const int wave = tid >> 6;
    const int tile_m = (gb >> 3) * 128;
    const int tile_n = (gb & 7) * 128;
    const int wm = (wave >> 1) * 64;
    const int wn = (wave & 1) * 64;
    const int srow = lane >> 2;
    const int scol = (lane & 3) * 8;

    f32x4 acc[4][4];
#pragma unroll
    for (int i = 0; i < 4; ++i)
#pragma unroll
      for (int j = 0; j < 4; ++j) acc[i][j] = {0.f, 0.f, 0.f, 0.f};

    for (int k0 = 0; k0 < 1024; k0 += 32) {
      float4 a0[2], a1[2];
#pragma unroll
      for (int s = 0; s < 2; ++s) {
        int arow = tile_m + s * 64 + wave * 16 + srow;
        const float* ap = x + (size_t)arow * 1024 + k0 + scol;
        a0[s] = *(const float4*)ap;
        a1[s] = *(const float4*)(ap + 4);
      }
      __syncthreads();
#pragma unroll
      for (int s = 0; s < 2; ++s) {
        bf16x8 ua;
        ua[0] = cvt_bf16(a0[s].x); ua[1] = cvt_bf16(a0[s].y);
        ua[2] = cvt_bf16(a0[s].z); ua[3] = cvt_bf16(a0[s].w);
        ua[4] = cvt_bf16(a1[s].x); ua[5] = cvt_bf16(a1[s].y);
        ua[6] = cvt_bf16(a1[s].z); ua[7] = cvt_bf16(a1[s].w);
        *(bf16x8*)&As[(s * 64 + wave * 16 + srow) * 32 + scol] = ua;
        int brow = tile_n + s * 64 + wave * 16 + srow;
        async_copy16((const __bf16*)Wgb + (size_t)brow * 1024 + k0 + scol,
                     &Bs[(s * 64 + wave * 16 + srow) * 32 + scol]);
      }
      __syncthreads();

      bf16x8 af[4], bfr[4];
#pragma unroll
      for (int i = 0; i < 4; ++i)
        af[i] = *(const bf16x8*)&As[(wm + i * 16 + (lane & 15)) * 32 + (lane >> 4) * 8];
#pragma unroll
      for (int j = 0; j < 4; ++j)
        bfr[j] = *(const bf16x8*)&Bs[(wn + j * 16 + (lane & 15)) * 32 + (lane >> 4) * 8];

#pragma unroll
      for (int i = 0; i < 4; ++i)
#pragma unroll
        for (int j = 0; j < 4; ++j)
          acc[i][j] = __builtin_amdgcn_mfma_f32_16x16x32_bf16(af[i], bfr[j], acc[i][j], 0, 0, 0);
    }

#pragma unroll
    for (int i = 0; i < 4; ++i)
#pragma unroll
      for (int j = 0; j < 4; ++j)
#pragma unroll
        for (int r = 0; r < 4; ++r) {
          int gm = tile_m + wm + i * 16 + (lane >> 4) * 4 + r;
          int gn = tile_n + wn + j * 16 + (lane & 15);
          float val = 1.f / (1.f + __expf(-acc[i][j][r]));
          gout[(size_t)gm * 1024 + gn] = (bf16)val;
        }
    return;
  }

  // ---------------- scan path (single wave; extra waves exit) ----------------
  if (threadIdx.x >= 64) return;
  __builtin_amdgcn_s_setprio(1);

  const int blk = blockIdx.x;
  const int qd = blk >> 5;
  const int bh = blk & 31;
  const int b = bh >> 4, h = bh & 15;
  const int lane = threadIdx.x;
  const int r4 = lane >> 4;
  const int sg = lane & 15;

  {
    const float* bp = betab + (size_t)h * 4096 + b * 2048;
    const float* gp = gkk   + (size_t)h * 4096 + b * 2048;
    for (int t4 = lane * 4; t4 < 2048; t4 += 256) {
      *(float4*)&sbeta[t4] = *(const float4*)(bp + t4);
      *(float4*)&sG[t4]    = *(const float4*)(gp + t4);
    }
  }

  const size_t bkq = (size_t)b * 2048 * 1024 + h * 64;
  const size_t bva = bkq + qd * 4;
  const __bf16* kp = (const __bf16*)k;
  const __bf16* qp = (const __bf16*)q;

  const int g_st = lane >> 3;
  const int g_cg = (lane & 7) * 8;
  const int sgp  = (lane & 7) * 2;
  const int va_vh = (lane >> 4) & 1;
  const int va_st = lane & 15;

  bf16x8 pk0, pk1, pq0, pq1;
  bf16x4v pva;
  auto fetch = [&](int t0) {
    int st0 = t0 + g_st, st1 = t0 + 8 + g_st;
    pk0 = *(const bf16x8*)(kp + bkq + (size_t)st0 * 1024 + g_cg);
    pk1 = *(const bf16x8*)(kp + bkq + (size_t)st1 * 1024 + g_cg);
    pq0 = *(const bf16x8*)(qp + bkq + (size_t)st0 * 1024 + g_cg);
    pq1 = *(const bf16x8*)(qp + bkq + (size_t)st1 * 1024 + g_cg);
    if (lane < 32) {
      const __bf16* src = va_vh ? (const __bf16*)a : (const __bf16*)v;
      pva = *(const bf16x4v*)(src + bva + (size_t)(t0 + va_st) * 1024);
    }
  };
  auto commit = [&](int cb) {
    {
      u32x4 wk = __builtin_bit_cast(u32x4, pk0);
      u32x4 wq = __builtin_bit_cast(u32x4, pq0);
      u32x2 lo, hi;
      lo[0] = wk[0]; lo[1] = wk[1]; hi[0] = wk[2]; hi[1] = wk[3];
      *(u32x2*)&skT[cb][sgp][g_st * 4]     = lo;
      *(u32x2*)&skT[cb][sgp + 1][g_st * 4] = hi;
      lo[0] = wq[0]; lo[1] = wq[1]; hi[0] = wq[2]; hi[1] = wq[3];
      *(u32x2*)&sqT[cb][sgp][g_st * 4]     = lo;
      *(u32x2*)&sqT[cb][sgp + 1][g_st * 4] = hi;
    }
    {
      u32x4 wk = __builtin_bit_cast(u32x4, pk1);
      u32x4 wq = __builtin_bit_cast(u32x4, pq1);
      u32x2 lo, hi;
      lo[0] = wk[0]; lo[1] = wk[1]; hi[0] = wk[2]; hi[1] = wk[3];
      *(u32x2*)&skT[cb][sgp][(8 + g_st) * 4]     = lo;
      *(u32x2*)&skT[cb][sgp + 1][(8 + g_st) * 4] = hi;
      lo[0] = wq[0]; lo[1] = wq[1]; hi[0] = wq[2]; hi[1] = wq[3];
      *(u32x2*)&sqT[cb][sgp][(8 + g_st) * 4]     = lo;
      *(u32x2*)&sqT[cb][sgp + 1][(8 + g_st) * 4] = hi;
    }
    if (lane < 32) {
#pragma unroll
      for (int r = 0; r < 4; ++r) svaT[cb][va_vh][r][va_st] = pva[r];
    }
  };

  fetch(0); commit(0);

  f32x2 S20 = {0.f, 0.f}, S21 = {0.f, 0.f};
  f32x2 Sold0 = {0.f, 0.f}, Sold1 = {0.f, 0.f};
  float u = 0.f, cc = 0.f, aprev = 0.f;

  auto unpk = [&](unsigned int w) -> f32x2 {
    f32x2 r; r[0] = bcf(w << 16); r[1] = bcf(w & 0xffff0000u); return r;
  };

  for (int c = 0; c < 128; ++c) {
    const int buf = c & 1;
    const bool hasNext = (c + 1 < 128);

    if (hasNext) fetch((c + 1) * 16);

    u32x4 kA, qA, kB, qB, kC, qC;
    unsigned int vA, aA, vB, aB, vC, aC;
    f32x2 bA, gA, bB, gB, bC, gC;

    LOADG(kA, qA, vA, aA, bA, gA, 0)
    LOADG(kB, qB, vB, aB, bB, gB, 1)
    LOADG(kC, qC, vC, aC, bC, gC, 2)

    f32x2 k2c0 = unpk(kA[0]);
    f32x2 k2c1 = unpk(kA[1]);
    {
      f32x2 dd = Sold0 * k2c0;
      dd += Sold1 * k2c1;
      float un = dd[0] + dd[1];
      un += dpp_f<0xB1>(un);
      un += dpp_f<0x4E>(un);
      un += dpp_f<0x141>(un);
      un += dpp_f<0x140>(un);
      u = un;
    }

    SCAN_STEP(0,  kA[2], kA[3], qA[0], qA[1], vA, aA, bA[0], gA[0], false)
    SCAN_STEP(1,  kB[0], kB[1], qA[2], qA[3], vA, aA, bA[1], gA[1], false)
    LOADG(kA, qA, vA, aA, bA, gA, 3)
    SCAN_STEP(2,  kB[2], kB[3], qB[0], qB[1], vB, aB, bB[0], gB[0], false)
    SCAN_STEP(3,  kC[0], kC[1], qB[2], qB[3], vB, aB, bB[1], gB[1], false)
    LOADG(kB, qB, vB, aB, bB, gB, 4)
    SCAN_STEP(4,  kC[2], kC[3], qC[0], qC[1], vC, aC, bC[0], gC[0], false)
    SCAN_STEP(5,  kA[0], kA[1], qC[2], qC[3], vC, aC, bC[1], gC[1], false)
    LOADG(kC, qC, vC, aC, bC, gC, 5)
    SCAN_STEP(6,  kA[2], kA[3], qA[0], qA[1], vA, aA, bA[0], gA[0], false)
    SCAN_STEP(7,  kB[0], kB[1], qA[2], qA[3], vA, aA, bA[1], gA[1], false)
    LOADG(kA, qA, vA, aA, bA, gA, 6)
    SCAN_STEP(8,  kB[2], kB[3], qB[0], qB[1], vB, aB, bB[0], gB[0], false)
    SCAN_STEP(9,  kC[0], kC[1], qB[2], qB[3], vB, aB, bB[1], gB[1], false)
    LOADG(kB, qB, vB, aB, bB, gB, 7)
    SCAN_STEP(10, kC[2], kC[3], qC[0], qC[1], vC, aC, bC[0], gC[0], false)
    SCAN_STEP(11, kA[0], kA[1], qC[2], qC[3], vC, aC, bC[1], gC[1], false)
    SCAN_STEP(12, kA[2], kA[3], qA[0], qA[1], vA, aA, bA[0], gA[0], false)
    SCAN_STEP(13, kB[0], kB[1], qA[2], qA[3], vA, aA, bA[1], gA[1], false)
    SCAN_STEP(14, kB[2], kB[3], qB[0], qB[1], vB, aB, bB[0], gB[0], false)
    SCAN_STEP(15, kB[2], kB[3], qB[2], qB[3], vB, aB, bB[1], gB[1], true)

    {
      int st = lane >> 2, rr = lane & 3;
      float4 A0 = *(const float4*)&so[st][rr * 16];
      float4 A1 = *(const float4*)&so[st][rr * 16 + 4];
      float4 A2 = *(const float4*)&so[st][rr * 16 + 8];
      float4 A3 = *(const float4*)&so[st][rr * 16 + 12];
      float s = (((A0.x + A0.y) + (A0.z + A0.w)) + ((A1.x + A1.y) + (A1.z + A1.w)))
              + (((A2.x + A2.y) + (A2.z + A2.w)) + ((A3.x + A3.y) + (A3.z + A3.w)));
      so2[st][rr] = cvt_bf16(s);
    }
    if (lane < 16)
      *(bf16x4v*)((__bf16*)o + bva + (size_t)(c * 16 + lane) * 1024) =
          *(const bf16x4v*)&so2[lane][0];

    if (hasNext) commit(buf ^ 1);
  }
}

// LayerNorm over DV=64 per (b,t,h) row, *ln_w+ln_b, *gate -> bf16 (fallback)
__global__ __launch_bounds__(256) void ln_gate_kernel(
    const bf16* __restrict__ o, const bf16* __restrict__ g,
    const float* __restrict__ lnw, const float* __restrict__ lnb,
    bf16* __restrict__ out)
{
  int row = blockIdx.x * 4 + (threadIdx.x >> 6);
  int lane = threadIdx.x & 63;
  size_t idx = (size_t)row * 64 + lane;
  float xv = (float)o[idx];
  float mu = xv;
#pragma unroll
  for (int s = 1; s < 64; s <<= 1) mu += __shfl_xor(mu, s);
  mu *= (1.f / 64.f);
  float d = xv - mu;
  float vv = d * d;
#pragma unroll
  for (int s = 1; s < 64; s <<= 1) vv += __shfl_xor(vv, s);
  vv *= (1.f / 64.f);
  float y = d * rsqrtf(vv + 1e-5f) * lnw[lane] + lnb[lane];
  y *= (float)g[idx];
  out[idx] = (bf16)y;
}

extern "C" void kernel_launch(void* const* d_in, const int* in_sizes, int n_in,
                              void* d_out, int out_size, void* d_ws, size_t ws_size,
                              hipStream_t stream)
{
  const float* x   = (const float*)d_in[0];
  const float* Wq  = (const float*)d_in[1];
  const float* Wk  = (const float*)d_in[2];
  const float* Wv  = (const float*)d_in[3];
  const float* Wa  = (const float*)d_in[4];
  const float* ba  = (const float*)d_in[5];
  const float* Wb  = (const float*)d_in[6];
  const float* bb  = (const float*)d_in[7];
  const float* Wg  = (const float*)d_in[8];
  const float* Wo  = (const float*)d_in[9];
  const float* qcw = (const float*)d_in[10];
  const float* qcb = (const float*)d_in[11];
  const float* kcw = (const float*)d_in[12];
  const float* kcb = (const float*)d_in[13];
  const float* vcw = (const float*)d_in[14];
  const float* vcb = (const float*)d_in[15];
  const float* lnw = (const float*)d_in[16];
  const float* lnb = (const float*)d_in[17];

  const int M = 4096, HID = 1024;
  const size_t PLANE = (size_t)M * HID;
  const size_t PB = PLANE * sizeof(bf16);          // 8 MB bf16 plane

  char* ws = (char*)d_ws;
  float* outf = (float*)d_out;
  const bool rich = (ws_size >= 5 * PB + 1024);

  dim3 blk(256);
  dim3 g8(8, 32);
  int nconv = (int)((size_t)M * 128 / 256);

  if (rich) {
    bf16* P0 = (bf16*)(ws);
    bf16* P1 = (bf16*)(ws + PB);
    bf16* P2 = (bf16*)(ws + 2 * PB);
    bf16* P3 = (bf16*)(ws + 3 * PB);
    bf16* P4 = (bf16*)(ws + 4 * PB);
    bf16*  xb    = (bf16*)d_out;                            // [0,8M)
    bf16*  W4b   = (bf16*)((char*)d_out + 8 * 1024 * 1024); // [8M,16M)
    bf16*  Kb    = xb;                                      // k-plane
    bf16*  Qb    = W4b;                                     // q-plane
    float* betab = (float*)P4;
    float* gkk   = (float*)((char*)P4 + 256 * 1024);
    bf16*  Wgb   = (bf16*)((char*)P4 + 1024 * 1024);
    bf16*  Wob   = (bf16*)((char*)P4 + 3 * 1024 * 1024);

    // 1. convert x + 6 weight matrices to bf16
    cvtw_kernel<<<10240, blk, 0, stream>>>(x, Wq, Wk, Wv, Wa, Wg, Wo,
                                           xb, W4b, Wgb, Wob);
    // 2. fused 4-projection + beta GEMM (1-D grid, XCD swizzle)
    mega_gemm2<<<1056, blk, 0, stream>>>(xb, W4b, Wb, bb, ba, P0, betab);
    // 3. conv q (P0->Qb) + conv k (P1->Kb) -- disjoint planes
    conv2_kernel<<<4096, blk, 0, stream>>>(P0, P1, qcw, qcb, kcw, kcb, Qb, Kb);
    // 4. conv v (P2->P1) + kk (reads Kb from launch 3)
    convv_kk_kernel<<<3072, blk, 0, stream>>>(P2, vcw, vcb, P1, Kb, betab, gkk);
    // 5. FUSED scan (o->P0) + g-GEMM (sigmoid(x@Wgb^T)->P2)
    scan_gemm_kernel<<<768, blk, 0, stream>>>(Qb, Kb, P1, P3, betab, gkk, P0,
                                              x, Wgb, P2);
    // 6. final GEMM with fused LN+gate (512 blocks = 2/CU, XCD swizzle)
    gemm_bb_ln<<<512, blk, 0, stream>>>(P0, P2, lnw, lnb, Wob, outf);
  } else {
    bf16* P  = (bf16*)(ws);
    bf16* qb = (bf16*)(ws + PB);
    bf16* kb = (bf16*)(ws + 2 * PB);
    bf16* vb = (bf16*)(ws + 3 * PB);
    float* betab = (float*)d_out;
    float* gkk   = (float*)((char*)d_out + 256 * 1024);
    bf16*  ob    = (bf16*)((char*)d_out + 8 * 1024 * 1024);

    gemm_bt<2, true><<<g8, blk, 0, stream>>>(x, Wq, nullptr, nullptr, P, M, HID, HID);
    conv_silu_kernel<<<nconv, blk, 0, stream>>>(P, qcw, qcb, qb, 1.f);
    gemm_bt<2, true><<<g8, blk, 0, stream>>>(x, Wk, nullptr, nullptr, P, M, HID, HID);
    conv_silu_kernel<<<nconv, blk, 0, stream>>>(P, kcw, kcb, kb, 0.125f);
    gemm_bt<2, true><<<g8, blk, 0, stream>>>(x, Wv, nullptr, nullptr, P, M, HID, HID);
    conv_silu_kernel<<<nconv, blk, 0, stream>>>(P, vcw, vcb, vb, 1.f);
    gemm_bt<3, true><<<g8, blk, 0, stream>>>(x, Wa, ba, nullptr, P, M, HID, HID);
    gemm_bt<5, true><<<dim3(1, 32), blk, 0, stream>>>(x, Wb, bb, betab, nullptr, M, 16, HID);
    kk_kernel<<<1024, blk, 0, stream>>>(kb, betab, gkk);
    scan_gemm_kernel<<<512, blk, 0, stream>>>(qb, kb, vb, P, betab, gkk, ob,
                                              x, nullptr, nullptr);
    gemm_bt<3, true><<<g8, blk, 0, stream>>>(x, Wg, nullptr, nullptr, qb, M, HID, HID);
    ln_gate_kernel<<<M * 16 / 4, blk, 0, stream>>>(ob, qb, lnw, lnb, kb);
    gemm_bt<4, false><<<g8, blk, 0, stream>>>(kb, Wo, nullptr, outf, nullptr, M, HID, HID);
  }
}

// Round 15
// 427.866 us; speedup vs baseline: 1.6324x; 1.0184x over previous
//
#include <hip/hip_runtime.h>
#include <hip/hip_bf16.h>
#include <cstdint>

// B=2, T=2048, HID=1024, H=16, DK=DV=64, K(conv)=4. fp32 in/out.
// RICH memory plan (ws >= 40MB): ws = P0..P4 (8MB bf16 planes).
//  d_out[0,8M): xb -> Kb (k-plane);  d_out[8M,16M): W4b -> Qb (q-plane)
//  P4: [0,256K) betab fp32; [256K,512K) gkk; [1M,3M) Wgb; [3M,5M) Wob
//  P0: zq -> scan o;  P1: zk -> v-plane;  P2: zv -> g-plane;  P3: a plane
// Launches (6): cvtw -> mega_gemm2(+beta) -> conv2(q,k) -> convv_kk
//   -> FUSED scan+g-GEMM -> gemm_bb_ln (final GEMM with LN+gate fused).
//
// R15: (a) mega_gemm2 XCD partition 8m x 16n per XCD (footprint 9MB->6MB;
// weight panels stay L2-resident across their 8 M-tile reuses);
// (b) gemm_bb_ln stages the full 64-k B-slab per head (Bs2[2][128][32],
// 2 barriers/head instead of 4). Scan core + rest: proven, untouched.

using bf16 = __hip_bfloat16;
typedef __bf16 bf16x8 __attribute__((ext_vector_type(8)));
typedef __bf16 bf16x4v __attribute__((ext_vector_type(4)));
typedef float f32x4 __attribute__((ext_vector_type(4)));
typedef float f32x2 __attribute__((ext_vector_type(2)));
typedef unsigned int u32x4 __attribute__((ext_vector_type(4)));
typedef unsigned int u32x2 __attribute__((ext_vector_type(2)));

__device__ __forceinline__ __bf16 cvt_bf16(float f) {
  __hip_bfloat16 h = (__hip_bfloat16)f;
  return *reinterpret_cast<__bf16*>(&h);
}
__device__ __forceinline__ void async_copy16(const void* g, void* l) {
  __builtin_amdgcn_global_load_lds((const __attribute__((address_space(1))) void*)g,
                                   (__attribute__((address_space(3))) void*)l,
                                   16, 0, 0);
}
__device__ __forceinline__ float bcf(unsigned int u) { return __builtin_bit_cast(float, u); }
template <int CTRL>
__device__ __forceinline__ float dpp_f(float x) {
  int y = __builtin_amdgcn_update_dpp(0, __builtin_bit_cast(int, x), CTRL, 0xF, 0xF, true);
  return __builtin_bit_cast(float, y);
}

// fp32 -> bf16: x (blocks 0..4095), W4 (4096..8191), Wg (8192..9215),
// Wo (9216..10239).
__global__ __launch_bounds__(256) void cvtw_kernel(
    const float* __restrict__ x, const float* __restrict__ Wq,
    const float* __restrict__ Wk, const float* __restrict__ Wv,
    const float* __restrict__ Wa, const float* __restrict__ Wg,
    const float* __restrict__ Wo, bf16* __restrict__ xb,
    bf16* __restrict__ w4b, bf16* __restrict__ wgb, bf16* __restrict__ wob)
{
  int blk = blockIdx.x;
  const float* src;
  __bf16* dst;
  size_t off;
  if (blk < 4096) {
    src = x; dst = (__bf16*)xb;
    off = (size_t)blk * 1024 + threadIdx.x * 4;
  } else if (blk < 8192) {
    int wb = blk - 4096;
    int wi = wb >> 10;
    src = (wi == 0) ? Wq : (wi == 1) ? Wk : (wi == 2) ? Wv : Wa;
    dst = (__bf16*)w4b + (size_t)wi * 1024 * 1024;
    off = (size_t)(wb & 1023) * 1024 + threadIdx.x * 4;
  } else if (blk < 9216) {
    src = Wg; dst = (__bf16*)wgb;
    off = (size_t)(blk - 8192) * 1024 + threadIdx.x * 4;
  } else {
    src = Wo; dst = (__bf16*)wob;
    off = (size_t)(blk - 9216) * 1024 + threadIdx.x * 4;
  }
  float4 f = *(const float4*)(src + off);
  bf16x4v t;
  t[0] = cvt_bf16(f.x); t[1] = cvt_bf16(f.y); t[2] = cvt_bf16(f.z); t[3] = cvt_bf16(f.w);
  *(bf16x4v*)(dst + off) = t;
}

// C = A * Bt^T. A: MxK (bf16 async-staged unless A_FP32); Bt: NxK fp32.
// MODE 2: raw->bf16; 3: sigmoid(acc+bias)->bf16; 4: raw->fp32; 5: sigmoid(acc+bias)->fp32 TRANSPOSED
template <int MODE, bool A_FP32>
__global__ __launch_bounds__(256) void gemm_bt(
    const void* __restrict__ Av, const float* __restrict__ Bt,
    const float* __restrict__ bias, float* __restrict__ Cf, bf16* __restrict__ Cb,
    int M, int N, int K)
{
  __shared__ __align__(16) __bf16 As[128 * 32];
  __shared__ __align__(16) __bf16 Bs[128 * 32];

  const int tid  = threadIdx.x;
  const int lane = tid & 63;
  const int wave = tid >> 6;
  const int tile_m = blockIdx.y * 128;
  const int tile_n = blockIdx.x * 128;
  const int wm = (wave >> 1) * 64;
  const int wn = (wave & 1) * 64;

  const int srow = lane >> 2;
  const int scol = (lane & 3) * 8;

  f32x4 acc[4][4];
#pragma unroll
  for (int i = 0; i < 4; ++i)
#pragma unroll
    for (int j = 0; j < 4; ++j) acc[i][j] = {0.f, 0.f, 0.f, 0.f};

  for (int k0 = 0; k0 < K; k0 += 32) {
    float4 b0[2], b1[2], a0[2], a1[2];
#pragma unroll
    for (int s = 0; s < 2; ++s) {
      int brow = tile_n + s * 64 + wave * 16 + srow;
      if (brow > N - 1) brow = N - 1;
      const float* bp = Bt + (size_t)brow * K + k0 + scol;
      b0[s] = *(const float4*)bp;
      b1[s] = *(const float4*)(bp + 4);
      if (A_FP32) {
        int arow = tile_m + s * 64 + wave * 16 + srow;
        const float* ap = (const float*)Av + (size_t)arow * K + k0 + scol;
        a0[s] = *(const float4*)ap;
        a1[s] = *(const float4*)(ap + 4);
      }
    }
    __syncthreads();
#pragma unroll
    for (int s = 0; s < 2; ++s) {
      if (!A_FP32) {
        int arow = tile_m + s * 64 + wave * 16 + srow;
        async_copy16((const __bf16*)Av + (size_t)arow * K + k0 + scol,
                     &As[(s * 64 + wave * 16 + srow) * 32 + scol]);
      } else {
        bf16x8 ua;
        ua[0] = cvt_bf16(a0[s].x); ua[1] = cvt_bf16(a0[s].y);
        ua[2] = cvt_bf16(a0[s].z); ua[3] = cvt_bf16(a0[s].w);
        ua[4] = cvt_bf16(a1[s].x); ua[5] = cvt_bf16(a1[s].y);
        ua[6] = cvt_bf16(a1[s].z); ua[7] = cvt_bf16(a1[s].w);
        *(bf16x8*)&As[(s * 64 + wave * 16 + srow) * 32 + scol] = ua;
      }
      bf16x8 u;
      u[0] = cvt_bf16(b0[s].x); u[1] = cvt_bf16(b0[s].y);
      u[2] = cvt_bf16(b0[s].z); u[3] = cvt_bf16(b0[s].w);
      u[4] = cvt_bf16(b1[s].x); u[5] = cvt_bf16(b1[s].y);
      u[6] = cvt_bf16(b1[s].z); u[7] = cvt_bf16(b1[s].w);
      *(bf16x8*)&Bs[(s * 64 + wave * 16 + srow) * 32 + scol] = u;
    }
    __syncthreads();

    bf16x8 af[4], bfr[4];
#pragma unroll
    for (int i = 0; i < 4; ++i)
      af[i] = *(const bf16x8*)&As[(wm + i * 16 + (lane & 15)) * 32 + (lane >> 4) * 8];
#pragma unroll
    for (int j = 0; j < 4; ++j)
      bfr[j] = *(const bf16x8*)&Bs[(wn + j * 16 + (lane & 15)) * 32 + (lane >> 4) * 8];

#pragma unroll
    for (int i = 0; i < 4; ++i)
#pragma unroll
      for (int j = 0; j < 4; ++j)
        acc[i][j] = __builtin_amdgcn_mfma_f32_16x16x32_bf16(af[i], bfr[j], acc[i][j], 0, 0, 0);
  }

#pragma unroll
  for (int i = 0; i < 4; ++i) {
#pragma unroll
    for (int j = 0; j < 4; ++j) {
#pragma unroll
      for (int r = 0; r < 4; ++r) {
        int gm = tile_m + wm + i * 16 + (lane >> 4) * 4 + r;
        int gn = tile_n + wn + j * 16 + (lane & 15);
        if (gn < N) {
          float val = acc[i][j][r];
          if (MODE == 3 || MODE == 5) {
            float bv = bias ? bias[gn] : 0.f;
            val = 1.f / (1.f + __expf(-(val + bv)));
          }
          if (MODE == 4)      Cf[(size_t)gm * N + gn] = val;
          else if (MODE == 5) Cf[(size_t)gn * M + gm] = val;
          else                Cb[(size_t)gm * N + gn] = (bf16)val;
        }
      }
    }
  }
}

// Final GEMM with fused LN+gate on the A operand. 64-row tiles -> 512
// blocks = 2 blocks/CU. Per head: stage FULL 64-k B-slab (Bs2[2][128][32])
// -> 2 barriers/head (was 4). Head loop software-pipelined (next head's
// o/g loads in flight across MFMA). XCD-bijective swizzle.
__global__ __launch_bounds__(256) void gemm_bb_ln(
    const bf16* __restrict__ o, const bf16* __restrict__ g,
    const float* __restrict__ lnw, const float* __restrict__ lnb,
    const bf16* __restrict__ Bw, float* __restrict__ C)
{
  __shared__ __align__(16) __bf16 As2[64][72];        // 9 KB (72-pad)
  __shared__ __align__(16) __bf16 Bs2[2][128][32];    // 16 KB (sub-major)
  __shared__ float sW[64], sB[64];

  const int bx = blockIdx.x;                       // 512 blocks
  const int logical = (bx & 7) * 64 + (bx >> 3);   // bijective XCD swizzle
  const int tile_m = (logical >> 3) * 64;
  const int tile_n = (logical & 7) * 128;

  const int tid  = threadIdx.x;
  const int lane = tid & 63;
  const int wave = tid >> 6;
  const int wm = (wave >> 1) * 32;     // row quadrant 0/32
  const int wn = (wave & 1) * 64;      // col half 0/64
  const int srow = lane >> 2;
  const int scol = (lane & 3) * 8;
  const int rl  = tid >> 2;            // local A row 0..63
  const int qtr = tid & 3;             // column quarter (16 cols each)

  if (tid < 64) { sW[tid] = lnw[tid]; sB[tid] = lnb[tid]; }

  const __bf16* obase = (const __bf16*)o + (size_t)(tile_m + rl) * 1024 + qtr * 16;
  const __bf16* gbase = (const __bf16*)g + (size_t)(tile_m + rl) * 1024 + qtr * 16;

  f32x4 acc[2][4];
#pragma unroll
  for (int i = 0; i < 2; ++i)
#pragma unroll
    for (int j = 0; j < 4; ++j) acc[i][j] = {0.f, 0.f, 0.f, 0.f};

  // preload head 0 (16 cols per thread)
  bf16x8 ov0, ov1, gv0, gv1;
  ov0 = *(const bf16x8*)(obase);
  ov1 = *(const bf16x8*)(obase + 8);
  gv0 = *(const bf16x8*)(gbase);
  gv1 = *(const bf16x8*)(gbase + 8);

  for (int h = 0; h < 16; ++h) {
    // issue NEXT head's o/g loads first (in flight across barriers + MFMA)
    bf16x8 no0, no1, ng0, ng1;
    if (h + 1 < 16) {
      const __bf16* op = obase + (h + 1) * 64;
      const __bf16* gp = gbase + (h + 1) * 64;
      no0 = *(const bf16x8*)(op);
      no1 = *(const bf16x8*)(op + 8);
      ng0 = *(const bf16x8*)(gp);
      ng1 = *(const bf16x8*)(gp + 8);
    }

    __syncthreads();   // prior head's MFMA reads of As2/Bs2 complete

    // issue full 64-k B-slab stage for head h (both subs)
#pragma unroll
    for (int sub = 0; sub < 2; ++sub)
#pragma unroll
      for (int s = 0; s < 2; ++s) {
        int brow = tile_n + s * 64 + wave * 16 + srow;
        async_copy16((const __bf16*)Bw + (size_t)brow * 1024 + h * 64 + sub * 32 + scol,
                     &Bs2[sub][s * 64 + wave * 16 + srow][scol]);
      }

    // ---- LN + gate for head h -> As2 (row rl; 4 threads per row) ----
    float sum = 0.f;
#pragma unroll
    for (int e = 0; e < 8; ++e)
      sum += (float)ov0[e] + (float)ov1[e];
    sum += __shfl_xor(sum, 1);
    sum += __shfl_xor(sum, 2);
    float mu = sum * (1.f / 64.f);
    float vv = 0.f;
#pragma unroll
    for (int e = 0; e < 8; ++e) {
      float d0 = (float)ov0[e] - mu, d1 = (float)ov1[e] - mu;
      vv += d0 * d0 + d1 * d1;
    }
    vv += __shfl_xor(vv, 1);
    vv += __shfl_xor(vv, 2);
    float rstd = rsqrtf(vv * (1.f / 64.f) + 1e-5f);

    bf16x8 res0, res1;
#pragma unroll
    for (int e = 0; e < 8; ++e) {
      int c0 = qtr * 16 + e;
      res0[e] = cvt_bf16((((float)ov0[e] - mu) * rstd * sW[c0] + sB[c0]) * (float)gv0[e]);
      res1[e] = cvt_bf16((((float)ov1[e] - mu) * rstd * sW[c0 + 8] + sB[c0 + 8]) * (float)gv1[e]);
    }
    *(bf16x8*)&As2[rl][qtr * 16 + 0] = res0;
    *(bf16x8*)&As2[rl][qtr * 16 + 8] = res1;

    __syncthreads();               // Bs2 landed + As2 visible

#pragma unroll
    for (int sub = 0; sub < 2; ++sub) {
      bf16x8 af[2], bfr[4];
#pragma unroll
      for (int i = 0; i < 2; ++i)
        af[i] = *(const bf16x8*)&As2[wm + i * 16 + (lane & 15)][(lane >> 4) * 8 + sub * 32];
#pragma unroll
      for (int j = 0; j < 4; ++j)
        bfr[j] = *(const bf16x8*)&Bs2[sub][wn + j * 16 + (lane & 15)][(lane >> 4) * 8];

#pragma unroll
      for (int i = 0; i < 2; ++i)
#pragma unroll
        for (int j = 0; j < 4; ++j)
          acc[i][j] = __builtin_amdgcn_mfma_f32_16x16x32_bf16(af[i], bfr[j], acc[i][j], 0, 0, 0);
    }

    if (h + 1 < 16) {
      ov0 = no0; ov1 = no1;
      gv0 = ng0; gv1 = ng1;
    }
  }

#pragma unroll
  for (int i = 0; i < 2; ++i)
#pragma unroll
    for (int j = 0; j < 4; ++j)
#pragma unroll
      for (int r = 0; r < 4; ++r) {
        int gm = tile_m + wm + i * 16 + (lane >> 4) * 4 + r;
        int gn = tile_n + wn + j * 16 + (lane & 15);
        C[(size_t)gm * 1024 + gn] = acc[i][j][r];
      }
}

// Fused 4-projection + beta GEMM. 1-D grid 1056 blocks:
//  bx < 1024: GEMM tiles; XCD partition = 8m x 16n per XCD
//  (footprint 2MB A + 4MB W = 6MB, weight panels L2-resident across
//  their 8 M-tile reuses). bx >= 1024: beta tiles.
__global__ __launch_bounds__(256) void mega_gemm2(
    const bf16* __restrict__ Av, const bf16* __restrict__ W4b,
    const float* __restrict__ Wb, const float* __restrict__ bb,
    const float* __restrict__ ba, bf16* __restrict__ C4,
    float* __restrict__ betab)
{
  __shared__ __align__(16) __bf16 As[128 * 32];
  __shared__ __align__(16) __bf16 Bs[128 * 32];

  const int bx = blockIdx.x;
  const bool isbeta = (bx >= 1024);
  int tile_m, tile_n;
  if (!isbeta) {
    const int xcd = bx & 7;
    const int local = bx >> 3;        // 0..127
    const int mg = xcd >> 1;          // 0..3 (M groups of 8)
    const int ng = xcd & 1;           // 0..1 (N groups of 16)
    const int lm = local & 7;         // 0..7
    const int ln = local >> 3;        // 0..15
    tile_m = (mg * 8 + lm) * 128;
    tile_n = (ng * 16 + ln) * 128;
  } else {
    tile_m = (bx - 1024) * 128;
    tile_n = 0;
  }
  const int grp = tile_n >> 10;
  const int tnl = tile_n & 1023;

  const int tid  = threadIdx.x;
  const int lane = tid & 63;
  const int wave = tid >> 6;
  const int wm = (wave >> 1) * 64;
  const int wn = (wave & 1) * 64;

  const int srow = lane >> 2;
  const int scol = (lane & 3) * 8;

  f32x4 acc[4][4];
#pragma unroll
  for (int i = 0; i < 4; ++i)
#pragma unroll
    for (int j = 0; j < 4; ++j) acc[i][j] = {0.f, 0.f, 0.f, 0.f};

  const __bf16* Wp = (const __bf16*)W4b + (size_t)grp * 1024 * 1024;

  for (int k0 = 0; k0 < 1024; k0 += 32) {
    float4 b0[2], b1[2];
    if (isbeta) {
#pragma unroll
      for (int s = 0; s < 2; ++s) {
        int brow = s * 64 + wave * 16 + srow;
        if (brow > 15) brow = 15;
        const float* bp = Wb + (size_t)brow * 1024 + k0 + scol;
        b0[s] = *(const float4*)bp;
        b1[s] = *(const float4*)(bp + 4);
      }
    }
    __syncthreads();
#pragma unroll
    for (int s = 0; s < 2; ++s) {
      int arow = tile_m + s * 64 + wave * 16 + srow;
      async_copy16((const __bf16*)Av + (size_t)arow * 1024 + k0 + scol,
                   &As[(s * 64 + wave * 16 + srow) * 32 + scol]);
      if (!isbeta) {
        int brow = tnl + s * 64 + wave * 16 + srow;
        async_copy16(Wp + (size_t)brow * 1024 + k0 + scol,
                     &Bs[(s * 64 + wave * 16 + srow) * 32 + scol]);
      } else {
        bf16x8 u;
        u[0] = cvt_bf16(b0[s].x); u[1] = cvt_bf16(b0[s].y);
        u[2] = cvt_bf16(b0[s].z); u[3] = cvt_bf16(b0[s].w);
        u[4] = cvt_bf16(b1[s].x); u[5] = cvt_bf16(b1[s].y);
        u[6] = cvt_bf16(b1[s].z); u[7] = cvt_bf16(b1[s].w);
        *(bf16x8*)&Bs[(s * 64 + wave * 16 + srow) * 32 + scol] = u;
      }
    }
    __syncthreads();

    bf16x8 af[4], bfr[4];
#pragma unroll
    for (int i = 0; i < 4; ++i)
      af[i] = *(const bf16x8*)&As[(wm + i * 16 + (lane & 15)) * 32 + (lane >> 4) * 8];
#pragma unroll
    for (int j = 0; j < 4; ++j)
      bfr[j] = *(const bf16x8*)&Bs[(wn + j * 16 + (lane & 15)) * 32 + (lane >> 4) * 8];

#pragma unroll
    for (int i = 0; i < 4; ++i)
#pragma unroll
      for (int j = 0; j < 4; ++j)
        acc[i][j] = __builtin_amdgcn_mfma_f32_16x16x32_bf16(af[i], bfr[j], acc[i][j], 0, 0, 0);
  }

  if (!isbeta) {
    bf16* Cp = (bf16*)((__bf16*)C4 + (size_t)grp * 4096 * 1024);
#pragma unroll
    for (int i = 0; i < 4; ++i)
#pragma unroll
      for (int j = 0; j < 4; ++j)
#pragma unroll
        for (int r = 0; r < 4; ++r) {
          int gm = tile_m + wm + i * 16 + (lane >> 4) * 4 + r;
          int col = tnl + wn + j * 16 + (lane & 15);
          float val = acc[i][j][r];
          if (grp == 3) val = 1.f / (1.f + __expf(-(val + ba[col])));
          ((__bf16*)Cp)[(size_t)gm * 1024 + col] = cvt_bf16(val);
        }
  } else {
#pragma unroll
    for (int i = 0; i < 4; ++i)
#pragma unroll
      for (int j = 0; j < 4; ++j)
#pragma unroll
        for (int r = 0; r < 4; ++r) {
          int gm = tile_m + wm + i * 16 + (lane >> 4) * 4 + r;
          int gn = wn + j * 16 + (lane & 15);
          if (gn < 16) {
            float val = 1.f / (1.f + __expf(-(acc[i][j][r] + bb[gn])));
            betab[(size_t)gn * 4096 + gm] = val;
          }
        }
  }
}

// shared conv body: causal depthwise K=4 + bias + SiLU (+scale), x8 vec.
__device__ __forceinline__ void conv_body(
    int idx, const bf16* __restrict__ z, const float* __restrict__ w,
    const float* __restrict__ bias, bf16* __restrict__ out, float scale)
{
  int c8 = idx & 127;
  int m  = idx >> 7;
  int t  = m & 2047;
  int c0 = c8 * 8;

  const __bf16* base = (const __bf16*)z + (size_t)m * 1024 + c0;
  const bf16x8 zzero = __builtin_bit_cast(bf16x8, (u32x4){0u, 0u, 0u, 0u});
  bf16x8 z3 = *(const bf16x8*)base;
  bf16x8 z2 = (t >= 1) ? *(const bf16x8*)(base - 1024) : zzero;
  bf16x8 z1 = (t >= 2) ? *(const bf16x8*)(base - 2048) : zzero;
  bf16x8 z0 = (t >= 3) ? *(const bf16x8*)(base - 3072) : zzero;

  const float* wp = w + c0 * 4;
  bf16x8 res;
#pragma unroll
  for (int e = 0; e < 8; ++e) {
    float4 we = *(const float4*)(wp + e * 4);
    float acc = bias[c0 + e] + (float)z3[e] * we.w;
    acc += (float)z2[e] * we.z;
    acc += (float)z1[e] * we.y;
    acc += (float)z0[e] * we.x;
    float s = acc / (1.f + __expf(-acc));
    res[e] = cvt_bf16(s * scale);
  }
  *(bf16x8*)((__bf16*)out + (size_t)m * 1024 + c0) = res;
}

// standalone conv (fallback path)
__global__ __launch_bounds__(256) void conv_silu_kernel(
    const bf16* __restrict__ z, const float* __restrict__ w,
    const float* __restrict__ bias, bf16* __restrict__ out, float scale)
{
  conv_body(blockIdx.x * 256 + threadIdx.x, z, w, bias, out, scale);
}

// conv_q + conv_k in one launch (disjoint planes). Grid 4096.
__global__ __launch_bounds__(256) void conv2_kernel(
    const bf16* __restrict__ zq, const bf16* __restrict__ zk,
    const float* __restrict__ qcw, const float* __restrict__ qcb,
    const float* __restrict__ kcw, const float* __restrict__ kcb,
    bf16* __restrict__ oq, bf16* __restrict__ ok)
{
  int sec = blockIdx.x >> 11;
  int bx  = blockIdx.x & 2047;
  int idx = bx * 256 + threadIdx.x;
  if (sec == 0) conv_body(idx, zq, qcw, qcb, oq, 1.f);
  else          conv_body(idx, zk, kcw, kcb, ok, 0.125f);
}

// conv_v + kk in one launch (kk reads k from PREVIOUS launch). Grid 3072.
__global__ __launch_bounds__(256) void convv_kk_kernel(
    const bf16* __restrict__ zv, const float* __restrict__ vcw,
    const float* __restrict__ vcb, bf16* __restrict__ ov,
    const bf16* __restrict__ k, const float* __restrict__ betab,
    float* __restrict__ G)
{
  if (blockIdx.x < 2048) {
    conv_body(blockIdx.x * 256 + threadIdx.x, zv, vcw, vcb, ov, 1.f);
    return;
  }
  int gtid = (blockIdx.x - 2048) * 256 + threadIdx.x;
  int out = gtid >> 2;           // h*4096 + m
  int j   = gtid & 3;
  int h = out >> 12;
  int m = out & 4095;
  int t = m & 2047;
  float s = 0.f;
  if (t > 0) {
    const __bf16* r1 = (const __bf16*)k + (size_t)m * 1024 + h * 64 + j * 16;
    const __bf16* r0 = r1 - 1024;
    bf16x8 a0 = *(const bf16x8*)r0;
    bf16x8 a1 = *(const bf16x8*)(r0 + 8);
    bf16x8 b0 = *(const bf16x8*)r1;
    bf16x8 b1 = *(const bf16x8*)(r1 + 8);
#pragma unroll
    for (int e = 0; e < 8; ++e)
      s += (float)a0[e] * (float)b0[e] + (float)a1[e] * (float)b1[e];
  }
  s += __shfl_xor(s, 1);
  s += __shfl_xor(s, 2);
  if (j == 0) G[out] = betab[out] * s;
}

// kk standalone (fallback)
__global__ __launch_bounds__(256) void kk_kernel(
    const bf16* __restrict__ k, const float* __restrict__ betab,
    float* __restrict__ G)
{
  int tid = blockIdx.x * 256 + threadIdx.x;
  int out = tid >> 2;
  int j   = tid & 3;
  int h = out >> 12;
  int m = out & 4095;
  int t = m & 2047;
  float s = 0.f;
  if (t > 0) {
    const __bf16* r1 = (const __bf16*)k + (size_t)m * 1024 + h * 64 + j * 16;
    const __bf16* r0 = r1 - 1024;
    bf16x8 a0 = *(const bf16x8*)r0;
    bf16x8 a1 = *(const bf16x8*)(r0 + 8);
    bf16x8 b0 = *(const bf16x8*)r1;
    bf16x8 b1 = *(const bf16x8*)(r1 + 8);
#pragma unroll
    for (int e = 0; e < 8; ++e)
      s += (float)a0[e] * (float)b0[e] + (float)a1[e] * (float)b1[e];
  }
  s += __shfl_xor(s, 1);
  s += __shfl_xor(s, 2);
  if (j == 0) G[out] = betab[out] * s;
}

// One scan step (constant word indices only).
#define SCAN_STEP(i, KN0, KN1, Q0, Q1, WV, WA, BT, GT, LAST)                  \
  {                                                                           \
    const float vr = ((i) & 1) ? bcf((WV) & 0xffff0000u) : bcf((WV) << 16);   \
    const float ar = ((i) & 1) ? bcf((WA) & 0xffff0000u) : bcf((WA) << 16);   \
    float unxt = 0.f;                                                         \
    f32x2 k2n0 = {0.f, 0.f}, k2n1 = {0.f, 0.f};                               \
    if (!(LAST)) {                                                            \
      k2n0 = unpk(KN0); k2n1 = unpk(KN1);                                     \
      f32x2 dd = S20 * k2n0; dd += S21 * k2n1;                                \
      unxt = dd[0] + dd[1];                                                   \
      unxt += dpp_f<0xB1>(unxt);  unxt += dpp_f<0x4E>(unxt);                  \
      unxt += dpp_f<0x141>(unxt); unxt += dpp_f<0x140>(unxt);                 \
    } else { Sold0 = S20; Sold1 = S21; }                                      \
    float A_ = (BT) * __builtin_fmaf(aprev, u, -vr);                          \
    cc = __builtin_fmaf(-cc, (GT), A_);                                       \
    f32x2 q20 = unpk(Q0), q21 = unpk(Q1);                                     \
    const f32x2 cc2 = {cc, cc}, arv = {ar, ar};                               \
    f32x2 oo;                                                                 \
    { f32x2 t0 = cc2 * k2c0; S20 = arv * S20 - t0; oo = S20 * q20;            \
      f32x2 t1 = cc2 * k2c1; S21 = arv * S21 - t1; oo += S21 * q21; }         \
    so[(i)][lane] = oo[0] + oo[1];                                            \
    aprev = ar;                                                               \
    if (!(LAST)) { k2c0 = k2n0; k2c1 = k2n1; u = unxt; }                      \
  }

// Load one 2-step group (g = 0..7) into a named set (14 regs).
#define LOADG(KS, QS, VS, AS, BS, GS, g)                                      \
  KS = *(const u32x4*)&skT[buf][sg][(g) * 8];                                 \
  QS = *(const u32x4*)&sqT[buf][sg][(g) * 8];                                 \
  VS = *(const unsigned int*)&svaT[buf][0][r4][(g) * 2];                      \
  AS = *(const unsigned int*)&svaT[buf][1][r4][(g) * 2];                      \
  BS = *(const f32x2*)&sbeta[c * 16 + (g) * 2];                               \
  GS = *(const f32x2*)&sG[c * 16 + (g) * 2];

// FUSED kernel: blocks 0..511 = delta-rule scan (single wave; threads>=64
// exit; NO barriers; s_setprio(1)). Blocks 512..767 = g-GEMM.
__global__ __launch_bounds__(256) void scan_gemm_kernel(
    const bf16* __restrict__ q, const bf16* __restrict__ k,
    const bf16* __restrict__ v, const bf16* __restrict__ a,
    const float* __restrict__ betab, const float* __restrict__ gkk,
    bf16* __restrict__ o,
    const float* __restrict__ x, const bf16* __restrict__ Wgb,
    bf16* __restrict__ gout)
{
  __shared__ __align__(16) __bf16 skT[2][16][72];
  __shared__ __align__(16) __bf16 sqT[2][16][72];
  __shared__ __align__(16) __bf16 svaT[2][2][4][16];
  __shared__ __align__(16) float  so[16][68];
  __shared__ __align__(16) __bf16 so2[16][4];
  __shared__ float sbeta[2048];
  __shared__ float sG[2048];
  __shared__ __align__(16) __bf16 As[128 * 32];
  __shared__ __align__(16) __bf16 Bs[128 * 32];

  if (blockIdx.x >= 512) {
    const int gb   = blockIdx.x - 512;
    const int tid  = threadIdx.x;
    const int lane = tid & 63;
    const int wave = tid >> 6;
    const int tile_m = (gb >> 3) * 128;
    const int tile_n = (gb & 7) * 128;
    const int wm = (wave >> 1) * 64;
    const int wn = (wave & 1) * 64;
    const int srow = lane >> 2;
    const int scol = (lane & 3) * 8;

    f32x4 acc[4][4];
#pragma unroll
    for (int i = 0; i < 4; ++i)
#pragma unroll
      for (int j = 0; j < 4; ++j) acc[i][j] = {0.f, 0.f, 0.f, 0.f};

    for (int k0 = 0; k0 < 1024; k0 += 32) {
      float4 a0[2], a1[2];
#pragma unroll
      for (int s = 0; s < 2; ++s) {
        int arow = tile_m + s * 64 + wave * 16 + srow;
        const float* ap = x + (size_t)arow * 1024 + k0 + scol;
        a0[s] = *(const float4*)ap;
        a1[s] = *(const float4*)(ap + 4);
      }
      __syncthreads();
#pragma unroll
      for (int s = 0; s < 2; ++s) {
        bf16x8 ua;
        ua[0] = cvt_bf16(a0[s].x); ua[1] = cvt_bf16(a0[s].y);
        ua[2] = cvt_bf16(a0[s].z); ua[3] = cvt_bf16(a0[s].w);
        ua[4] = cvt_bf16(a1[s].x); ua[5] = cvt_bf16(a1[s].y);
        ua[6] = cvt_bf16(a1[s].z); ua[7] = cvt_bf16(a1[s].w);
        *(bf16x8*)&As[(s * 64 + wave * 16 + srow) * 32 + scol] = ua;
        int brow = tile_n + s * 64 + wave * 16 + srow;
        async_copy16((const __bf16*)Wgb + (size_t)brow * 1024 + k0 + scol,
                     &Bs[(s * 64 + wave * 16 + srow) * 32 + scol]);
      }
      __syncthreads();

      bf16x8 af[4], bfr[4];
#pragma unroll
      for (int i = 0; i < 4; ++i)
        af[i] = *(const bf16x8*)&As[(wm + i * 16 + (lane & 15)) * 32 + (lane >> 4) * 8];
#pragma unroll
      for (int j = 0; j < 4; ++j)
        bfr[j] = *(const bf16x8*)&Bs[(wn + j * 16 + (lane & 15)) * 32 + (lane >> 4) * 8];

#pragma unroll
      for (int i = 0; i < 4; ++i)
#pragma unroll
        for (int j = 0; j < 4; ++j)
          acc[i][j] = __builtin_amdgcn_mfma_f32_16x16x32_bf16(af[i], bfr[j], acc[i][j], 0, 0, 0);
    }

#pragma unroll
    for (int i = 0; i < 4; ++i)
#pragma unroll
      for (int j = 0; j < 4; ++j)
#pragma unroll
        for (int r = 0; r < 4; ++r) {
          int gm = tile_m + wm + i * 16 + (lane >> 4) * 4 + r;
          int gn = tile_n + wn + j * 16 + (lane & 15);
          float val = 1.f / (1.f + __expf(-acc[i][j][r]));
          gout[(size_t)gm * 1024 + gn] = (bf16)val;
        }
    return;
  }

  // ---------------- scan path (single wave; extra waves exit) ----------------
  if (threadIdx.x >= 64) return;
  __builtin_amdgcn_s_setprio(1);

  const int blk = blockIdx.x;
  const int qd = blk >> 5;
  const int bh = blk & 31;
  const int b = bh >> 4, h = bh & 15;
  const int lane = threadIdx.x;
  const int r4 = lane >> 4;
  const int sg = lane & 15;

  {
    const float* bp = betab + (size_t)h * 4096 + b * 2048;
    const float* gp = gkk   + (size_t)h * 4096 + b * 2048;
    for (int t4 = lane * 4; t4 < 2048; t4 += 256) {
      *(float4*)&sbeta[t4] = *(const float4*)(bp + t4);
      *(float4*)&sG[t4]    = *(const float4*)(gp + t4);
    }
  }

  const size_t bkq = (size_t)b * 2048 * 1024 + h * 64;
  const size_t bva = bkq + qd * 4;
  const __bf16* kp = (const __bf16*)k;
  const __bf16* qp = (const __bf16*)q;

  const int g_st = lane >> 3;
  const int g_cg = (lane & 7) * 8;
  const int sgp  = (lane & 7) * 2;
  const int va_vh = (lane >> 4) & 1;
  const int va_st = lane & 15;

  bf16x8 pk0, pk1, pq0, pq1;
  bf16x4v pva;
  auto fetch = [&](int t0) {
    int st0 = t0 + g_st, st1 = t0 + 8 + g_st;
    pk0 = *(const bf16x8*)(kp + bkq + (size_t)st0 * 1024 + g_cg);
    pk1 = *(const bf16x8*)(kp + bkq + (size_t)st1 * 1024 + g_cg);
    pq0 = *(const bf16x8*)(qp + bkq + (size_t)st0 * 1024 + g_cg);
    pq1 = *(const bf16x8*)(qp + bkq + (size_t)st1 * 1024 + g_cg);
    if (lane < 32) {
      const __bf16* src = va_vh ? (const __bf16*)a : (const __bf16*)v;
      pva = *(const bf16x4v*)(src + bva + (size_t)(t0 + va_st) * 1024);
    }
  };
  auto commit = [&](int cb) {
    {
      u32x4 wk = __builtin_bit_cast(u32x4, pk0);
      u32x4 wq = __builtin_bit_cast(u32x4, pq0);
      u32x2 lo, hi;
      lo[0] = wk[0]; lo[1] = wk[1]; hi[0] = wk[2]; hi[1] = wk[3];
      *(u32x2*)&skT[cb][sgp][g_st * 4]     = lo;
      *(u32x2*)&skT[cb][sgp + 1][g_st * 4] = hi;
      lo[0] = wq[0]; lo[1] = wq[1]; hi[0] = wq[2]; hi[1] = wq[3];
      *(u32x2*)&sqT[cb][sgp][g_st * 4]     = lo;
      *(u32x2*)&sqT[cb][sgp + 1][g_st * 4] = hi;
    }
    {
      u32x4 wk = __builtin_bit_cast(u32x4, pk1);
      u32x4 wq = __builtin_bit_cast(u32x4, pq1);
      u32x2 lo, hi;
      lo[0] = wk[0]; lo[1] = wk[1]; hi[0] = wk[2]; hi[1] = wk[3];
      *(u32x2*)&skT[cb][sgp][(8 + g_st) * 4]     = lo;
      *(u32x2*)&skT[cb][sgp + 1][(8 + g_st) * 4] = hi;
      lo[0] = wq[0]; lo[1] = wq[1]; hi[0] = wq[2]; hi[1] = wq[3];
      *(u32x2*)&sqT[cb][sgp][(8 + g_st) * 4]     = lo;
      *(u32x2*)&sqT[cb][sgp + 1][(8 + g_st) * 4] = hi;
    }
    if (lane < 32) {
#pragma unroll
      for (int r = 0; r < 4; ++r) svaT[cb][va_vh][r][va_st] = pva[r];
    }
  };

  fetch(0); commit(0);

  f32x2 S20 = {0.f, 0.f}, S21 = {0.f, 0.f};
  f32x2 Sold0 = {0.f, 0.f}, Sold1 = {0.f, 0.f};
  float u = 0.f, cc = 0.f, aprev = 0.f;

  auto unpk = [&](unsigned int w) -> f32x2 {
    f32x2 r; r[0] = bcf(w << 16); r[1] = bcf(w & 0xffff0000u); return r;
  };

  for (int c = 0; c < 128; ++c) {
    const int buf = c & 1;
    const bool hasNext = (c + 1 < 128);

    if (hasNext) fetch((c + 1) * 16);

    u32x4 kA, qA, kB, qB, kC, qC;
    unsigned int vA, aA, vB, aB, vC, aC;
    f32x2 bA, gA, bB, gB, bC, gC;

    LOADG(kA, qA, vA, aA, bA, gA, 0)
    LOADG(kB, qB, vB, aB, bB, gB, 1)
    LOADG(kC, qC, vC, aC, bC, gC, 2)

    f32x2 k2c0 = unpk(kA[0]);
    f32x2 k2c1 = unpk(kA[1]);
    {
      f32x2 dd = Sold0 * k2c0;
      dd += Sold1 * k2c1;
      float un = dd[0] + dd[1];
      un += dpp_f<0xB1>(un);
      un += dpp_f<0x4E>(un);
      un += dpp_f<0x141>(un);
      un += dpp_f<0x140>(un);
      u = un;
    }

    SCAN_STEP(0,  kA[2], kA[3], qA[0], qA[1], vA, aA, bA[0], gA[0], false)
    SCAN_STEP(1,  kB[0], kB[1], qA[2], qA[3], vA, aA, bA[1], gA[1], false)
    LOADG(kA, qA, vA, aA, bA, gA, 3)
    SCAN_STEP(2,  kB[2], kB[3], qB[0], qB[1], vB, aB, bB[0], gB[0], false)
    SCAN_STEP(3,  kC[0], kC[1], qB[2], qB[3], vB, aB, bB[1], gB[1], false)
    LOADG(kB, qB, vB, aB, bB, gB, 4)
    SCAN_STEP(4,  kC[2], kC[3], qC[0], qC[1], vC, aC, bC[0], gC[0], false)
    SCAN_STEP(5,  kA[0], kA[1], qC[2], qC[3], vC, aC, bC[1], gC[1], false)
    LOADG(kC, qC, vC, aC, bC, gC, 5)
    SCAN_STEP(6,  kA[2], kA[3], qA[0], qA[1], vA, aA, bA[0], gA[0], false)
    SCAN_STEP(7,  kB[0], kB[1], qA[2], qA[3], vA, aA, bA[1], gA[1], false)
    LOADG(kA, qA, vA, aA, bA, gA, 6)
    SCAN_STEP(8,  kB[2], kB[3], qB[0], qB[1], vB, aB, bB[0], gB[0], false)
    SCAN_STEP(9,  kC[0], kC[1], qB[2], qB[3], vB, aB, bB[1], gB[1], false)
    LOADG(kB, qB, vB, aB, bB, gB, 7)
    SCAN_STEP(10, kC[2], kC[3], qC[0], qC[1], vC, aC, bC[0], gC[0], false)
    SCAN_STEP(11, kA[0], kA[1], qC[2], qC[3], vC, aC, bC[1], gC[1], false)
    SCAN_STEP(12, kA[2], kA[3], qA[0], qA[1], vA, aA, bA[0], gA[0], false)
    SCAN_STEP(13, kB[0], kB[1], qA[2], qA[3], vA, aA, bA[1], gA[1], false)
    SCAN_STEP(14, kB[2], kB[3], qB[0], qB[1], vB, aB, bB[0], gB[0], false)
    SCAN_STEP(15, kB[2], kB[3], qB[2], qB[3], vB, aB, bB[1], gB[1], true)

    {
      int st = lane >> 2, rr = lane & 3;
      float4 A0 = *(const float4*)&so[st][rr * 16];
      float4 A1 = *(const float4*)&so[st][rr * 16 + 4];
      float4 A2 = *(const float4*)&so[st][rr * 16 + 8];
      float4 A3 = *(const float4*)&so[st][rr * 16 + 12];
      float s = (((A0.x + A0.y) + (A0.z + A0.w)) + ((A1.x + A1.y) + (A1.z + A1.w)))
              + (((A2.x + A2.y) + (A2.z + A2.w)) + ((A3.x + A3.y) + (A3.z + A3.w)));
      so2[st][rr] = cvt_bf16(s);
    }
    if (lane < 16)
      *(bf16x4v*)((__bf16*)o + bva + (size_t)(c * 16 + lane) * 1024) =
          *(const bf16x4v*)&so2[lane][0];

    if (hasNext) commit(buf ^ 1);
  }
}

// LayerNorm over DV=64 per (b,t,h) row, *ln_w+ln_b, *gate -> bf16 (fallback)
__global__ __launch_bounds__(256) void ln_gate_kernel(
    const bf16* __restrict__ o, const bf16* __restrict__ g,
    const float* __restrict__ lnw, const float* __restrict__ lnb,
    bf16* __restrict__ out)
{
  int row = blockIdx.x * 4 + (threadIdx.x >> 6);
  int lane = threadIdx.x & 63;
  size_t idx = (size_t)row * 64 + lane;
  float xv = (float)o[idx];
  float mu = xv;
#pragma unroll
  for (int s = 1; s < 64; s <<= 1) mu += __shfl_xor(mu, s);
  mu *= (1.f / 64.f);
  float d = xv - mu;
  float vv = d * d;
#pragma unroll
  for (int s = 1; s < 64; s <<= 1) vv += __shfl_xor(vv, s);
  vv *= (1.f / 64.f);
  float y = d * rsqrtf(vv + 1e-5f) * lnw[lane] + lnb[lane];
  y *= (float)g[idx];
  out[idx] = (bf16)y;
}

extern "C" void kernel_launch(void* const* d_in, const int* in_sizes, int n_in,
                              void* d_out, int out_size, void* d_ws, size_t ws_size,
                              hipStream_t stream)
{
  const float* x   = (const float*)d_in[0];
  const float* Wq  = (const float*)d_in[1];
  const float* Wk  = (const float*)d_in[2];
  const float* Wv  = (const float*)d_in[3];
  const float* Wa  = (const float*)d_in[4];
  const float* ba  = (const float*)d_in[5];
  const float* Wb  = (const float*)d_in[6];
  const float* bb  = (const float*)d_in[7];
  const float* Wg  = (const float*)d_in[8];
  const float* Wo  = (const float*)d_in[9];
  const float* qcw = (const float*)d_in[10];
  const float* qcb = (const float*)d_in[11];
  const float* kcw = (const float*)d_in[12];
  const float* kcb = (const float*)d_in[13];
  const float* vcw = (const float*)d_in[14];
  const float* vcb = (const float*)d_in[15];
  const float* lnw = (const float*)d_in[16];
  const float* lnb = (const float*)d_in[17];

  const int M = 4096, HID = 1024;
  const size_t PLANE = (size_t)M * HID;
  const size_t PB = PLANE * sizeof(bf16);          // 8 MB bf16 plane

  char* ws = (char*)d_ws;
  float* outf = (float*)d_out;
  const bool rich = (ws_size >= 5 * PB + 1024);

  dim3 blk(256);
  dim3 g8(8, 32);
  int nconv = (int)((size_t)M * 128 / 256);

  if (rich) {
    bf16* P0 = (bf16*)(ws);
    bf16* P1 = (bf16*)(ws + PB);
    bf16* P2 = (bf16*)(ws + 2 * PB);
    bf16* P3 = (bf16*)(ws + 3 * PB);
    bf16* P4 = (bf16*)(ws + 4 * PB);
    bf16*  xb    = (bf16*)d_out;                            // [0,8M)
    bf16*  W4b   = (bf16*)((char*)d_out + 8 * 1024 * 1024); // [8M,16M)
    bf16*  Kb    = xb;                                      // k-plane
    bf16*  Qb    = W4b;                                     // q-plane
    float* betab = (float*)P4;
    float* gkk   = (float*)((char*)P4 + 256 * 1024);
    bf16*  Wgb   = (bf16*)((char*)P4 + 1024 * 1024);
    bf16*  Wob   = (bf16*)((char*)P4 + 3 * 1024 * 1024);

    // 1. convert x + 6 weight matrices to bf16
    cvtw_kernel<<<10240, blk, 0, stream>>>(x, Wq, Wk, Wv, Wa, Wg, Wo,
                                           xb, W4b, Wgb, Wob);
    // 2. fused 4-projection + beta GEMM (1-D grid, 8m x 16n per-XCD partition)
    mega_gemm2<<<1056, blk, 0, stream>>>(xb, W4b, Wb, bb, ba, P0, betab);
    // 3. conv q (P0->Qb) + conv k (P1->Kb) -- disjoint planes
    conv2_kernel<<<4096, blk, 0, stream>>>(P0, P1, qcw, qcb, kcw, kcb, Qb, Kb);
    // 4. conv v (P2->P1) + kk (reads Kb from launch 3)
    convv_kk_kernel<<<3072, blk, 0, stream>>>(P2, vcw, vcb, P1, Kb, betab, gkk);
    // 5. FUSED scan (o->P0) + g-GEMM (sigmoid(x@Wgb^T)->P2)
    scan_gemm_kernel<<<768, blk, 0, stream>>>(Qb, Kb, P1, P3, betab, gkk, P0,
                                              x, Wgb, P2);
    // 6. final GEMM with fused LN+gate (512 blocks = 2/CU, XCD swizzle,
    //    full-64k B staging: 2 barriers/head)
    gemm_bb_ln<<<512, blk, 0, stream>>>(P0, P2, lnw, lnb, Wob, outf);
  } else {
    bf16* P  = (bf16*)(ws);
    bf16* qb = (bf16*)(ws + PB);
    bf16* kb = (bf16*)(ws + 2 * PB);
    bf16* vb = (bf16*)(ws + 3 * PB);
    float* betab = (float*)d_out;
    float* gkk   = (float*)((char*)d_out + 256 * 1024);
    bf16*  ob    = (bf16*)((char*)d_out + 8 * 1024 * 1024);

    gemm_bt<2, true><<<g8, blk, 0, stream>>>(x, Wq, nullptr, nullptr, P, M, HID, HID);
    conv_silu_kernel<<<nconv, blk, 0, stream>>>(P, qcw, qcb, qb, 1.f);
    gemm_bt<2, true><<<g8, blk, 0, stream>>>(x, Wk, nullptr, nullptr, P, M, HID, HID);
    conv_silu_kernel<<<nconv, blk, 0, stream>>>(P, kcw, kcb, kb, 0.125f);
    gemm_bt<2, true><<<g8, blk, 0, stream>>>(x, Wv, nullptr, nullptr, P, M, HID, HID);
    conv_silu_kernel<<<nconv, blk, 0, stream>>>(P, vcw, vcb, vb, 1.f);
    gemm_bt<3, true><<<g8, blk, 0, stream>>>(x, Wa, ba, nullptr, P, M, HID, HID);
    gemm_bt<5, true><<<dim3(1, 32), blk, 0, stream>>>(x, Wb, bb, betab, nullptr, M, 16, HID);
    kk_kernel<<<1024, blk, 0, stream>>>(kb, betab, gkk);
    scan_gemm_kernel<<<512, blk, 0, stream>>>(qb, kb, vb, P, betab, gkk, ob,
                                              x, nullptr, nullptr);
    gemm_bt<3, true><<<g8, blk, 0, stream>>>(x, Wg, nullptr, nullptr, qb, M, HID, HID);
    ln_gate_kernel<<<M * 16 / 4, blk, 0, stream>>>(ob, qb, lnw, lnb, kb);
    gemm_bt<4, false><<<g8, blk, 0, stream>>>(kb, Wo, nullptr, outf, nullptr, M, HID, HID);
  }
}